// Round 5
// baseline (3842.799 us; speedup 1.0000x reference)
//
#include <hip/hip_runtime.h>
#include <cstdint>
#include <cstddef>

#define NN 20000
#define NE 640000
#define NF 64
#define HD 256
#define NL 4

typedef __attribute__((ext_vector_type(8))) short short8;
typedef __attribute__((ext_vector_type(4))) float f32x4;

__device__ __forceinline__ float bf2f(unsigned short u){
  union { unsigned int i; float f; } x; x.i = ((unsigned int)u) << 16; return x.f;
}
__device__ __forceinline__ unsigned short f2bf(float f){
  union { float f; unsigned int i; } x; x.f = f;
  unsigned int r = x.i + 0x7FFFu + ((x.i >> 16) & 1u);   // RNE
  return (unsigned short)(r >> 16);
}
__device__ __forceinline__ float silu_f(float v){
  return v * (1.0f / (1.0f + __expf(-v)));
}
__device__ __forceinline__ void async16(const void* g, void* l){
  __builtin_amdgcn_global_load_lds(
      (const __attribute__((address_space(1))) unsigned int*)g,
      (__attribute__((address_space(3))) unsigned int*)l, 16, 0, 0);
}

// ---------------- prep: weight transpose->bf16, h->bf16, radial ----------------
__global__ __launch_bounds__(256) void prep_k(
    const float* __restrict__ h_in, const float* __restrict__ cd,
    const float* __restrict__ w_in, const float* __restrict__ w_out,
    const float* __restrict__ ew1, const float* __restrict__ ew2,
    const float* __restrict__ nw1, const float* __restrict__ nw2,
    unsigned short* __restrict__ w_in_t, unsigned short* __restrict__ w_out_t,
    unsigned short* __restrict__ ew1t, float* __restrict__ w1r,
    unsigned short* __restrict__ ew2t, unsigned short* __restrict__ nw1t,
    unsigned short* __restrict__ nw2t, unsigned short* __restrict__ hb_in,
    float* __restrict__ radial)
{
  const int s = blockIdx.y;
  const int tid = blockIdx.x * 256 + threadIdx.x;
  if (s == 18) {
    if (tid < NN * NF) hb_in[tid] = f2bf(h_in[tid]);
    return;
  }
  if (s == 19) {
    if (tid < NE) {
      float x = cd[tid*3+0], y = cd[tid*3+1], z = cd[tid*3+2];
      radial[tid] = x*x + y*y + z*z;
    }
    return;
  }
  const float* src; unsigned short* dst; int K, N, dstK; float* extra = nullptr;
  if (s == 0)      { src = w_in;  dst = w_in_t;  K = NF;   N = HD; dstK = NF; }
  else if (s == 1) { src = w_out; dst = w_out_t; K = HD;   N = NF; dstK = HD; }
  else if (s < 6)  { int l = s-2;  src = ew1 + (size_t)l*513*HD;  dst = ew1t + (size_t)l*HD*512; K = 513;  N = HD; dstK = 512; extra = w1r + l*HD; }
  else if (s < 10) { int l = s-6;  src = ew2 + (size_t)l*HD*HD;   dst = ew2t + (size_t)l*HD*HD;  K = HD;   N = HD; dstK = HD; }
  else if (s < 14) { int l = s-10; src = nw1 + (size_t)l*2*HD*HD; dst = nw1t + (size_t)l*HD*512; K = 2*HD; N = HD; dstK = 512; }
  else             { int l = s-14; src = nw2 + (size_t)l*HD*HD;   dst = nw2t + (size_t)l*HD*HD;  K = HD;   N = HD; dstK = HD; }
  if (tid >= K * N) return;
  int k = tid / N, n = tid - k * N;
  float v = src[tid];
  if (k >= dstK) { if (extra) extra[n] = v; return; }   // radial row of edge_w1
  dst[(size_t)n * dstK + k] = f2bf(v);
}

// ---------------- CSR build (counting sort of edges by row) ----------------
__global__ __launch_bounds__(256) void hist_k(const int* __restrict__ erow, int* __restrict__ hist){
  int e = blockIdx.x * 256 + threadIdx.x;
  if (e < NE){
    unsigned r = (unsigned)erow[e]; if (r >= NN) r = 0;
    atomicAdd(&hist[r], 1);
  }
}

__global__ __launch_bounds__(256) void scan_k(const int* __restrict__ hist,
                                              int* __restrict__ starts, int* __restrict__ cursor){
  __shared__ int part[256];
  const int t = threadIdx.x;
  const int CH = 79;                 // 256*79 = 20224 >= 20000
  int lo = t * CH, hi = lo + CH; if (hi > NN) hi = NN; if (lo > NN) lo = NN;
  int s = 0;
  for (int i = lo; i < hi; ++i) s += hist[i];
  part[t] = s; __syncthreads();
  for (int off = 1; off < 256; off <<= 1){
    int v = (t >= off) ? part[t - off] : 0;
    __syncthreads();
    part[t] += v;
    __syncthreads();
  }
  int base = (t == 0) ? 0 : part[t - 1];
  for (int i = lo; i < hi; ++i){ starts[i] = base; cursor[i] = base; base += hist[i]; }
  if (t == 255) starts[NN] = part[255];
}

__global__ __launch_bounds__(256) void scatter_k(const int* __restrict__ erow,
                                                 int* __restrict__ cursor, int* __restrict__ sorted){
  int e = blockIdx.x * 256 + threadIdx.x;
  if (e < NE){
    unsigned r = (unsigned)erow[e]; if (r >= NN) r = 0;
    int pos = atomicAdd(&cursor[r], 1);
    sorted[pos] = e;
  }
}

// ---------------- generic 128x128 bf16 MFMA GEMM: out = [silu](A @ Wt^T + bias) ----------------
__global__ __launch_bounds__(256) void gemm_k(
    const unsigned short* __restrict__ Am, const unsigned short* __restrict__ Wt,
    const float* __restrict__ bias,
    unsigned short* __restrict__ outB, float* __restrict__ outF,
    int M, int N, int K, int fuseSilu)
{
  __shared__ __align__(16) unsigned short As[128*32];
  __shared__ __align__(16) unsigned short Bs[128*32];
  const int t = threadIdx.x;
  const int lane = t & 63, wave = t >> 6;
  const int ln15 = lane & 15, q = lane >> 4;
  const int bm = blockIdx.x, bn = blockIdx.y;
  const int wm = wave >> 1, wn = wave & 1;

  f32x4 acc[4][4];
  #pragma unroll
  for (int i = 0; i < 4; ++i)
    #pragma unroll
    for (int j = 0; j < 4; ++j) acc[i][j] = (f32x4){0.f,0.f,0.f,0.f};

  const int sr = t >> 2;
  const int sc = (t & 3) * 8;
  int am0 = bm*128 + sr;      if (am0 > M-1) am0 = M-1;
  int am1 = bm*128 + 64 + sr; if (am1 > M-1) am1 = M-1;
  int an0 = bn*128 + sr;      if (an0 > N-1) an0 = N-1;
  int an1 = bn*128 + 64 + sr; if (an1 > N-1) an1 = N-1;
  const unsigned short* a0 = Am + (size_t)am0 * K + sc;
  const unsigned short* a1 = Am + (size_t)am1 * K + sc;
  const unsigned short* b0 = Wt + (size_t)an0 * K + sc;
  const unsigned short* b1 = Wt + (size_t)an1 * K + sc;

  const int nkt = K >> 5;
  for (int kt = 0; kt < nkt; ++kt) {
    const int k0 = kt * 32;
    async16(a0 + k0, &As[t*8]);
    async16(a1 + k0, &As[2048 + t*8]);
    async16(b0 + k0, &Bs[t*8]);
    async16(b1 + k0, &Bs[2048 + t*8]);
    __syncthreads();
    short8 fa[4], fb[4];
    #pragma unroll
    for (int i = 0; i < 4; ++i)
      fa[i] = *(const short8*)&As[(wm*64 + i*16 + ln15)*32 + q*8];
    #pragma unroll
    for (int j = 0; j < 4; ++j)
      fb[j] = *(const short8*)&Bs[(wn*64 + j*16 + ln15)*32 + q*8];
    #pragma unroll
    for (int i = 0; i < 4; ++i)
      #pragma unroll
      for (int j = 0; j < 4; ++j)
        acc[i][j] = __builtin_amdgcn_mfma_f32_16x16x32_bf16(fa[i], fb[j], acc[i][j], 0, 0, 0);
    __syncthreads();
  }

  #pragma unroll
  for (int i = 0; i < 4; ++i) {
    #pragma unroll
    for (int j = 0; j < 4; ++j) {
      const int n = bn*128 + wn*64 + j*16 + ln15;
      if (n >= N) continue;
      const float bv = bias ? bias[n] : 0.0f;
      #pragma unroll
      for (int r = 0; r < 4; ++r) {
        const int m = bm*128 + wm*64 + i*16 + q*4 + r;
        if (m >= M) continue;
        float v = acc[i][j][r] + bv;
        if (fuseSilu) v = silu_f(v);
        if (outB) outB[(size_t)m * N + n] = f2bf(v);
        else      outF[(size_t)m * N + n] = v;
      }
    }
  }
}

// ---------------- fused edge MLP + aggregation: barrier-free K-loops ----------------
// 64 sorted edges per block, 256 threads. A and B fragments go global->VGPR
// (weights are L2-hot; per-wave B rows are disjoint). Register ping-pong gives
// fine-grained vmcnt overlap. Only 2 barriers per block (around the M1 LDS pass).
__global__ __launch_bounds__(256, 3) void edge_k(
    const unsigned short* __restrict__ hb,
    const int* __restrict__ erow, const int* __restrict__ ecol,
    const float* __restrict__ radial, const int* __restrict__ sorted,
    const unsigned short* __restrict__ w1t,  // [256][512]
    const float* __restrict__ b1, const float* __restrict__ w1r,
    const unsigned short* __restrict__ w2t,  // [256][256]
    const float* __restrict__ b2,
    float* __restrict__ agg)                  // [NN][256] fp32, pre-zeroed
{
  __shared__ __align__(16) unsigned short M1[8*2048];    // 32 KB, block kt: [64][32]
  __shared__ float radS[64];
  __shared__ int   rowS[64];
  // ~33 KB total

  const int t = threadIdx.x;
  const int lane = t & 63, wave = t >> 6;
  const int ln15 = lane & 15, q = lane >> 4;
  const int e0 = blockIdx.x * 64;

  // per-lane A-row element offsets (rows ln15, 16+ln15, 32+ln15, 48+ln15)
  int offR[4], offC[4];
  #pragma unroll
  for (int i = 0; i < 4; ++i) {
    int e = sorted[e0 + i*16 + ln15];
    unsigned r = (unsigned)erow[e]; if (r >= NN) r = 0;
    unsigned c = (unsigned)ecol[e]; if (c >= NN) c = 0;
    offR[i] = (int)r * HD + q*8;
    offC[i] = (int)c * HD + q*8;
  }
  if (t < 64) {
    int e = sorted[e0 + t];
    radS[t] = radial[e];
    unsigned r = (unsigned)erow[e]; if (r >= NN) r = 0;
    rowS[t] = (int)r;
  }
  __syncthreads();   // radS/rowS visible for epilogues

  // per-lane B-row bases (each wave owns rows wave*64 .. wave*64+63)
  const unsigned short* w1row[4];
  const unsigned short* w2row[4];
  #pragma unroll
  for (int j = 0; j < 4; ++j) {
    const int n = wave*64 + j*16 + ln15;
    w1row[j] = w1t + (size_t)n * 512 + q*8;
    w2row[j] = w2t + (size_t)n * HD  + q*8;
  }

  f32x4 acc[4][4];
  #pragma unroll
  for (int i = 0; i < 4; ++i)
    #pragma unroll
    for (int j = 0; j < 4; ++j) acc[i][j] = (f32x4){0.f,0.f,0.f,0.f};

  auto loadA = [&](short8* f, int kt){
    const int k0 = kt * 32;
    #pragma unroll
    for (int i = 0; i < 4; ++i) {
      const int off = (kt < 8) ? (offR[i] + k0) : (offC[i] + (k0 - HD));
      f[i] = *(const short8*)(hb + off);
    }
  };
  auto loadB1 = [&](short8* f, int kt){
    const int k0 = kt * 32;
    #pragma unroll
    for (int j = 0; j < 4; ++j) f[j] = *(const short8*)(w1row[j] + k0);
  };

  // phase 1: K = 512 (h[row] | h[col]) — no barriers, register ping-pong
  {
    short8 fa0[4], fb0[4], fa1[4], fb1[4];
    loadA(fa0, 0); loadB1(fb0, 0);
    #pragma unroll
    for (int kt = 0; kt < 16; kt += 2) {
      loadA(fa1, kt+1); loadB1(fb1, kt+1);
      #pragma unroll
      for (int i = 0; i < 4; ++i)
        #pragma unroll
        for (int j = 0; j < 4; ++j)
          acc[i][j] = __builtin_amdgcn_mfma_f32_16x16x32_bf16(fa0[i], fb0[j], acc[i][j], 0, 0, 0);
      if (kt + 2 < 16) { loadA(fa0, kt+2); loadB1(fb0, kt+2); }
      #pragma unroll
      for (int i = 0; i < 4; ++i)
        #pragma unroll
        for (int j = 0; j < 4; ++j)
          acc[i][j] = __builtin_amdgcn_mfma_f32_16x16x32_bf16(fa1[i], fb1[j], acc[i][j], 0, 0, 0);
    }
  }

  // epilogue 1: bias + radial rank-1 term + silu -> M1 (bf16, K-tile-blocked)
  #pragma unroll
  for (int i = 0; i < 4; ++i) {
    #pragma unroll
    for (int j = 0; j < 4; ++j) {
      const int n = wave*64 + j*16 + ln15;
      const float bv = b1[n], wr = w1r[n];
      #pragma unroll
      for (int r = 0; r < 4; ++r) {
        const int m = i*16 + q*4 + r;
        float v = acc[i][j][r] + bv + radS[m] * wr;
        M1[(n >> 5)*2048 + m*32 + (n & 31)] = f2bf(silu_f(v));
      }
    }
  }
  __syncthreads();   // M1 visible to all waves

  // phase 2: K = 256 (M1 @ W2^T) — fa from LDS, fb gathered, no barriers
  f32x4 acc2[4][4];
  #pragma unroll
  for (int i = 0; i < 4; ++i)
    #pragma unroll
    for (int j = 0; j < 4; ++j) acc2[i][j] = (f32x4){0.f,0.f,0.f,0.f};

  auto loadB2 = [&](short8* f, int kt){
    const int k0 = kt * 32;
    #pragma unroll
    for (int j = 0; j < 4; ++j) f[j] = *(const short8*)(w2row[j] + k0);
  };
  auto loadM = [&](short8* f, int kt){
    #pragma unroll
    for (int i = 0; i < 4; ++i)
      f[i] = *(const short8*)&M1[kt*2048 + (i*16 + ln15)*32 + q*8];
  };

  {
    short8 gb0[4], gb1[4], ma0[4], ma1[4];
    loadB2(gb0, 0); loadM(ma0, 0);
    #pragma unroll
    for (int kt = 0; kt < 8; kt += 2) {
      loadB2(gb1, kt+1); loadM(ma1, kt+1);
      #pragma unroll
      for (int i = 0; i < 4; ++i)
        #pragma unroll
        for (int j = 0; j < 4; ++j)
          acc2[i][j] = __builtin_amdgcn_mfma_f32_16x16x32_bf16(ma0[i], gb0[j], acc2[i][j], 0, 0, 0);
      if (kt + 2 < 8) { loadB2(gb0, kt+2); loadM(ma0, kt+2); }
      #pragma unroll
      for (int i = 0; i < 4; ++i)
        #pragma unroll
        for (int j = 0; j < 4; ++j)
          acc2[i][j] = __builtin_amdgcn_mfma_f32_16x16x32_bf16(ma1[i], gb1[j], acc2[i][j], 0, 0, 0);
    }
  }

  // epilogue 2: silu -> run-compressed atomicAdd into agg (sorted rows => runs)
  #pragma unroll
  for (int i = 0; i < 4; ++i) {
    #pragma unroll
    for (int j = 0; j < 4; ++j) {
      const int n = wave*64 + j*16 + ln15;
      const float bv = b2[n];
      const int mb = i*16 + q*4;
      int cur = rowS[mb];
      float s = 0.f;
      #pragma unroll
      for (int r = 0; r < 4; ++r) {
        int node = rowS[mb + r];
        float v = silu_f(acc2[i][j][r] + bv);
        if (node != cur) { atomicAdd(&agg[(size_t)cur * HD + n], s); s = 0.f; cur = node; }
        s += v;
      }
      atomicAdd(&agg[(size_t)cur * HD + n], s);
    }
  }
}

// ---------------- concat: xcat = [h | bf16(agg)] ----------------
__global__ __launch_bounds__(256) void concat_k(
    const unsigned short* __restrict__ h, const float* __restrict__ agg,
    unsigned short* __restrict__ xcat)
{
  const int g = blockIdx.x * 256 + threadIdx.x;   // NN*64 threads, 4 cols each
  const int node = g >> 6;
  const int c = (g & 63) * 4;
  if (node >= NN) return;
  *(ushort4*)(xcat + (size_t)node * 2 * HD + c) =
      *(const ushort4*)(h + (size_t)node * HD + c);
  float4 a = *(const float4*)(agg + (size_t)node * HD + c);
  ushort4 o; o.x = f2bf(a.x); o.y = f2bf(a.y); o.z = f2bf(a.z); o.w = f2bf(a.w);
  *(ushort4*)(xcat + (size_t)node * 2 * HD + HD + c) = o;
}

// ---------------- launch ----------------
extern "C" void kernel_launch(void* const* d_in, const int* in_sizes, int n_in,
                              void* d_out, int out_size, void* d_ws, size_t ws_size,
                              hipStream_t stream)
{
  (void)in_sizes; (void)n_in; (void)out_size; (void)ws_size;
  const float* h_in  = (const float*)d_in[0];
  const int*   ei    = (const int*)d_in[1];
  const float* cd    = (const float*)d_in[2];
  const float* w_in  = (const float*)d_in[3];
  const float* b_in  = (const float*)d_in[4];
  const float* w_out = (const float*)d_in[5];
  const float* b_out = (const float*)d_in[6];
  const float* ew1   = (const float*)d_in[7];
  const float* eb1   = (const float*)d_in[8];
  const float* ew2   = (const float*)d_in[9];
  const float* eb2   = (const float*)d_in[10];
  const float* nw1   = (const float*)d_in[11];
  const float* nb1   = (const float*)d_in[12];
  const float* nw2   = (const float*)d_in[13];
  const float* nb2   = (const float*)d_in[14];
  float* out = (float*)d_out;

  char* base = (char*)d_ws;
  size_t off = 0;
  auto WS = [&](size_t bytes) -> char* {
    char* p = base + off;
    off = (off + bytes + 255) & ~(size_t)255;
    return p;
  };
  float*          radial  = (float*)WS((size_t)NE * 4);
  unsigned short* hb_in   = (unsigned short*)WS((size_t)NN * NF * 2);
  unsigned short* hcur    = (unsigned short*)WS((size_t)NN * HD * 2);
  unsigned short* xcat    = (unsigned short*)WS((size_t)NN * 2 * HD * 2);
  float*          aggF    = (float*)WS((size_t)NN * HD * 4);
  unsigned short* x1      = (unsigned short*)aggF;   // alias: agg dead when x1 live
  unsigned short* w_in_t  = (unsigned short*)WS((size_t)NF * HD * 2);
  unsigned short* w_out_t = (unsigned short*)WS((size_t)NF * HD * 2);
  unsigned short* ew1t    = (unsigned short*)WS((size_t)NL * HD * 512 * 2);
  float*          w1r     = (float*)WS((size_t)NL * HD * 4);
  unsigned short* ew2t    = (unsigned short*)WS((size_t)NL * HD * HD * 2);
  unsigned short* nw1t    = (unsigned short*)WS((size_t)NL * HD * 512 * 2);
  unsigned short* nw2t    = (unsigned short*)WS((size_t)NL * HD * HD * 2);
  int*            hist    = (int*)WS((size_t)NN * 4);
  int*            starts  = (int*)WS((size_t)(NN + 1) * 4);
  int*            cursor  = (int*)WS((size_t)NN * 4);
  int*            sorted  = (int*)WS((size_t)NE * 4);

  hipMemsetAsync(hist, 0, (size_t)NN * 4, stream);
  prep_k<<<dim3(5000, 20, 1), 256, 0, stream>>>(h_in, cd, w_in, w_out, ew1, ew2, nw1, nw2,
      w_in_t, w_out_t, ew1t, w1r, ew2t, nw1t, nw2t, hb_in, radial);
  hist_k<<<NE / 256, 256, 0, stream>>>(ei, hist);
  scan_k<<<1, 256, 0, stream>>>(hist, starts, cursor);
  scatter_k<<<NE / 256, 256, 0, stream>>>(ei, cursor, sorted);

  // h = h_in @ w_in + b_in
  gemm_k<<<dim3(157, 2), 256, 0, stream>>>(hb_in, w_in_t, b_in, hcur, nullptr, NN, HD, NF, 0);

  for (int l = 0; l < NL; ++l) {
    hipMemsetAsync(aggF, 0, (size_t)NN * HD * 4, stream);
    edge_k<<<NE / 64, 256, 0, stream>>>(hcur, ei, ei + NE, radial, sorted,
        ew1t + (size_t)l * HD * 512, eb1 + l * HD, w1r + l * HD,
        ew2t + (size_t)l * HD * HD, eb2 + l * HD, aggF);
    concat_k<<<NN * 64 / 256, 256, 0, stream>>>(hcur, aggF, xcat);
    gemm_k<<<dim3(157, 2), 256, 0, stream>>>(xcat, nw1t + (size_t)l * HD * 512,
        nb1 + l * HD, x1, nullptr, NN, HD, 2 * HD, 1);
    gemm_k<<<dim3(157, 2), 256, 0, stream>>>(x1, nw2t + (size_t)l * HD * HD,
        nb2 + l * HD, hcur, nullptr, NN, HD, HD, 0);
  }

  // out = h @ w_out + b_out  (fp32 output)
  gemm_k<<<dim3(157, 1), 256, 0, stream>>>(hcur, w_out_t, b_out, nullptr, out, NN, NF, HD, 0);
}

// Round 6
// 3815.102 us; speedup vs baseline: 1.0073x; 1.0073x over previous
//
#include <hip/hip_runtime.h>
#include <cstdint>
#include <cstddef>

#define NN 20000
#define NE 640000
#define NF 64
#define HD 256
#define NL 4

typedef __attribute__((ext_vector_type(8))) short short8;
typedef __attribute__((ext_vector_type(4))) float f32x4;

__device__ __forceinline__ float bf2f(unsigned short u){
  union { unsigned int i; float f; } x; x.i = ((unsigned int)u) << 16; return x.f;
}
__device__ __forceinline__ unsigned short f2bf(float f){
  union { float f; unsigned int i; } x; x.f = f;
  unsigned int r = x.i + 0x7FFFu + ((x.i >> 16) & 1u);   // RNE
  return (unsigned short)(r >> 16);
}
__device__ __forceinline__ float silu_f(float v){
  return v * (1.0f / (1.0f + __expf(-v)));
}
__device__ __forceinline__ void async16(const void* g, void* l){
  __builtin_amdgcn_global_load_lds(
      (const __attribute__((address_space(1))) unsigned int*)g,
      (__attribute__((address_space(3))) unsigned int*)l, 16, 0, 0);
}

// ---------------- prep: weight transpose->bf16, h->bf16, radial ----------------
__global__ __launch_bounds__(256) void prep_k(
    const float* __restrict__ h_in, const float* __restrict__ cd,
    const float* __restrict__ w_in, const float* __restrict__ w_out,
    const float* __restrict__ ew1, const float* __restrict__ ew2,
    const float* __restrict__ nw1, const float* __restrict__ nw2,
    unsigned short* __restrict__ w_in_t, unsigned short* __restrict__ w_out_t,
    unsigned short* __restrict__ ew1t, float* __restrict__ w1r,
    unsigned short* __restrict__ ew2t, unsigned short* __restrict__ nw1t,
    unsigned short* __restrict__ nw2t, unsigned short* __restrict__ hb_in,
    float* __restrict__ radial)
{
  const int s = blockIdx.y;
  const int tid = blockIdx.x * 256 + threadIdx.x;
  if (s == 18) {
    if (tid < NN * NF) hb_in[tid] = f2bf(h_in[tid]);
    return;
  }
  if (s == 19) {
    if (tid < NE) {
      float x = cd[tid*3+0], y = cd[tid*3+1], z = cd[tid*3+2];
      radial[tid] = x*x + y*y + z*z;
    }
    return;
  }
  const float* src; unsigned short* dst; int K, N, dstK; float* extra = nullptr;
  if (s == 0)      { src = w_in;  dst = w_in_t;  K = NF;   N = HD; dstK = NF; }
  else if (s == 1) { src = w_out; dst = w_out_t; K = HD;   N = NF; dstK = HD; }
  else if (s < 6)  { int l = s-2;  src = ew1 + (size_t)l*513*HD;  dst = ew1t + (size_t)l*HD*512; K = 513;  N = HD; dstK = 512; extra = w1r + l*HD; }
  else if (s < 10) { int l = s-6;  src = ew2 + (size_t)l*HD*HD;   dst = ew2t + (size_t)l*HD*HD;  K = HD;   N = HD; dstK = HD; }
  else if (s < 14) { int l = s-10; src = nw1 + (size_t)l*2*HD*HD; dst = nw1t + (size_t)l*HD*512; K = 2*HD; N = HD; dstK = 512; }
  else             { int l = s-14; src = nw2 + (size_t)l*HD*HD;   dst = nw2t + (size_t)l*HD*HD;  K = HD;   N = HD; dstK = HD; }
  if (tid >= K * N) return;
  int k = tid / N, n = tid - k * N;
  float v = src[tid];
  if (k >= dstK) { if (extra) extra[n] = v; return; }   // radial row of edge_w1
  dst[(size_t)n * dstK + k] = f2bf(v);
}

// ---------------- CSR build (counting sort of edges by row) ----------------
__global__ __launch_bounds__(256) void hist_k(const int* __restrict__ erow, int* __restrict__ hist){
  int e = blockIdx.x * 256 + threadIdx.x;
  if (e < NE){
    unsigned r = (unsigned)erow[e]; if (r >= NN) r = 0;
    atomicAdd(&hist[r], 1);
  }
}

__global__ __launch_bounds__(256) void scan_k(const int* __restrict__ hist,
                                              int* __restrict__ starts, int* __restrict__ cursor){
  __shared__ int part[256];
  const int t = threadIdx.x;
  const int CH = 79;                 // 256*79 = 20224 >= 20000
  int lo = t * CH, hi = lo + CH; if (hi > NN) hi = NN; if (lo > NN) lo = NN;
  int s = 0;
  for (int i = lo; i < hi; ++i) s += hist[i];
  part[t] = s; __syncthreads();
  for (int off = 1; off < 256; off <<= 1){
    int v = (t >= off) ? part[t - off] : 0;
    __syncthreads();
    part[t] += v;
    __syncthreads();
  }
  int base = (t == 0) ? 0 : part[t - 1];
  for (int i = lo; i < hi; ++i){ starts[i] = base; cursor[i] = base; base += hist[i]; }
  if (t == 255) starts[NN] = part[255];
}

__global__ __launch_bounds__(256) void scatter_k(const int* __restrict__ erow,
                                                 int* __restrict__ cursor, int* __restrict__ sorted){
  int e = blockIdx.x * 256 + threadIdx.x;
  if (e < NE){
    unsigned r = (unsigned)erow[e]; if (r >= NN) r = 0;
    int pos = atomicAdd(&cursor[r], 1);
    sorted[pos] = e;
  }
}

// ---------------- generic 128x128 bf16 MFMA GEMM: out = [silu](A @ Wt^T + bias) ----------------
__global__ __launch_bounds__(256) void gemm_k(
    const unsigned short* __restrict__ Am, const unsigned short* __restrict__ Wt,
    const float* __restrict__ bias,
    unsigned short* __restrict__ outB, float* __restrict__ outF,
    int M, int N, int K, int fuseSilu)
{
  __shared__ __align__(16) unsigned short As[128*32];
  __shared__ __align__(16) unsigned short Bs[128*32];
  const int t = threadIdx.x;
  const int lane = t & 63, wave = t >> 6;
  const int ln15 = lane & 15, q = lane >> 4;
  const int bm = blockIdx.x, bn = blockIdx.y;
  const int wm = wave >> 1, wn = wave & 1;

  f32x4 acc[4][4];
  #pragma unroll
  for (int i = 0; i < 4; ++i)
    #pragma unroll
    for (int j = 0; j < 4; ++j) acc[i][j] = (f32x4){0.f,0.f,0.f,0.f};

  const int sr = t >> 2;
  const int sc = (t & 3) * 8;
  int am0 = bm*128 + sr;      if (am0 > M-1) am0 = M-1;
  int am1 = bm*128 + 64 + sr; if (am1 > M-1) am1 = M-1;
  int an0 = bn*128 + sr;      if (an0 > N-1) an0 = N-1;
  int an1 = bn*128 + 64 + sr; if (an1 > N-1) an1 = N-1;
  const unsigned short* a0 = Am + (size_t)am0 * K + sc;
  const unsigned short* a1 = Am + (size_t)am1 * K + sc;
  const unsigned short* b0 = Wt + (size_t)an0 * K + sc;
  const unsigned short* b1 = Wt + (size_t)an1 * K + sc;

  const int nkt = K >> 5;
  for (int kt = 0; kt < nkt; ++kt) {
    const int k0 = kt * 32;
    async16(a0 + k0, &As[t*8]);
    async16(a1 + k0, &As[2048 + t*8]);
    async16(b0 + k0, &Bs[t*8]);
    async16(b1 + k0, &Bs[2048 + t*8]);
    __syncthreads();
    short8 fa[4], fb[4];
    #pragma unroll
    for (int i = 0; i < 4; ++i)
      fa[i] = *(const short8*)&As[(wm*64 + i*16 + ln15)*32 + q*8];
    #pragma unroll
    for (int j = 0; j < 4; ++j)
      fb[j] = *(const short8*)&Bs[(wn*64 + j*16 + ln15)*32 + q*8];
    #pragma unroll
    for (int i = 0; i < 4; ++i)
      #pragma unroll
      for (int j = 0; j < 4; ++j)
        acc[i][j] = __builtin_amdgcn_mfma_f32_16x16x32_bf16(fa[i], fb[j], acc[i][j], 0, 0, 0);
    __syncthreads();
  }

  #pragma unroll
  for (int i = 0; i < 4; ++i) {
    #pragma unroll
    for (int j = 0; j < 4; ++j) {
      const int n = bn*128 + wn*64 + j*16 + ln15;
      if (n >= N) continue;
      const float bv = bias ? bias[n] : 0.0f;
      #pragma unroll
      for (int r = 0; r < 4; ++r) {
        const int m = bm*128 + wm*64 + i*16 + q*4 + r;
        if (m >= M) continue;
        float v = acc[i][j][r] + bv;
        if (fuseSilu) v = silu_f(v);
        if (outB) outB[(size_t)m * N + n] = f2bf(v);
        else      outF[(size_t)m * N + n] = v;
      }
    }
  }
}

// ---------------- fused edge MLP + aggregation, BM=128 / 512 threads / 8 waves ----------------
// 128 sorted edges per block; full-LDS staging (m97 ratio: 24KB staged per 128 MFMAs);
// M1 in LDS K-tile-blocked [8][128][32], As aliased onto M1's last kt-block;
// run-compressed fp32 atomicAdd into agg.
__global__ __launch_bounds__(512, 2) void edge_k(
    const unsigned short* __restrict__ hb,
    const int* __restrict__ erow, const int* __restrict__ ecol,
    const float* __restrict__ radial, const int* __restrict__ sorted,
    const unsigned short* __restrict__ w1t,  // [256][512]
    const float* __restrict__ b1, const float* __restrict__ w1r,
    const unsigned short* __restrict__ w2t,  // [256][256]
    const float* __restrict__ b2,
    float* __restrict__ agg)                  // [NN][256] fp32, pre-zeroed
{
  __shared__ __align__(16) unsigned short M1[8*4096];    // 64 KB, block kt: [128][32]
  __shared__ __align__(16) unsigned short Bs[8192];      // 16 KB (256 rows x 32 k)
  __shared__ float radS[128];
  __shared__ int   rowS[128];
  unsigned short* As = &M1[7*4096];   // 8 KB alias; dead before epilogue-1 writes M1

  const int t = threadIdx.x;                // 0..511
  const int lane = t & 63, wave = t >> 6;   // 8 waves
  const int ln15 = lane & 15, q = lane >> 4;
  const int wm = wave >> 2, wn = wave & 3;  // 2x4 wave grid: 64 rows x 64 cols each
  const int e0 = blockIdx.x * 128;
  const int ar = t >> 2;                    // staged A-row (edge) 0..127
  const int sc = (t & 3) * 8;               // k-segment within tile

  const int es = sorted[e0 + ar];
  unsigned nr = (unsigned)erow[es]; if (nr >= NN) nr = 0;
  unsigned nc = (unsigned)ecol[es]; if (nc >= NN) nc = 0;
  const int offR = (int)nr * HD + sc;
  const int offC = (int)nc * HD + sc;
  if (t < 128) {
    int e = sorted[e0 + t];
    radS[t] = radial[e];
    unsigned r = (unsigned)erow[e]; if (r >= NN) r = 0;
    rowS[t] = (int)r;
  }

  f32x4 acc[4][4];
  #pragma unroll
  for (int i = 0; i < 4; ++i)
    #pragma unroll
    for (int j = 0; j < 4; ++j) acc[i][j] = (f32x4){0.f,0.f,0.f,0.f};

  // phase 1: K = 512 (h[row] | h[col]) -> acc = [h_r|h_c] @ W1^T
  for (int kt = 0; kt < 16; ++kt) {
    const int k0 = kt * 32;
    const unsigned short* asrc = (kt < 8) ? (hb + offR + k0) : (hb + offC + (k0 - HD));
    async16(asrc, &As[t*8]);
    async16(w1t + (size_t)ar*512 + k0 + sc,         &Bs[t*8]);        // W1 rows 0..127
    async16(w1t + (size_t)(128 + ar)*512 + k0 + sc, &Bs[4096 + t*8]); // W1 rows 128..255
    __syncthreads();
    short8 fa[4], fb[4];
    #pragma unroll
    for (int i = 0; i < 4; ++i) fa[i] = *(const short8*)&As[(wm*64 + i*16 + ln15)*32 + q*8];
    #pragma unroll
    for (int j = 0; j < 4; ++j) fb[j] = *(const short8*)&Bs[(wn*64 + j*16 + ln15)*32 + q*8];
    #pragma unroll
    for (int i = 0; i < 4; ++i)
      #pragma unroll
      for (int j = 0; j < 4; ++j)
        acc[i][j] = __builtin_amdgcn_mfma_f32_16x16x32_bf16(fa[i], fb[j], acc[i][j], 0, 0, 0);
    __syncthreads();
  }

  // epilogue 1: bias + radial rank-1 term + silu -> M1 (bf16, K-tile-blocked)
  #pragma unroll
  for (int i = 0; i < 4; ++i) {
    #pragma unroll
    for (int j = 0; j < 4; ++j) {
      const int n = wn*64 + j*16 + ln15;
      const float bv = b1[n], wr = w1r[n];
      #pragma unroll
      for (int r = 0; r < 4; ++r) {
        const int m = wm*64 + i*16 + q*4 + r;
        float v = acc[i][j][r] + bv + radS[m] * wr;
        M1[(n >> 5)*4096 + m*32 + (n & 31)] = f2bf(silu_f(v));
      }
    }
  }

  // phase 2: K = 256 (M1 @ W2^T)
  f32x4 acc2[4][4];
  #pragma unroll
  for (int i = 0; i < 4; ++i)
    #pragma unroll
    for (int j = 0; j < 4; ++j) acc2[i][j] = (f32x4){0.f,0.f,0.f,0.f};

  for (int kt = 0; kt < 8; ++kt) {
    const int k0 = kt * 32;
    async16(w2t + (size_t)ar*HD + k0 + sc,         &Bs[t*8]);
    async16(w2t + (size_t)(128 + ar)*HD + k0 + sc, &Bs[4096 + t*8]);
    __syncthreads();   // covers epilogue-1 M1 writes (kt=0) + Bs staging
    short8 fa[4], fb[4];
    #pragma unroll
    for (int i = 0; i < 4; ++i) fa[i] = *(const short8*)&M1[kt*4096 + (wm*64 + i*16 + ln15)*32 + q*8];
    #pragma unroll
    for (int j = 0; j < 4; ++j) fb[j] = *(const short8*)&Bs[(wn*64 + j*16 + ln15)*32 + q*8];
    #pragma unroll
    for (int i = 0; i < 4; ++i)
      #pragma unroll
      for (int j = 0; j < 4; ++j)
        acc2[i][j] = __builtin_amdgcn_mfma_f32_16x16x32_bf16(fa[i], fb[j], acc2[i][j], 0, 0, 0);
    __syncthreads();
  }

  // epilogue 2: silu -> run-compressed atomicAdd into agg (sorted rows => runs)
  #pragma unroll
  for (int i = 0; i < 4; ++i) {
    #pragma unroll
    for (int j = 0; j < 4; ++j) {
      const int n = wn*64 + j*16 + ln15;
      const float bv = b2[n];
      const int mb = wm*64 + i*16 + q*4;
      int cur = rowS[mb];
      float s = 0.f;
      #pragma unroll
      for (int r = 0; r < 4; ++r) {
        int node = rowS[mb + r];
        float v = silu_f(acc2[i][j][r] + bv);
        if (node != cur) { atomicAdd(&agg[(size_t)cur * HD + n], s); s = 0.f; cur = node; }
        s += v;
      }
      atomicAdd(&agg[(size_t)cur * HD + n], s);
    }
  }
}

// ---------------- concat: xcat = [h | bf16(agg)] ----------------
__global__ __launch_bounds__(256) void concat_k(
    const unsigned short* __restrict__ h, const float* __restrict__ agg,
    unsigned short* __restrict__ xcat)
{
  const int g = blockIdx.x * 256 + threadIdx.x;   // NN*64 threads, 4 cols each
  const int node = g >> 6;
  const int c = (g & 63) * 4;
  if (node >= NN) return;
  *(ushort4*)(xcat + (size_t)node * 2 * HD + c) =
      *(const ushort4*)(h + (size_t)node * HD + c);
  float4 a = *(const float4*)(agg + (size_t)node * HD + c);
  ushort4 o; o.x = f2bf(a.x); o.y = f2bf(a.y); o.z = f2bf(a.z); o.w = f2bf(a.w);
  *(ushort4*)(xcat + (size_t)node * 2 * HD + HD + c) = o;
}

// ---------------- launch ----------------
extern "C" void kernel_launch(void* const* d_in, const int* in_sizes, int n_in,
                              void* d_out, int out_size, void* d_ws, size_t ws_size,
                              hipStream_t stream)
{
  (void)in_sizes; (void)n_in; (void)out_size; (void)ws_size;
  const float* h_in  = (const float*)d_in[0];
  const int*   ei    = (const int*)d_in[1];
  const float* cd    = (const float*)d_in[2];
  const float* w_in  = (const float*)d_in[3];
  const float* b_in  = (const float*)d_in[4];
  const float* w_out = (const float*)d_in[5];
  const float* b_out = (const float*)d_in[6];
  const float* ew1   = (const float*)d_in[7];
  const float* eb1   = (const float*)d_in[8];
  const float* ew2   = (const float*)d_in[9];
  const float* eb2   = (const float*)d_in[10];
  const float* nw1   = (const float*)d_in[11];
  const float* nb1   = (const float*)d_in[12];
  const float* nw2   = (const float*)d_in[13];
  const float* nb2   = (const float*)d_in[14];
  float* out = (float*)d_out;

  char* base = (char*)d_ws;
  size_t off = 0;
  auto WS = [&](size_t bytes) -> char* {
    char* p = base + off;
    off = (off + bytes + 255) & ~(size_t)255;
    return p;
  };
  float*          radial  = (float*)WS((size_t)NE * 4);
  unsigned short* hb_in   = (unsigned short*)WS((size_t)NN * NF * 2);
  unsigned short* hcur    = (unsigned short*)WS((size_t)NN * HD * 2);
  unsigned short* xcat    = (unsigned short*)WS((size_t)NN * 2 * HD * 2);
  float*          aggF    = (float*)WS((size_t)NN * HD * 4);
  unsigned short* x1      = (unsigned short*)aggF;   // alias: agg dead when x1 live
  unsigned short* w_in_t  = (unsigned short*)WS((size_t)NF * HD * 2);
  unsigned short* w_out_t = (unsigned short*)WS((size_t)NF * HD * 2);
  unsigned short* ew1t    = (unsigned short*)WS((size_t)NL * HD * 512 * 2);
  float*          w1r     = (float*)WS((size_t)NL * HD * 4);
  unsigned short* ew2t    = (unsigned short*)WS((size_t)NL * HD * HD * 2);
  unsigned short* nw1t    = (unsigned short*)WS((size_t)NL * HD * 512 * 2);
  unsigned short* nw2t    = (unsigned short*)WS((size_t)NL * HD * HD * 2);
  int*            hist    = (int*)WS((size_t)NN * 4);
  int*            starts  = (int*)WS((size_t)(NN + 1) * 4);
  int*            cursor  = (int*)WS((size_t)NN * 4);
  int*            sorted  = (int*)WS((size_t)NE * 4);

  hipMemsetAsync(hist, 0, (size_t)NN * 4, stream);
  prep_k<<<dim3(5000, 20, 1), 256, 0, stream>>>(h_in, cd, w_in, w_out, ew1, ew2, nw1, nw2,
      w_in_t, w_out_t, ew1t, w1r, ew2t, nw1t, nw2t, hb_in, radial);
  hist_k<<<NE / 256, 256, 0, stream>>>(ei, hist);
  scan_k<<<1, 256, 0, stream>>>(hist, starts, cursor);
  scatter_k<<<NE / 256, 256, 0, stream>>>(ei, cursor, sorted);

  // h = h_in @ w_in + b_in
  gemm_k<<<dim3(157, 2), 256, 0, stream>>>(hb_in, w_in_t, b_in, hcur, nullptr, NN, HD, NF, 0);

  for (int l = 0; l < NL; ++l) {
    hipMemsetAsync(aggF, 0, (size_t)NN * HD * 4, stream);
    edge_k<<<NE / 128, 512, 0, stream>>>(hcur, ei, ei + NE, radial, sorted,
        ew1t + (size_t)l * HD * 512, eb1 + l * HD, w1r + l * HD,
        ew2t + (size_t)l * HD * HD, eb2 + l * HD, aggF);
    concat_k<<<NN * 64 / 256, 256, 0, stream>>>(hcur, aggF, xcat);
    gemm_k<<<dim3(157, 2), 256, 0, stream>>>(xcat, nw1t + (size_t)l * HD * 512,
        nb1 + l * HD, x1, nullptr, NN, HD, 2 * HD, 1);
    gemm_k<<<dim3(157, 2), 256, 0, stream>>>(x1, nw2t + (size_t)l * HD * HD,
        nb2 + l * HD, hcur, nullptr, NN, HD, HD, 0);
  }

  // out = h @ w_out + b_out  (fp32 output)
  gemm_k<<<dim3(157, 1), 256, 0, stream>>>(hcur, w_out_t, b_out, nullptr, out, NN, NF, HD, 0);
}

// Round 7
// 2505.388 us; speedup vs baseline: 1.5338x; 1.5228x over previous
//
#include <hip/hip_runtime.h>
#include <cstdint>
#include <cstddef>

#define NN 20000
#define NE 640000
#define NF 64
#define HD 256
#define NL 4

typedef __attribute__((ext_vector_type(8))) short short8;
typedef __attribute__((ext_vector_type(4))) float f32x4;

__device__ __forceinline__ float bf2f(unsigned short u){
  union { unsigned int i; float f; } x; x.i = ((unsigned int)u) << 16; return x.f;
}
__device__ __forceinline__ unsigned short f2bf(float f){
  union { float f; unsigned int i; } x; x.f = f;
  unsigned int r = x.i + 0x7FFFu + ((x.i >> 16) & 1u);   // RNE
  return (unsigned short)(r >> 16);
}
__device__ __forceinline__ float silu_f(float v){
  return v * (1.0f / (1.0f + __expf(-v)));
}
__device__ __forceinline__ void async16(const void* g, void* l){
  __builtin_amdgcn_global_load_lds(
      (const __attribute__((address_space(1))) unsigned int*)g,
      (__attribute__((address_space(3))) unsigned int*)l, 16, 0, 0);
}

// ---------------- prep: weight transpose->bf16, h->bf16, radial ----------------
__global__ __launch_bounds__(256) void prep_k(
    const float* __restrict__ h_in, const float* __restrict__ cd,
    const float* __restrict__ w_in, const float* __restrict__ w_out,
    const float* __restrict__ ew1, const float* __restrict__ ew2,
    const float* __restrict__ nw1, const float* __restrict__ nw2,
    unsigned short* __restrict__ w_in_t, unsigned short* __restrict__ w_out_t,
    unsigned short* __restrict__ ew1t, float* __restrict__ w1r,
    unsigned short* __restrict__ ew2t, unsigned short* __restrict__ nw1t,
    unsigned short* __restrict__ nw2t, unsigned short* __restrict__ hb_in,
    float* __restrict__ radial)
{
  const int s = blockIdx.y;
  const int tid = blockIdx.x * 256 + threadIdx.x;
  if (s == 18) {
    if (tid < NN * NF) hb_in[tid] = f2bf(h_in[tid]);
    return;
  }
  if (s == 19) {
    if (tid < NE) {
      float x = cd[tid*3+0], y = cd[tid*3+1], z = cd[tid*3+2];
      radial[tid] = x*x + y*y + z*z;
    }
    return;
  }
  const float* src; unsigned short* dst; int K, N, dstK; float* extra = nullptr;
  if (s == 0)      { src = w_in;  dst = w_in_t;  K = NF;   N = HD; dstK = NF; }
  else if (s == 1) { src = w_out; dst = w_out_t; K = HD;   N = NF; dstK = HD; }
  else if (s < 6)  { int l = s-2;  src = ew1 + (size_t)l*513*HD;  dst = ew1t + (size_t)l*HD*512; K = 513;  N = HD; dstK = 512; extra = w1r + l*HD; }
  else if (s < 10) { int l = s-6;  src = ew2 + (size_t)l*HD*HD;   dst = ew2t + (size_t)l*HD*HD;  K = HD;   N = HD; dstK = HD; }
  else if (s < 14) { int l = s-10; src = nw1 + (size_t)l*2*HD*HD; dst = nw1t + (size_t)l*HD*512; K = 2*HD; N = HD; dstK = 512; }
  else             { int l = s-14; src = nw2 + (size_t)l*HD*HD;   dst = nw2t + (size_t)l*HD*HD;  K = HD;   N = HD; dstK = HD; }
  if (tid >= K * N) return;
  int k = tid / N, n = tid - k * N;
  float v = src[tid];
  if (k >= dstK) { if (extra) extra[n] = v; return; }   // radial row of edge_w1
  dst[(size_t)n * dstK + k] = f2bf(v);
}

// ---------------- CSR build (counting sort of edges by row) ----------------
__global__ __launch_bounds__(256) void hist_k(const int* __restrict__ erow, int* __restrict__ hist){
  int e = blockIdx.x * 256 + threadIdx.x;
  if (e < NE){
    unsigned r = (unsigned)erow[e]; if (r >= NN) r = 0;
    atomicAdd(&hist[r], 1);
  }
}

__global__ __launch_bounds__(256) void scan_k(const int* __restrict__ hist,
                                              int* __restrict__ starts, int* __restrict__ cursor){
  __shared__ int part[256];
  const int t = threadIdx.x;
  const int CH = 79;                 // 256*79 = 20224 >= 20000
  int lo = t * CH, hi = lo + CH; if (hi > NN) hi = NN; if (lo > NN) lo = NN;
  int s = 0;
  for (int i = lo; i < hi; ++i) s += hist[i];
  part[t] = s; __syncthreads();
  for (int off = 1; off < 256; off <<= 1){
    int v = (t >= off) ? part[t - off] : 0;
    __syncthreads();
    part[t] += v;
    __syncthreads();
  }
  int base = (t == 0) ? 0 : part[t - 1];
  for (int i = lo; i < hi; ++i){ starts[i] = base; cursor[i] = base; base += hist[i]; }
  if (t == 255) starts[NN] = part[255];
}

__global__ __launch_bounds__(256) void scatter_k(const int* __restrict__ erow,
                                                 int* __restrict__ cursor, int* __restrict__ sorted){
  int e = blockIdx.x * 256 + threadIdx.x;
  if (e < NE){
    unsigned r = (unsigned)erow[e]; if (r >= NN) r = 0;
    int pos = atomicAdd(&cursor[r], 1);
    sorted[pos] = e;
  }
}

// ---------------- generic 128x128 bf16 MFMA GEMM: out = [silu](A @ Wt^T + bias) ----------------
__global__ __launch_bounds__(256) void gemm_k(
    const unsigned short* __restrict__ Am, const unsigned short* __restrict__ Wt,
    const float* __restrict__ bias,
    unsigned short* __restrict__ outB, float* __restrict__ outF,
    int M, int N, int K, int fuseSilu)
{
  __shared__ __align__(16) unsigned short As[128*32];
  __shared__ __align__(16) unsigned short Bs[128*32];
  const int t = threadIdx.x;
  const int lane = t & 63, wave = t >> 6;
  const int ln15 = lane & 15, q = lane >> 4;
  const int bm = blockIdx.x, bn = blockIdx.y;
  const int wm = wave >> 1, wn = wave & 1;

  f32x4 acc[4][4];
  #pragma unroll
  for (int i = 0; i < 4; ++i)
    #pragma unroll
    for (int j = 0; j < 4; ++j) acc[i][j] = (f32x4){0.f,0.f,0.f,0.f};

  const int sr = t >> 2;
  const int sc = (t & 3) * 8;
  int am0 = bm*128 + sr;      if (am0 > M-1) am0 = M-1;
  int am1 = bm*128 + 64 + sr; if (am1 > M-1) am1 = M-1;
  int an0 = bn*128 + sr;      if (an0 > N-1) an0 = N-1;
  int an1 = bn*128 + 64 + sr; if (an1 > N-1) an1 = N-1;
  const unsigned short* a0 = Am + (size_t)am0 * K + sc;
  const unsigned short* a1 = Am + (size_t)am1 * K + sc;
  const unsigned short* b0 = Wt + (size_t)an0 * K + sc;
  const unsigned short* b1 = Wt + (size_t)an1 * K + sc;

  const int nkt = K >> 5;
  for (int kt = 0; kt < nkt; ++kt) {
    const int k0 = kt * 32;
    async16(a0 + k0, &As[t*8]);
    async16(a1 + k0, &As[2048 + t*8]);
    async16(b0 + k0, &Bs[t*8]);
    async16(b1 + k0, &Bs[2048 + t*8]);
    __syncthreads();
    short8 fa[4], fb[4];
    #pragma unroll
    for (int i = 0; i < 4; ++i)
      fa[i] = *(const short8*)&As[(wm*64 + i*16 + ln15)*32 + q*8];
    #pragma unroll
    for (int j = 0; j < 4; ++j)
      fb[j] = *(const short8*)&Bs[(wn*64 + j*16 + ln15)*32 + q*8];
    #pragma unroll
    for (int i = 0; i < 4; ++i)
      #pragma unroll
      for (int j = 0; j < 4; ++j)
        acc[i][j] = __builtin_amdgcn_mfma_f32_16x16x32_bf16(fa[i], fb[j], acc[i][j], 0, 0, 0);
    __syncthreads();
  }

  #pragma unroll
  for (int i = 0; i < 4; ++i) {
    #pragma unroll
    for (int j = 0; j < 4; ++j) {
      const int n = bn*128 + wn*64 + j*16 + ln15;
      if (n >= N) continue;
      const float bv = bias ? bias[n] : 0.0f;
      #pragma unroll
      for (int r = 0; r < 4; ++r) {
        const int m = bm*128 + wm*64 + i*16 + q*4 + r;
        if (m >= M) continue;
        float v = acc[i][j][r] + bv;
        if (fuseSilu) v = silu_f(v);
        if (outB) outB[(size_t)m * N + n] = f2bf(v);
        else      outF[(size_t)m * N + n] = v;
      }
    }
  }
}

// ---------------- fused edge MLP + aggregation (R2 structure + LDS-compressed atomics) ----
// 64 sorted edges per block; m1 in LDS; epilogue: m2 -> transposed LDS, per-column
// segmented reduction over sorted rows, ~3 coalesced atomics per column per block.
__global__ __launch_bounds__(256) void edge_k(
    const unsigned short* __restrict__ hb,
    const int* __restrict__ erow, const int* __restrict__ ecol,
    const float* __restrict__ radial, const int* __restrict__ sorted,
    const unsigned short* __restrict__ w1t,  // [256][512]
    const float* __restrict__ b1, const float* __restrict__ w1r,
    const unsigned short* __restrict__ w2t,  // [256][256]
    const float* __restrict__ b2,
    float* __restrict__ agg)                  // [NN][256] fp32, pre-zeroed
{
  __shared__ __align__(16) unsigned short As[64*32];     //  4 KB
  __shared__ __align__(16) unsigned short Bs[256*32];    // 16 KB
  // MBUF serves two lives (separated by barriers):
  //  - M1 [64 rows][stride 264]  (33,792 shorts-bytes... 16,896 shorts)
  //  - m2T [256 cols][stride 68] (17,408 shorts)  -- written after last phase-2 read
  __shared__ __align__(16) unsigned short MBUF[17408];   // 34 KB
  __shared__ float radS[64];
  __shared__ int   rowS[64];
  unsigned short* M1  = MBUF;
  unsigned short* m2T = MBUF;

  const int t = threadIdx.x;
  const int lane = t & 63, wave = t >> 6;
  const int ln15 = lane & 15, q = lane >> 4;
  const int e0 = blockIdx.x * 64;
  const int sr = t >> 2;
  const int sc = (t & 3) * 8;

  const int es = sorted[e0 + sr];
  unsigned nr = (unsigned)erow[es]; if (nr >= NN) nr = 0;
  unsigned nc = (unsigned)ecol[es]; if (nc >= NN) nc = 0;
  const unsigned short* aR = hb + (size_t)nr * HD + sc;
  const unsigned short* aC = hb + (size_t)nc * HD + sc;
  if (t < 64) {
    int e = sorted[e0 + t];
    radS[t] = radial[e];
    unsigned r = (unsigned)erow[e]; if (r >= NN) r = 0;
    rowS[t] = (int)r;
  }

  f32x4 acc[4][4];
  #pragma unroll
  for (int i = 0; i < 4; ++i)
    #pragma unroll
    for (int j = 0; j < 4; ++j) acc[i][j] = (f32x4){0.f,0.f,0.f,0.f};

  // phase 1: K = 512 (h[row] | h[col])
  for (int kt = 0; kt < 16; ++kt) {
    const int k0 = kt * 32;
    const unsigned short* as = (k0 < HD) ? (aR + k0) : (aC + (k0 - HD));
    async16(as, &As[t*8]);
    #pragma unroll
    for (int p = 0; p < 4; ++p)
      async16(w1t + (size_t)(p*64 + sr)*512 + k0 + sc, &Bs[p*2048 + t*8]);
    __syncthreads();
    short8 fa[4], fb[4];
    #pragma unroll
    for (int i = 0; i < 4; ++i) fa[i] = *(const short8*)&As[(i*16 + ln15)*32 + q*8];
    #pragma unroll
    for (int j = 0; j < 4; ++j) fb[j] = *(const short8*)&Bs[(wave*64 + j*16 + ln15)*32 + q*8];
    #pragma unroll
    for (int i = 0; i < 4; ++i)
      #pragma unroll
      for (int j = 0; j < 4; ++j)
        acc[i][j] = __builtin_amdgcn_mfma_f32_16x16x32_bf16(fa[i], fb[j], acc[i][j], 0, 0, 0);
    __syncthreads();
  }

  // epilogue 1: bias + radial rank-1 term + silu -> M1 (bf16, LDS, stride 264)
  #pragma unroll
  for (int i = 0; i < 4; ++i) {
    #pragma unroll
    for (int j = 0; j < 4; ++j) {
      const int n = wave*64 + j*16 + ln15;
      const float bv = b1[n], wr = w1r[n];
      #pragma unroll
      for (int r = 0; r < 4; ++r) {
        const int m = i*16 + q*4 + r;
        float v = acc[i][j][r] + bv + radS[m] * wr;
        M1[m*264 + n] = f2bf(silu_f(v));
      }
    }
  }
  __syncthreads();

  // phase 2: K = 256 (M1 @ W2)
  f32x4 acc2[4][4];
  #pragma unroll
  for (int i = 0; i < 4; ++i)
    #pragma unroll
    for (int j = 0; j < 4; ++j) acc2[i][j] = (f32x4){0.f,0.f,0.f,0.f};

  for (int kt = 0; kt < 8; ++kt) {
    const int k0 = kt * 32;
    #pragma unroll
    for (int p = 0; p < 4; ++p)
      async16(w2t + (size_t)(p*64 + sr)*HD + k0 + sc, &Bs[p*2048 + t*8]);
    __syncthreads();
    short8 fa[4], fb[4];
    #pragma unroll
    for (int i = 0; i < 4; ++i) fa[i] = *(const short8*)&M1[(i*16 + ln15)*264 + k0 + q*8];
    #pragma unroll
    for (int j = 0; j < 4; ++j) fb[j] = *(const short8*)&Bs[(wave*64 + j*16 + ln15)*32 + q*8];
    #pragma unroll
    for (int i = 0; i < 4; ++i)
      #pragma unroll
      for (int j = 0; j < 4; ++j)
        acc2[i][j] = __builtin_amdgcn_mfma_f32_16x16x32_bf16(fa[i], fb[j], acc2[i][j], 0, 0, 0);
    __syncthreads();   // last iteration: all M1/Bs reads done -> MBUF reusable as m2T
  }

  // epilogue 2a: silu -> m2T[col][row] (bf16, stride 68) in LDS
  #pragma unroll
  for (int i = 0; i < 4; ++i) {
    #pragma unroll
    for (int j = 0; j < 4; ++j) {
      const int n = wave*64 + j*16 + ln15;
      const float bv = b2[n];
      ushort4 o;
      o.x = f2bf(silu_f(acc2[i][j][0] + bv));
      o.y = f2bf(silu_f(acc2[i][j][1] + bv));
      o.z = f2bf(silu_f(acc2[i][j][2] + bv));
      o.w = f2bf(silu_f(acc2[i][j][3] + bv));
      const int m = i*16 + q*4;
      *(ushort4*)&m2T[n*68 + m] = o;   // byte addr 136n+2m, m%4==0 -> 8B aligned
    }
  }
  __syncthreads();

  // epilogue 2b: per-column segmented reduction over sorted rows -> few coalesced atomics
  {
    const int c = t;                   // 256 threads = 256 columns
    int cur = rowS[0];
    float s = 0.f;
    #pragma unroll
    for (int m = 0; m < 64; m += 4) {
      ushort4 v = *(const ushort4*)&m2T[c*68 + m];
      int n0 = rowS[m], n1 = rowS[m+1], n2 = rowS[m+2], n3 = rowS[m+3];
      float f0 = bf2f(v.x), f1 = bf2f(v.y), f2v = bf2f(v.z), f3 = bf2f(v.w);
      if (n0 != cur) { atomicAdd(&agg[(size_t)cur * HD + c], s); s = 0.f; cur = n0; }
      s += f0;
      if (n1 != cur) { atomicAdd(&agg[(size_t)cur * HD + c], s); s = 0.f; cur = n1; }
      s += f1;
      if (n2 != cur) { atomicAdd(&agg[(size_t)cur * HD + c], s); s = 0.f; cur = n2; }
      s += f2v;
      if (n3 != cur) { atomicAdd(&agg[(size_t)cur * HD + c], s); s = 0.f; cur = n3; }
      s += f3;
    }
    atomicAdd(&agg[(size_t)cur * HD + c], s);
  }
}

// ---------------- concat: xcat = [h | bf16(agg)] ----------------
__global__ __launch_bounds__(256) void concat_k(
    const unsigned short* __restrict__ h, const float* __restrict__ agg,
    unsigned short* __restrict__ xcat)
{
  const int g = blockIdx.x * 256 + threadIdx.x;   // NN*64 threads, 4 cols each
  const int node = g >> 6;
  const int c = (g & 63) * 4;
  if (node >= NN) return;
  *(ushort4*)(xcat + (size_t)node * 2 * HD + c) =
      *(const ushort4*)(h + (size_t)node * HD + c);
  float4 a = *(const float4*)(agg + (size_t)node * HD + c);
  ushort4 o; o.x = f2bf(a.x); o.y = f2bf(a.y); o.z = f2bf(a.z); o.w = f2bf(a.w);
  *(ushort4*)(xcat + (size_t)node * 2 * HD + HD + c) = o;
}

// ---------------- launch ----------------
extern "C" void kernel_launch(void* const* d_in, const int* in_sizes, int n_in,
                              void* d_out, int out_size, void* d_ws, size_t ws_size,
                              hipStream_t stream)
{
  (void)in_sizes; (void)n_in; (void)out_size; (void)ws_size;
  const float* h_in  = (const float*)d_in[0];
  const int*   ei    = (const int*)d_in[1];
  const float* cd    = (const float*)d_in[2];
  const float* w_in  = (const float*)d_in[3];
  const float* b_in  = (const float*)d_in[4];
  const float* w_out = (const float*)d_in[5];
  const float* b_out = (const float*)d_in[6];
  const float* ew1   = (const float*)d_in[7];
  const float* eb1   = (const float*)d_in[8];
  const float* ew2   = (const float*)d_in[9];
  const float* eb2   = (const float*)d_in[10];
  const float* nw1   = (const float*)d_in[11];
  const float* nb1   = (const float*)d_in[12];
  const float* nw2   = (const float*)d_in[13];
  const float* nb2   = (const float*)d_in[14];
  float* out = (float*)d_out;

  char* base = (char*)d_ws;
  size_t off = 0;
  auto WS = [&](size_t bytes) -> char* {
    char* p = base + off;
    off = (off + bytes + 255) & ~(size_t)255;
    return p;
  };
  float*          radial  = (float*)WS((size_t)NE * 4);
  unsigned short* hb_in   = (unsigned short*)WS((size_t)NN * NF * 2);
  unsigned short* hcur    = (unsigned short*)WS((size_t)NN * HD * 2);
  unsigned short* xcat    = (unsigned short*)WS((size_t)NN * 2 * HD * 2);
  float*          aggF    = (float*)WS((size_t)NN * HD * 4);
  unsigned short* x1      = (unsigned short*)aggF;   // alias: agg dead when x1 live
  unsigned short* w_in_t  = (unsigned short*)WS((size_t)NF * HD * 2);
  unsigned short* w_out_t = (unsigned short*)WS((size_t)NF * HD * 2);
  unsigned short* ew1t    = (unsigned short*)WS((size_t)NL * HD * 512 * 2);
  float*          w1r     = (float*)WS((size_t)NL * HD * 4);
  unsigned short* ew2t    = (unsigned short*)WS((size_t)NL * HD * HD * 2);
  unsigned short* nw1t    = (unsigned short*)WS((size_t)NL * HD * 512 * 2);
  unsigned short* nw2t    = (unsigned short*)WS((size_t)NL * HD * HD * 2);
  int*            hist    = (int*)WS((size_t)NN * 4);
  int*            starts  = (int*)WS((size_t)(NN + 1) * 4);
  int*            cursor  = (int*)WS((size_t)NN * 4);
  int*            sorted  = (int*)WS((size_t)NE * 4);

  hipMemsetAsync(hist, 0, (size_t)NN * 4, stream);
  prep_k<<<dim3(5000, 20, 1), 256, 0, stream>>>(h_in, cd, w_in, w_out, ew1, ew2, nw1, nw2,
      w_in_t, w_out_t, ew1t, w1r, ew2t, nw1t, nw2t, hb_in, radial);
  hist_k<<<NE / 256, 256, 0, stream>>>(ei, hist);
  scan_k<<<1, 256, 0, stream>>>(hist, starts, cursor);
  scatter_k<<<NE / 256, 256, 0, stream>>>(ei, cursor, sorted);

  // h = h_in @ w_in + b_in
  gemm_k<<<dim3(157, 2), 256, 0, stream>>>(hb_in, w_in_t, b_in, hcur, nullptr, NN, HD, NF, 0);

  for (int l = 0; l < NL; ++l) {
    hipMemsetAsync(aggF, 0, (size_t)NN * HD * 4, stream);
    edge_k<<<NE / 64, 256, 0, stream>>>(hcur, ei, ei + NE, radial, sorted,
        ew1t + (size_t)l * HD * 512, eb1 + l * HD, w1r + l * HD,
        ew2t + (size_t)l * HD * HD, eb2 + l * HD, aggF);
    concat_k<<<NN * 64 / 256, 256, 0, stream>>>(hcur, aggF, xcat);
    gemm_k<<<dim3(157, 2), 256, 0, stream>>>(xcat, nw1t + (size_t)l * HD * 512,
        nb1 + l * HD, x1, nullptr, NN, HD, 2 * HD, 1);
    gemm_k<<<dim3(157, 2), 256, 0, stream>>>(x1, nw2t + (size_t)l * HD * HD,
        nb2 + l * HD, hcur, nullptr, NN, HD, HD, 0);
  }

  // out = h @ w_out + b_out  (fp32 output)
  gemm_k<<<dim3(157, 1), 256, 0, stream>>>(hcur, w_out_t, b_out, nullptr, out, NN, NF, HD, 0);
}

// Round 8
// 2395.516 us; speedup vs baseline: 1.6042x; 1.0459x over previous
//
#include <hip/hip_runtime.h>
#include <hip/hip_bf16.h>
#include <cstdint>
#include <cstddef>

#define NN 20000
#define NE 640000
#define NF 64
#define HD 256
#define NL 4

typedef __attribute__((ext_vector_type(8))) short short8;
typedef __attribute__((ext_vector_type(4))) float f32x4;

__device__ __forceinline__ float bf2f(unsigned short u){
  union { unsigned int i; float f; } x; x.i = ((unsigned int)u) << 16; return x.f;
}
__device__ __forceinline__ unsigned short f2bf(float f){
  union { float f; unsigned int i; } x; x.f = f;
  unsigned int r = x.i + 0x7FFFu + ((x.i >> 16) & 1u);   // RNE
  return (unsigned short)(r >> 16);
}
// packed 2xf32 -> 2xbf16 (v_cvt_pk_bf16_f32 on gfx950, RNE)
__device__ __forceinline__ unsigned int pk2bf(float a, float b){
  union { __hip_bfloat162 h; unsigned int u; } cv;
  cv.h = __float22bfloat162_rn(float2{a, b});
  return cv.u;
}
__device__ __forceinline__ float silu_f(float v){
  return v * (1.0f / (1.0f + __expf(-v)));
}
__device__ __forceinline__ void async16(const void* g, void* l){
  __builtin_amdgcn_global_load_lds(
      (const __attribute__((address_space(1))) unsigned int*)g,
      (__attribute__((address_space(3))) unsigned int*)l, 16, 0, 0);
}

// ---------------- prep: weight transpose->bf16, h->bf16, radial ----------------
__global__ __launch_bounds__(256) void prep_k(
    const float* __restrict__ h_in, const float* __restrict__ cd,
    const float* __restrict__ w_in, const float* __restrict__ w_out,
    const float* __restrict__ ew1, const float* __restrict__ ew2,
    const float* __restrict__ nw1, const float* __restrict__ nw2,
    unsigned short* __restrict__ w_in_t, unsigned short* __restrict__ w_out_t,
    unsigned short* __restrict__ ew1t, float* __restrict__ w1r,
    unsigned short* __restrict__ ew2t, unsigned short* __restrict__ nw1t,
    unsigned short* __restrict__ nw2t, unsigned short* __restrict__ hb_in,
    float* __restrict__ radial)
{
  const int s = blockIdx.y;
  const int tid = blockIdx.x * 256 + threadIdx.x;
  if (s == 18) {
    if (tid < NN * NF) hb_in[tid] = f2bf(h_in[tid]);
    return;
  }
  if (s == 19) {
    if (tid < NE) {
      float x = cd[tid*3+0], y = cd[tid*3+1], z = cd[tid*3+2];
      radial[tid] = x*x + y*y + z*z;
    }
    return;
  }
  const float* src; unsigned short* dst; int K, N, dstK; float* extra = nullptr;
  if (s == 0)      { src = w_in;  dst = w_in_t;  K = NF;   N = HD; dstK = NF; }
  else if (s == 1) { src = w_out; dst = w_out_t; K = HD;   N = NF; dstK = HD; }
  else if (s < 6)  { int l = s-2;  src = ew1 + (size_t)l*513*HD;  dst = ew1t + (size_t)l*HD*512; K = 513;  N = HD; dstK = 512; extra = w1r + l*HD; }
  else if (s < 10) { int l = s-6;  src = ew2 + (size_t)l*HD*HD;   dst = ew2t + (size_t)l*HD*HD;  K = HD;   N = HD; dstK = HD; }
  else if (s < 14) { int l = s-10; src = nw1 + (size_t)l*2*HD*HD; dst = nw1t + (size_t)l*HD*512; K = 2*HD; N = HD; dstK = 512; }
  else             { int l = s-14; src = nw2 + (size_t)l*HD*HD;   dst = nw2t + (size_t)l*HD*HD;  K = HD;   N = HD; dstK = HD; }
  if (tid >= K * N) return;
  int k = tid / N, n = tid - k * N;
  float v = src[tid];
  if (k >= dstK) { if (extra) extra[n] = v; return; }   // radial row of edge_w1
  dst[(size_t)n * dstK + k] = f2bf(v);
}

// ---------------- CSR build (counting sort of edges by row) ----------------
__global__ __launch_bounds__(256) void hist_k(const int* __restrict__ erow, int* __restrict__ hist){
  int e = blockIdx.x * 256 + threadIdx.x;
  if (e < NE){
    unsigned r = (unsigned)erow[e]; if (r >= NN) r = 0;
    atomicAdd(&hist[r], 1);
  }
}

__global__ __launch_bounds__(256) void scan_k(const int* __restrict__ hist,
                                              int* __restrict__ starts, int* __restrict__ cursor){
  __shared__ int part[256];
  const int t = threadIdx.x;
  const int CH = 79;                 // 256*79 = 20224 >= 20000
  int lo = t * CH, hi = lo + CH; if (hi > NN) hi = NN; if (lo > NN) lo = NN;
  int s = 0;
  for (int i = lo; i < hi; ++i) s += hist[i];
  part[t] = s; __syncthreads();
  for (int off = 1; off < 256; off <<= 1){
    int v = (t >= off) ? part[t - off] : 0;
    __syncthreads();
    part[t] += v;
    __syncthreads();
  }
  int base = (t == 0) ? 0 : part[t - 1];
  for (int i = lo; i < hi; ++i){ starts[i] = base; cursor[i] = base; base += hist[i]; }
  if (t == 255) starts[NN] = part[255];
}

__global__ __launch_bounds__(256) void scatter_k(const int* __restrict__ erow,
                                                 int* __restrict__ cursor, int* __restrict__ sorted){
  int e = blockIdx.x * 256 + threadIdx.x;
  if (e < NE){
    unsigned r = (unsigned)erow[e]; if (r >= NN) r = 0;
    int pos = atomicAdd(&cursor[r], 1);
    sorted[pos] = e;
  }
}

// ---------------- generic 128x128 bf16 MFMA GEMM: out = [silu](A @ Wt^T + bias) ----------------
__global__ __launch_bounds__(256) void gemm_k(
    const unsigned short* __restrict__ Am, const unsigned short* __restrict__ Wt,
    const float* __restrict__ bias,
    unsigned short* __restrict__ outB, float* __restrict__ outF,
    int M, int N, int K, int fuseSilu)
{
  __shared__ __align__(16) unsigned short As[128*32];
  __shared__ __align__(16) unsigned short Bs[128*32];
  const int t = threadIdx.x;
  const int lane = t & 63, wave = t >> 6;
  const int ln15 = lane & 15, q = lane >> 4;
  const int bm = blockIdx.x, bn = blockIdx.y;
  const int wm = wave >> 1, wn = wave & 1;

  f32x4 acc[4][4];
  #pragma unroll
  for (int i = 0; i < 4; ++i)
    #pragma unroll
    for (int j = 0; j < 4; ++j) acc[i][j] = (f32x4){0.f,0.f,0.f,0.f};

  const int sr = t >> 2;
  const int sc = (t & 3) * 8;
  int am0 = bm*128 + sr;      if (am0 > M-1) am0 = M-1;
  int am1 = bm*128 + 64 + sr; if (am1 > M-1) am1 = M-1;
  int an0 = bn*128 + sr;      if (an0 > N-1) an0 = N-1;
  int an1 = bn*128 + 64 + sr; if (an1 > N-1) an1 = N-1;
  const unsigned short* a0 = Am + (size_t)am0 * K + sc;
  const unsigned short* a1 = Am + (size_t)am1 * K + sc;
  const unsigned short* b0 = Wt + (size_t)an0 * K + sc;
  const unsigned short* b1 = Wt + (size_t)an1 * K + sc;

  const int nkt = K >> 5;
  for (int kt = 0; kt < nkt; ++kt) {
    const int k0 = kt * 32;
    async16(a0 + k0, &As[t*8]);
    async16(a1 + k0, &As[2048 + t*8]);
    async16(b0 + k0, &Bs[t*8]);
    async16(b1 + k0, &Bs[2048 + t*8]);
    __syncthreads();
    short8 fa[4], fb[4];
    #pragma unroll
    for (int i = 0; i < 4; ++i)
      fa[i] = *(const short8*)&As[(wm*64 + i*16 + ln15)*32 + q*8];
    #pragma unroll
    for (int j = 0; j < 4; ++j)
      fb[j] = *(const short8*)&Bs[(wn*64 + j*16 + ln15)*32 + q*8];
    #pragma unroll
    for (int i = 0; i < 4; ++i)
      #pragma unroll
      for (int j = 0; j < 4; ++j)
        acc[i][j] = __builtin_amdgcn_mfma_f32_16x16x32_bf16(fa[i], fb[j], acc[i][j], 0, 0, 0);
    __syncthreads();
  }

  #pragma unroll
  for (int i = 0; i < 4; ++i) {
    #pragma unroll
    for (int j = 0; j < 4; ++j) {
      const int n = bn*128 + wn*64 + j*16 + ln15;
      if (n >= N) continue;
      const float bv = bias ? bias[n] : 0.0f;
      #pragma unroll
      for (int r = 0; r < 4; ++r) {
        const int m = bm*128 + wm*64 + i*16 + q*4 + r;
        if (m >= M) continue;
        float v = acc[i][j][r] + bv;
        if (fuseSilu) v = silu_f(v);
        if (outB) outB[(size_t)m * N + n] = f2bf(v);
        else      outF[(size_t)m * N + n] = v;
      }
    }
  }
}

// ---------------- fused edge MLP + aggregation (R7 + kt-blocked M1 + packed cvt) ----
// 64 sorted edges per block; m1 in LDS (kt-blocked [8][64][32]); epilogue: m2 ->
// transposed LDS, per-column segmented reduction, few coalesced atomics per block.
__global__ __launch_bounds__(256) void edge_k(
    const unsigned short* __restrict__ hb,
    const int* __restrict__ erow, const int* __restrict__ ecol,
    const float* __restrict__ radial, const int* __restrict__ sorted,
    const unsigned short* __restrict__ w1t,  // [256][512]
    const float* __restrict__ b1, const float* __restrict__ w1r,
    const unsigned short* __restrict__ w2t,  // [256][256]
    const float* __restrict__ b2,
    float* __restrict__ agg)                  // [NN][256] fp32, pre-zeroed
{
  __shared__ __align__(16) unsigned short As[64*32];     //  4 KB
  __shared__ __align__(16) unsigned short Bs[256*32];    // 16 KB
  // MBUF serves two lives (separated by barriers):
  //  - M1 kt-blocked [8][64][32] (16384 shorts)
  //  - m2T [256 cols][stride 68] (17408 shorts) -- written after last phase-2 read
  __shared__ __align__(16) unsigned short MBUF[17408];   // 34 KB
  __shared__ float radS[64];
  __shared__ int   rowS[64];
  unsigned short* M1  = MBUF;
  unsigned short* m2T = MBUF;

  const int t = threadIdx.x;
  const int lane = t & 63, wave = t >> 6;
  const int ln15 = lane & 15, q = lane >> 4;
  const int e0 = blockIdx.x * 64;
  const int sr = t >> 2;
  const int sc = (t & 3) * 8;

  const int es = sorted[e0 + sr];
  unsigned nr = (unsigned)erow[es]; if (nr >= NN) nr = 0;
  unsigned nc = (unsigned)ecol[es]; if (nc >= NN) nc = 0;
  const unsigned short* aR = hb + (size_t)nr * HD + sc;
  const unsigned short* aC = hb + (size_t)nc * HD + sc;
  if (t < 64) {
    int e = sorted[e0 + t];
    radS[t] = radial[e];
    unsigned r = (unsigned)erow[e]; if (r >= NN) r = 0;
    rowS[t] = (int)r;
  }

  // prefetch per-thread bias/scale values (used in epilogues)
  float bv1[4], wr1v[4], bv2[4];
  #pragma unroll
  for (int j = 0; j < 4; ++j) {
    const int n = wave*64 + j*16 + ln15;
    bv1[j]  = b1[n];
    wr1v[j] = w1r[n];
    bv2[j]  = b2[n];
  }

  f32x4 acc[4][4];
  #pragma unroll
  for (int i = 0; i < 4; ++i)
    #pragma unroll
    for (int j = 0; j < 4; ++j) acc[i][j] = (f32x4){0.f,0.f,0.f,0.f};

  // phase 1: K = 512 (h[row] | h[col])
  #pragma unroll
  for (int kt = 0; kt < 16; ++kt) {
    const int k0 = kt * 32;
    const unsigned short* as = (k0 < HD) ? (aR + k0) : (aC + (k0 - HD));
    async16(as, &As[t*8]);
    #pragma unroll
    for (int p = 0; p < 4; ++p)
      async16(w1t + (size_t)(p*64 + sr)*512 + k0 + sc, &Bs[p*2048 + t*8]);
    __syncthreads();
    short8 fa[4], fb[4];
    #pragma unroll
    for (int i = 0; i < 4; ++i) fa[i] = *(const short8*)&As[(i*16 + ln15)*32 + q*8];
    #pragma unroll
    for (int j = 0; j < 4; ++j) fb[j] = *(const short8*)&Bs[(wave*64 + j*16 + ln15)*32 + q*8];
    #pragma unroll
    for (int i = 0; i < 4; ++i)
      #pragma unroll
      for (int j = 0; j < 4; ++j)
        acc[i][j] = __builtin_amdgcn_mfma_f32_16x16x32_bf16(fa[i], fb[j], acc[i][j], 0, 0, 0);
    __syncthreads();
  }

  // epilogue 1: bias + radial rank-1 term + silu -> M1 (bf16, kt-blocked [8][64][32])
  #pragma unroll
  for (int i = 0; i < 4; ++i) {
    #pragma unroll
    for (int j = 0; j < 4; ++j) {
      const int n = wave*64 + j*16 + ln15;
      const float bv = bv1[j], wr = wr1v[j];
      const int m = i*16 + q*4;
      float s0 = silu_f(acc[i][j][0] + bv + radS[m+0] * wr);
      float s1 = silu_f(acc[i][j][1] + bv + radS[m+1] * wr);
      float s2 = silu_f(acc[i][j][2] + bv + radS[m+2] * wr);
      float s3 = silu_f(acc[i][j][3] + bv + radS[m+3] * wr);
      unsigned int u01 = pk2bf(s0, s1), u23 = pk2bf(s2, s3);
      unsigned short* p = &M1[(n >> 5)*2048 + m*32 + (n & 31)];
      p[0]  = (unsigned short)u01;
      p[32] = (unsigned short)(u01 >> 16);
      p[64] = (unsigned short)u23;
      p[96] = (unsigned short)(u23 >> 16);
    }
  }
  __syncthreads();

  // phase 2: K = 256 (M1 @ W2)
  f32x4 acc2[4][4];
  #pragma unroll
  for (int i = 0; i < 4; ++i)
    #pragma unroll
    for (int j = 0; j < 4; ++j) acc2[i][j] = (f32x4){0.f,0.f,0.f,0.f};

  #pragma unroll
  for (int kt = 0; kt < 8; ++kt) {
    const int k0 = kt * 32;
    #pragma unroll
    for (int p = 0; p < 4; ++p)
      async16(w2t + (size_t)(p*64 + sr)*HD + k0 + sc, &Bs[p*2048 + t*8]);
    __syncthreads();
    short8 fa[4], fb[4];
    #pragma unroll
    for (int i = 0; i < 4; ++i) fa[i] = *(const short8*)&M1[kt*2048 + (i*16 + ln15)*32 + q*8];
    #pragma unroll
    for (int j = 0; j < 4; ++j) fb[j] = *(const short8*)&Bs[(wave*64 + j*16 + ln15)*32 + q*8];
    #pragma unroll
    for (int i = 0; i < 4; ++i)
      #pragma unroll
      for (int j = 0; j < 4; ++j)
        acc2[i][j] = __builtin_amdgcn_mfma_f32_16x16x32_bf16(fa[i], fb[j], acc2[i][j], 0, 0, 0);
    __syncthreads();   // last iteration: all M1/Bs reads done -> MBUF reusable as m2T
  }

  // epilogue 2a: silu -> m2T[col][row] (bf16, stride 68) in LDS, packed b64 stores
  #pragma unroll
  for (int i = 0; i < 4; ++i) {
    #pragma unroll
    for (int j = 0; j < 4; ++j) {
      const int n = wave*64 + j*16 + ln15;
      const float bv = bv2[j];
      float s0 = silu_f(acc2[i][j][0] + bv);
      float s1 = silu_f(acc2[i][j][1] + bv);
      float s2 = silu_f(acc2[i][j][2] + bv);
      float s3 = silu_f(acc2[i][j][3] + bv);
      const int m = i*16 + q*4;
      uint2 pk; pk.x = pk2bf(s0, s1); pk.y = pk2bf(s2, s3);
      *(uint2*)&m2T[n*68 + m] = pk;    // byte addr 136n+2m, m%4==0 -> 8B aligned
    }
  }
  __syncthreads();

  // epilogue 2b: per-column segmented reduction over sorted rows -> few coalesced atomics
  {
    const int c = t;                   // 256 threads = 256 columns
    int cur = rowS[0];
    float s = 0.f;
    #pragma unroll
    for (int m = 0; m < 64; m += 4) {
      ushort4 v = *(const ushort4*)&m2T[c*68 + m];
      int n0 = rowS[m], n1 = rowS[m+1], n2 = rowS[m+2], n3 = rowS[m+3];
      float f0 = bf2f(v.x), f1 = bf2f(v.y), f2v = bf2f(v.z), f3 = bf2f(v.w);
      if (n0 != cur) { atomicAdd(&agg[(size_t)cur * HD + c], s); s = 0.f; cur = n0; }
      s += f0;
      if (n1 != cur) { atomicAdd(&agg[(size_t)cur * HD + c], s); s = 0.f; cur = n1; }
      s += f1;
      if (n2 != cur) { atomicAdd(&agg[(size_t)cur * HD + c], s); s = 0.f; cur = n2; }
      s += f2v;
      if (n3 != cur) { atomicAdd(&agg[(size_t)cur * HD + c], s); s = 0.f; cur = n3; }
      s += f3;
    }
    atomicAdd(&agg[(size_t)cur * HD + c], s);
  }
}

// ---------------- concat: xcat = [h | bf16(agg)] ----------------
__global__ __launch_bounds__(256) void concat_k(
    const unsigned short* __restrict__ h, const float* __restrict__ agg,
    unsigned short* __restrict__ xcat)
{
  const int g = blockIdx.x * 256 + threadIdx.x;   // NN*64 threads, 4 cols each
  const int node = g >> 6;
  const int c = (g & 63) * 4;
  if (node >= NN) return;
  *(ushort4*)(xcat + (size_t)node * 2 * HD + c) =
      *(const ushort4*)(h + (size_t)node * HD + c);
  float4 a = *(const float4*)(agg + (size_t)node * HD + c);
  uint2 pk; pk.x = pk2bf(a.x, a.y); pk.y = pk2bf(a.z, a.w);
  *(uint2*)(xcat + (size_t)node * 2 * HD + HD + c) = pk;
}

// ---------------- launch ----------------
extern "C" void kernel_launch(void* const* d_in, const int* in_sizes, int n_in,
                              void* d_out, int out_size, void* d_ws, size_t ws_size,
                              hipStream_t stream)
{
  (void)in_sizes; (void)n_in; (void)out_size; (void)ws_size;
  const float* h_in  = (const float*)d_in[0];
  const int*   ei    = (const int*)d_in[1];
  const float* cd    = (const float*)d_in[2];
  const float* w_in  = (const float*)d_in[3];
  const float* b_in  = (const float*)d_in[4];
  const float* w_out = (const float*)d_in[5];
  const float* b_out = (const float*)d_in[6];
  const float* ew1   = (const float*)d_in[7];
  const float* eb1   = (const float*)d_in[8];
  const float* ew2   = (const float*)d_in[9];
  const float* eb2   = (const float*)d_in[10];
  const float* nw1   = (const float*)d_in[11];
  const float* nb1   = (const float*)d_in[12];
  const float* nw2   = (const float*)d_in[13];
  const float* nb2   = (const float*)d_in[14];
  float* out = (float*)d_out;

  char* base = (char*)d_ws;
  size_t off = 0;
  auto WS = [&](size_t bytes) -> char* {
    char* p = base + off;
    off = (off + bytes + 255) & ~(size_t)255;
    return p;
  };
  float*          radial  = (float*)WS((size_t)NE * 4);
  unsigned short* hb_in   = (unsigned short*)WS((size_t)NN * NF * 2);
  unsigned short* hcur    = (unsigned short*)WS((size_t)NN * HD * 2);
  unsigned short* xcat    = (unsigned short*)WS((size_t)NN * 2 * HD * 2);
  float*          aggF    = (float*)WS((size_t)NN * HD * 4);
  unsigned short* x1      = (unsigned short*)aggF;   // alias: agg dead when x1 live
  unsigned short* w_in_t  = (unsigned short*)WS((size_t)NF * HD * 2);
  unsigned short* w_out_t = (unsigned short*)WS((size_t)NF * HD * 2);
  unsigned short* ew1t    = (unsigned short*)WS((size_t)NL * HD * 512 * 2);
  float*          w1r     = (float*)WS((size_t)NL * HD * 4);
  unsigned short* ew2t    = (unsigned short*)WS((size_t)NL * HD * HD * 2);
  unsigned short* nw1t    = (unsigned short*)WS((size_t)NL * HD * 512 * 2);
  unsigned short* nw2t    = (unsigned short*)WS((size_t)NL * HD * HD * 2);
  int*            hist    = (int*)WS((size_t)NN * 4);
  int*            starts  = (int*)WS((size_t)(NN + 1) * 4);
  int*            cursor  = (int*)WS((size_t)NN * 4);
  int*            sorted  = (int*)WS((size_t)NE * 4);

  hipMemsetAsync(hist, 0, (size_t)NN * 4, stream);
  prep_k<<<dim3(5000, 20, 1), 256, 0, stream>>>(h_in, cd, w_in, w_out, ew1, ew2, nw1, nw2,
      w_in_t, w_out_t, ew1t, w1r, ew2t, nw1t, nw2t, hb_in, radial);
  hist_k<<<NE / 256, 256, 0, stream>>>(ei, hist);
  scan_k<<<1, 256, 0, stream>>>(hist, starts, cursor);
  scatter_k<<<NE / 256, 256, 0, stream>>>(ei, cursor, sorted);

  // h = h_in @ w_in + b_in
  gemm_k<<<dim3(157, 2), 256, 0, stream>>>(hb_in, w_in_t, b_in, hcur, nullptr, NN, HD, NF, 0);

  for (int l = 0; l < NL; ++l) {
    hipMemsetAsync(aggF, 0, (size_t)NN * HD * 4, stream);
    edge_k<<<NE / 64, 256, 0, stream>>>(hcur, ei, ei + NE, radial, sorted,
        ew1t + (size_t)l * HD * 512, eb1 + l * HD, w1r + l * HD,
        ew2t + (size_t)l * HD * HD, eb2 + l * HD, aggF);
    concat_k<<<NN * 64 / 256, 256, 0, stream>>>(hcur, aggF, xcat);
    gemm_k<<<dim3(157, 2), 256, 0, stream>>>(xcat, nw1t + (size_t)l * HD * 512,
        nb1 + l * HD, x1, nullptr, NN, HD, 2 * HD, 1);
    gemm_k<<<dim3(157, 2), 256, 0, stream>>>(x1, nw2t + (size_t)l * HD * HD,
        nb2 + l * HD, hcur, nullptr, NN, HD, HD, 0);
  }

  // out = h @ w_out + b_out  (fp32 output)
  gemm_k<<<dim3(157, 1), 256, 0, stream>>>(hcur, w_out_t, b_out, nullptr, out, NN, NF, HD, 0);
}

// Round 9
// 2359.200 us; speedup vs baseline: 1.6289x; 1.0154x over previous
//
#include <hip/hip_runtime.h>
#include <hip/hip_bf16.h>
#include <cstdint>
#include <cstddef>

#define NN 20000
#define NE 640000
#define NF 64
#define HD 256
#define NL 4

typedef __attribute__((ext_vector_type(8))) short short8;
typedef __attribute__((ext_vector_type(4))) float f32x4;

__device__ __forceinline__ float bf2f(unsigned short u){
  union { unsigned int i; float f; } x; x.i = ((unsigned int)u) << 16; return x.f;
}
__device__ __forceinline__ unsigned short f2bf(float f){
  union { float f; unsigned int i; } x; x.f = f;
  unsigned int r = x.i + 0x7FFFu + ((x.i >> 16) & 1u);   // RNE
  return (unsigned short)(r >> 16);
}
// packed 2xf32 -> 2xbf16 (v_cvt_pk_bf16_f32 on gfx950, RNE)
__device__ __forceinline__ unsigned int pk2bf(float a, float b){
  union { __hip_bfloat162 h; unsigned int u; } cv;
  cv.h = __float22bfloat162_rn(float2{a, b});
  return cv.u;
}
__device__ __forceinline__ float silu_f(float v){
  return v * (1.0f / (1.0f + __expf(-v)));
}
__device__ __forceinline__ void async16(const void* g, void* l){
  __builtin_amdgcn_global_load_lds(
      (const __attribute__((address_space(1))) unsigned int*)g,
      (__attribute__((address_space(3))) unsigned int*)l, 16, 0, 0);
}

// ---------------- prep: weight transpose->bf16, h->bf16, radial ----------------
__global__ __launch_bounds__(256) void prep_k(
    const float* __restrict__ h_in, const float* __restrict__ cd,
    const float* __restrict__ w_in, const float* __restrict__ w_out,
    const float* __restrict__ ew1, const float* __restrict__ ew2,
    const float* __restrict__ nw1, const float* __restrict__ nw2,
    unsigned short* __restrict__ w_in_t, unsigned short* __restrict__ w_out_t,
    unsigned short* __restrict__ ew1t, float* __restrict__ w1r,
    unsigned short* __restrict__ ew2t, unsigned short* __restrict__ nw1t,
    unsigned short* __restrict__ nw2t, unsigned short* __restrict__ hb_in,
    float* __restrict__ radial)
{
  const int s = blockIdx.y;
  const int tid = blockIdx.x * 256 + threadIdx.x;
  if (s == 18) {
    if (tid < NN * NF) hb_in[tid] = f2bf(h_in[tid]);
    return;
  }
  if (s == 19) {
    if (tid < NE) {
      float x = cd[tid*3+0], y = cd[tid*3+1], z = cd[tid*3+2];
      radial[tid] = x*x + y*y + z*z;
    }
    return;
  }
  const float* src; unsigned short* dst; int K, N, dstK; float* extra = nullptr;
  if (s == 0)      { src = w_in;  dst = w_in_t;  K = NF;   N = HD; dstK = NF; }
  else if (s == 1) { src = w_out; dst = w_out_t; K = HD;   N = NF; dstK = HD; }
  else if (s < 6)  { int l = s-2;  src = ew1 + (size_t)l*513*HD;  dst = ew1t + (size_t)l*HD*512; K = 513;  N = HD; dstK = 512; extra = w1r + l*HD; }
  else if (s < 10) { int l = s-6;  src = ew2 + (size_t)l*HD*HD;   dst = ew2t + (size_t)l*HD*HD;  K = HD;   N = HD; dstK = HD; }
  else if (s < 14) { int l = s-10; src = nw1 + (size_t)l*2*HD*HD; dst = nw1t + (size_t)l*HD*512; K = 2*HD; N = HD; dstK = 512; }
  else             { int l = s-14; src = nw2 + (size_t)l*HD*HD;   dst = nw2t + (size_t)l*HD*HD;  K = HD;   N = HD; dstK = HD; }
  if (tid >= K * N) return;
  int k = tid / N, n = tid - k * N;
  float v = src[tid];
  if (k >= dstK) { if (extra) extra[n] = v; return; }   // radial row of edge_w1
  dst[(size_t)n * dstK + k] = f2bf(v);
}

// ---------------- CSR build (counting sort of edges by row) ----------------
__global__ __launch_bounds__(256) void hist_k(const int* __restrict__ erow, int* __restrict__ hist){
  int e = blockIdx.x * 256 + threadIdx.x;
  if (e < NE){
    unsigned r = (unsigned)erow[e]; if (r >= NN) r = 0;
    atomicAdd(&hist[r], 1);
  }
}

__global__ __launch_bounds__(256) void scan_k(const int* __restrict__ hist,
                                              int* __restrict__ starts, int* __restrict__ cursor){
  __shared__ int part[256];
  const int t = threadIdx.x;
  const int CH = 79;                 // 256*79 = 20224 >= 20000
  int lo = t * CH, hi = lo + CH; if (hi > NN) hi = NN; if (lo > NN) lo = NN;
  int s = 0;
  for (int i = lo; i < hi; ++i) s += hist[i];
  part[t] = s; __syncthreads();
  for (int off = 1; off < 256; off <<= 1){
    int v = (t >= off) ? part[t - off] : 0;
    __syncthreads();
    part[t] += v;
    __syncthreads();
  }
  int base = (t == 0) ? 0 : part[t - 1];
  for (int i = lo; i < hi; ++i){ starts[i] = base; cursor[i] = base; base += hist[i]; }
  if (t == 255) starts[NN] = part[255];
}

__global__ __launch_bounds__(256) void scatter_k(const int* __restrict__ erow,
                                                 int* __restrict__ cursor, int* __restrict__ sorted){
  int e = blockIdx.x * 256 + threadIdx.x;
  if (e < NE){
    unsigned r = (unsigned)erow[e]; if (r >= NN) r = 0;
    int pos = atomicAdd(&cursor[r], 1);
    sorted[pos] = e;
  }
}

// ---------------- generic 128x128 bf16 MFMA GEMM: out = [silu](A @ Wt^T + bias) ----------------
// outB2 (optional): duplicate bf16 store with row stride 512 (xcat first half)
__global__ __launch_bounds__(256) void gemm_k(
    const unsigned short* __restrict__ Am, const unsigned short* __restrict__ Wt,
    const float* __restrict__ bias,
    unsigned short* __restrict__ outB, float* __restrict__ outF,
    unsigned short* __restrict__ outB2,
    int M, int N, int K, int fuseSilu)
{
  __shared__ __align__(16) unsigned short As[128*32];
  __shared__ __align__(16) unsigned short Bs[128*32];
  const int t = threadIdx.x;
  const int lane = t & 63, wave = t >> 6;
  const int ln15 = lane & 15, q = lane >> 4;
  const int bm = blockIdx.x, bn = blockIdx.y;
  const int wm = wave >> 1, wn = wave & 1;

  f32x4 acc[4][4];
  #pragma unroll
  for (int i = 0; i < 4; ++i)
    #pragma unroll
    for (int j = 0; j < 4; ++j) acc[i][j] = (f32x4){0.f,0.f,0.f,0.f};

  const int sr = t >> 2;
  const int sc = (t & 3) * 8;
  int am0 = bm*128 + sr;      if (am0 > M-1) am0 = M-1;
  int am1 = bm*128 + 64 + sr; if (am1 > M-1) am1 = M-1;
  int an0 = bn*128 + sr;      if (an0 > N-1) an0 = N-1;
  int an1 = bn*128 + 64 + sr; if (an1 > N-1) an1 = N-1;
  const unsigned short* a0 = Am + (size_t)am0 * K + sc;
  const unsigned short* a1 = Am + (size_t)am1 * K + sc;
  const unsigned short* b0 = Wt + (size_t)an0 * K + sc;
  const unsigned short* b1 = Wt + (size_t)an1 * K + sc;

  const int nkt = K >> 5;
  for (int kt = 0; kt < nkt; ++kt) {
    const int k0 = kt * 32;
    async16(a0 + k0, &As[t*8]);
    async16(a1 + k0, &As[2048 + t*8]);
    async16(b0 + k0, &Bs[t*8]);
    async16(b1 + k0, &Bs[2048 + t*8]);
    __syncthreads();
    short8 fa[4], fb[4];
    #pragma unroll
    for (int i = 0; i < 4; ++i)
      fa[i] = *(const short8*)&As[(wm*64 + i*16 + ln15)*32 + q*8];
    #pragma unroll
    for (int j = 0; j < 4; ++j)
      fb[j] = *(const short8*)&Bs[(wn*64 + j*16 + ln15)*32 + q*8];
    #pragma unroll
    for (int i = 0; i < 4; ++i)
      #pragma unroll
      for (int j = 0; j < 4; ++j)
        acc[i][j] = __builtin_amdgcn_mfma_f32_16x16x32_bf16(fa[i], fb[j], acc[i][j], 0, 0, 0);
    __syncthreads();
  }

  #pragma unroll
  for (int i = 0; i < 4; ++i) {
    #pragma unroll
    for (int j = 0; j < 4; ++j) {
      const int n = bn*128 + wn*64 + j*16 + ln15;
      if (n >= N) continue;
      const float bv = bias ? bias[n] : 0.0f;
      #pragma unroll
      for (int r = 0; r < 4; ++r) {
        const int m = bm*128 + wm*64 + i*16 + q*4 + r;
        if (m >= M) continue;
        float v = acc[i][j][r] + bv;
        if (fuseSilu) v = silu_f(v);
        if (outB) {
          unsigned short b = f2bf(v);
          outB[(size_t)m * N + n] = b;
          if (outB2) outB2[(size_t)m * 512 + n] = b;
        }
        else outF[(size_t)m * N + n] = v;
      }
    }
  }
}

// ---------------- fused edge MLP + aggregation (R8 + XOR-swizzled LDS) ----------------
// 64 sorted edges per block; all row-stride-32 LDS tiles XOR-swizzled on the k-segment
// (phys_seg = logical_seg ^ ((row>>1)&3)) to break the 8-way b128 bank aliasing.
__global__ __launch_bounds__(256) void edge_k(
    const unsigned short* __restrict__ hb,
    const int* __restrict__ erow, const int* __restrict__ ecol,
    const float* __restrict__ radial, const int* __restrict__ sorted,
    const unsigned short* __restrict__ w1t,  // [256][512]
    const float* __restrict__ b1, const float* __restrict__ w1r,
    const unsigned short* __restrict__ w2t,  // [256][256]
    const float* __restrict__ b2,
    float* __restrict__ agg)                  // [NN][256] fp32, pre-zeroed
{
  __shared__ __align__(16) unsigned short As[64*32];     //  4 KB
  __shared__ __align__(16) unsigned short Bs[256*32];    // 16 KB
  // MBUF: M1 kt-blocked [8][64][32] (16384), then m2T [256][stride 68] (17408)
  __shared__ __align__(16) unsigned short MBUF[17408];   // 34 KB
  __shared__ float radS[64];
  __shared__ int   rowS[64];
  unsigned short* M1  = MBUF;
  unsigned short* m2T = MBUF;

  const int t = threadIdx.x;
  const int lane = t & 63, wave = t >> 6;
  const int ln15 = lane & 15, q = lane >> 4;
  const int e0 = blockIdx.x * 64;
  const int sr = t >> 2;
  // staging column segment: XOR-swizzle by row pair (self-inverse)
  const int sc_swz = (((t & 3) ^ ((sr >> 1) & 3))) * 8;
  // reader segment offset (uniform across i/j/kt since tile-row strides are mult of 8)
  const int xq = ((q ^ ((ln15 >> 1) & 3))) * 8;

  const int es = sorted[e0 + sr];
  unsigned nr = (unsigned)erow[es]; if (nr >= NN) nr = 0;
  unsigned nc = (unsigned)ecol[es]; if (nc >= NN) nc = 0;
  const unsigned short* aR = hb + (size_t)nr * HD + sc_swz;
  const unsigned short* aC = hb + (size_t)nc * HD + sc_swz;
  if (t < 64) {
    int e = sorted[e0 + t];
    radS[t] = radial[e];
    unsigned r = (unsigned)erow[e]; if (r >= NN) r = 0;
    rowS[t] = (int)r;
  }

  // prefetch per-thread bias/scale values (used in epilogues)
  float bv1[4], wr1v[4], bv2[4];
  #pragma unroll
  for (int j = 0; j < 4; ++j) {
    const int n = wave*64 + j*16 + ln15;
    bv1[j]  = b1[n];
    wr1v[j] = w1r[n];
    bv2[j]  = b2[n];
  }

  f32x4 acc[4][4];
  #pragma unroll
  for (int i = 0; i < 4; ++i)
    #pragma unroll
    for (int j = 0; j < 4; ++j) acc[i][j] = (f32x4){0.f,0.f,0.f,0.f};

  // phase 1: K = 512 (h[row] | h[col])
  #pragma unroll
  for (int kt = 0; kt < 16; ++kt) {
    const int k0 = kt * 32;
    const unsigned short* as = (k0 < HD) ? (aR + k0) : (aC + (k0 - HD));
    async16(as, &As[t*8]);
    #pragma unroll
    for (int p = 0; p < 4; ++p)
      async16(w1t + (size_t)(p*64 + sr)*512 + k0 + sc_swz, &Bs[p*2048 + t*8]);
    __syncthreads();
    short8 fa[4], fb[4];
    #pragma unroll
    for (int i = 0; i < 4; ++i) fa[i] = *(const short8*)&As[(i*16 + ln15)*32 + xq];
    #pragma unroll
    for (int j = 0; j < 4; ++j) fb[j] = *(const short8*)&Bs[(wave*64 + j*16 + ln15)*32 + xq];
    #pragma unroll
    for (int i = 0; i < 4; ++i)
      #pragma unroll
      for (int j = 0; j < 4; ++j)
        acc[i][j] = __builtin_amdgcn_mfma_f32_16x16x32_bf16(fa[i], fb[j], acc[i][j], 0, 0, 0);
    __syncthreads();
  }

  // epilogue 1: bias + radial + silu -> M1 (bf16, kt-blocked [8][64][32], swizzled cols)
  #pragma unroll
  for (int i = 0; i < 4; ++i) {
    #pragma unroll
    for (int j = 0; j < 4; ++j) {
      const int n = wave*64 + j*16 + ln15;
      const float bv = bv1[j], wr = wr1v[j];
      const int mb = i*16 + q*4;
      const int blk = (n >> 5) * 2048;
      const int gl  = (n & 31) >> 3;      // logical segment within row
      const int nlo = n & 7;
      #pragma unroll
      for (int r = 0; r < 4; ++r) {
        const int m = mb + r;
        float v = silu_f(acc[i][j][r] + bv + radS[m] * wr);
        const int pseg = gl ^ ((m >> 1) & 3);
        M1[blk + m*32 + pseg*8 + nlo] = f2bf(v);
      }
    }
  }
  __syncthreads();

  // phase 2: K = 256 (M1 @ W2)
  f32x4 acc2[4][4];
  #pragma unroll
  for (int i = 0; i < 4; ++i)
    #pragma unroll
    for (int j = 0; j < 4; ++j) acc2[i][j] = (f32x4){0.f,0.f,0.f,0.f};

  #pragma unroll
  for (int kt = 0; kt < 8; ++kt) {
    const int k0 = kt * 32;
    #pragma unroll
    for (int p = 0; p < 4; ++p)
      async16(w2t + (size_t)(p*64 + sr)*HD + k0 + sc_swz, &Bs[p*2048 + t*8]);
    __syncthreads();
    short8 fa[4], fb[4];
    #pragma unroll
    for (int i = 0; i < 4; ++i) fa[i] = *(const short8*)&M1[kt*2048 + (i*16 + ln15)*32 + xq];
    #pragma unroll
    for (int j = 0; j < 4; ++j) fb[j] = *(const short8*)&Bs[(wave*64 + j*16 + ln15)*32 + xq];
    #pragma unroll
    for (int i = 0; i < 4; ++i)
      #pragma unroll
      for (int j = 0; j < 4; ++j)
        acc2[i][j] = __builtin_amdgcn_mfma_f32_16x16x32_bf16(fa[i], fb[j], acc2[i][j], 0, 0, 0);
    __syncthreads();   // last iteration: all M1/Bs reads done -> MBUF reusable as m2T
  }

  // epilogue 2a: silu -> m2T[col][row] (bf16, stride 68) in LDS, packed b64 stores
  #pragma unroll
  for (int i = 0; i < 4; ++i) {
    #pragma unroll
    for (int j = 0; j < 4; ++j) {
      const int n = wave*64 + j*16 + ln15;
      const float bv = bv2[j];
      float s0 = silu_f(acc2[i][j][0] + bv);
      float s1 = silu_f(acc2[i][j][1] + bv);
      float s2 = silu_f(acc2[i][j][2] + bv);
      float s3 = silu_f(acc2[i][j][3] + bv);
      const int m = i*16 + q*4;
      uint2 pk; pk.x = pk2bf(s0, s1); pk.y = pk2bf(s2, s3);
      *(uint2*)&m2T[n*68 + m] = pk;    // byte addr 136n+2m, m%4==0 -> 8B aligned
    }
  }
  __syncthreads();

  // epilogue 2b: per-column segmented reduction over sorted rows -> few coalesced atomics
  {
    const int c = t;                   // 256 threads = 256 columns
    int cur = rowS[0];
    float s = 0.f;
    #pragma unroll
    for (int m = 0; m < 64; m += 4) {
      ushort4 v = *(const ushort4*)&m2T[c*68 + m];
      int n0 = rowS[m], n1 = rowS[m+1], n2 = rowS[m+2], n3 = rowS[m+3];
      float f0 = bf2f(v.x), f1 = bf2f(v.y), f2v = bf2f(v.z), f3 = bf2f(v.w);
      if (n0 != cur) { atomicAdd(&agg[(size_t)cur * HD + c], s); s = 0.f; cur = n0; }
      s += f0;
      if (n1 != cur) { atomicAdd(&agg[(size_t)cur * HD + c], s); s = 0.f; cur = n1; }
      s += f1;
      if (n2 != cur) { atomicAdd(&agg[(size_t)cur * HD + c], s); s = 0.f; cur = n2; }
      s += f2v;
      if (n3 != cur) { atomicAdd(&agg[(size_t)cur * HD + c], s); s = 0.f; cur = n3; }
      s += f3;
    }
    atomicAdd(&agg[(size_t)cur * HD + c], s);
  }
}

// ---------------- aggcvt: xcat[:,256:512] = bf16(agg); agg re-zeroed for next layer ----
__global__ __launch_bounds__(256) void aggcvt_k(
    float* __restrict__ agg, unsigned short* __restrict__ xcat)
{
  const int g = blockIdx.x * 256 + threadIdx.x;   // NN*64 threads, 4 cols each
  const int node = g >> 6;
  const int c = (g & 63) * 4;
  if (node >= NN) return;
  float4 a = *(const float4*)(agg + (size_t)node * HD + c);
  uint2 pk; pk.x = pk2bf(a.x, a.y); pk.y = pk2bf(a.z, a.w);
  *(uint2*)(xcat + (size_t)node * 2 * HD + HD + c) = pk;
  *(float4*)(agg + (size_t)node * HD + c) = float4{0.f, 0.f, 0.f, 0.f};
}

// ---------------- launch ----------------
extern "C" void kernel_launch(void* const* d_in, const int* in_sizes, int n_in,
                              void* d_out, int out_size, void* d_ws, size_t ws_size,
                              hipStream_t stream)
{
  (void)in_sizes; (void)n_in; (void)out_size; (void)ws_size;
  const float* h_in  = (const float*)d_in[0];
  const int*   ei    = (const int*)d_in[1];
  const float* cd    = (const float*)d_in[2];
  const float* w_in  = (const float*)d_in[3];
  const float* b_in  = (const float*)d_in[4];
  const float* w_out = (const float*)d_in[5];
  const float* b_out = (const float*)d_in[6];
  const float* ew1   = (const float*)d_in[7];
  const float* eb1   = (const float*)d_in[8];
  const float* ew2   = (const float*)d_in[9];
  const float* eb2   = (const float*)d_in[10];
  const float* nw1   = (const float*)d_in[11];
  const float* nb1   = (const float*)d_in[12];
  const float* nw2   = (const float*)d_in[13];
  const float* nb2   = (const float*)d_in[14];
  float* out = (float*)d_out;

  char* base = (char*)d_ws;
  size_t off = 0;
  auto WS = [&](size_t bytes) -> char* {
    char* p = base + off;
    off = (off + bytes + 255) & ~(size_t)255;
    return p;
  };
  float*          radial  = (float*)WS((size_t)NE * 4);
  unsigned short* hb_in   = (unsigned short*)WS((size_t)NN * NF * 2);
  unsigned short* hcur    = (unsigned short*)WS((size_t)NN * HD * 2);
  unsigned short* xcat    = (unsigned short*)WS((size_t)NN * 2 * HD * 2);
  float*          aggF    = (float*)WS((size_t)NN * HD * 4);
  unsigned short* x1      = (unsigned short*)WS((size_t)NN * HD * 2);
  unsigned short* w_in_t  = (unsigned short*)WS((size_t)NF * HD * 2);
  unsigned short* w_out_t = (unsigned short*)WS((size_t)NF * HD * 2);
  unsigned short* ew1t    = (unsigned short*)WS((size_t)NL * HD * 512 * 2);
  float*          w1r     = (float*)WS((size_t)NL * HD * 4);
  unsigned short* ew2t    = (unsigned short*)WS((size_t)NL * HD * HD * 2);
  unsigned short* nw1t    = (unsigned short*)WS((size_t)NL * HD * 512 * 2);
  unsigned short* nw2t    = (unsigned short*)WS((size_t)NL * HD * HD * 2);
  int*            hist    = (int*)WS((size_t)NN * 4);
  int*            starts  = (int*)WS((size_t)(NN + 1) * 4);
  int*            cursor  = (int*)WS((size_t)NN * 4);
  int*            sorted  = (int*)WS((size_t)NE * 4);

  hipMemsetAsync(hist, 0, (size_t)NN * 4, stream);
  hipMemsetAsync(aggF, 0, (size_t)NN * HD * 4, stream);
  prep_k<<<dim3(5000, 20, 1), 256, 0, stream>>>(h_in, cd, w_in, w_out, ew1, ew2, nw1, nw2,
      w_in_t, w_out_t, ew1t, w1r, ew2t, nw1t, nw2t, hb_in, radial);
  hist_k<<<NE / 256, 256, 0, stream>>>(ei, hist);
  scan_k<<<1, 256, 0, stream>>>(hist, starts, cursor);
  scatter_k<<<NE / 256, 256, 0, stream>>>(ei, cursor, sorted);

  // h = h_in @ w_in + b_in  (also writes xcat first half)
  gemm_k<<<dim3(157, 2), 256, 0, stream>>>(hb_in, w_in_t, b_in, hcur, nullptr, xcat,
      NN, HD, NF, 0);

  for (int l = 0; l < NL; ++l) {
    edge_k<<<NE / 64, 256, 0, stream>>>(hcur, ei, ei + NE, radial, sorted,
        ew1t + (size_t)l * HD * 512, eb1 + l * HD, w1r + l * HD,
        ew2t + (size_t)l * HD * HD, eb2 + l * HD, aggF);
    aggcvt_k<<<NN * 64 / 256, 256, 0, stream>>>(aggF, xcat);
    gemm_k<<<dim3(157, 2), 256, 0, stream>>>(xcat, nw1t + (size_t)l * HD * 512,
        nb1 + l * HD, x1, nullptr, nullptr, NN, HD, 2 * HD, 1);
    // nw2 writes hcur AND xcat first half for the next layer's concat
    gemm_k<<<dim3(157, 2), 256, 0, stream>>>(x1, nw2t + (size_t)l * HD * HD,
        nb2 + l * HD, hcur, nullptr, (l < NL-1) ? xcat : nullptr, NN, HD, HD, 0);
  }

  // out = h @ w_out + b_out  (fp32 output)
  gemm_k<<<dim3(157, 1), 256, 0, stream>>>(hcur, w_out_t, b_out, nullptr, out, nullptr,
      NN, NF, HD, 0);
}

// Round 10
// 1802.585 us; speedup vs baseline: 2.1318x; 1.3088x over previous
//
#include <hip/hip_runtime.h>
#include <hip/hip_bf16.h>
#include <cstdint>
#include <cstddef>

#define NN 20000
#define NE 640000
#define NF 64
#define HD 256
#define NL 4

typedef __attribute__((ext_vector_type(8))) short short8;
typedef __attribute__((ext_vector_type(4))) float f32x4;

__device__ __forceinline__ float bf2f(unsigned short u){
  union { unsigned int i; float f; } x; x.i = ((unsigned int)u) << 16; return x.f;
}
__device__ __forceinline__ unsigned short f2bf(float f){
  union { float f; unsigned int i; } x; x.f = f;
  unsigned int r = x.i + 0x7FFFu + ((x.i >> 16) & 1u);   // RNE
  return (unsigned short)(r >> 16);
}
// packed 2xf32 -> 2xbf16 (v_cvt_pk_bf16_f32 on gfx950, RNE)
__device__ __forceinline__ unsigned int pk2bf(float a, float b){
  union { __hip_bfloat162 h; unsigned int u; } cv;
  cv.h = __float22bfloat162_rn(float2{a, b});
  return cv.u;
}
__device__ __forceinline__ float silu_f(float v){
  return v * (1.0f / (1.0f + __expf(-v)));
}
__device__ __forceinline__ void async16(const void* g, void* l){
  __builtin_amdgcn_global_load_lds(
      (const __attribute__((address_space(1))) unsigned int*)g,
      (__attribute__((address_space(3))) unsigned int*)l, 16, 0, 0);
}

// ---------------- prep: weight transpose->bf16, h->bf16, radial, b1e ----------------
__global__ __launch_bounds__(256) void prep_k(
    const float* __restrict__ h_in, const float* __restrict__ cd,
    const float* __restrict__ w_in, const float* __restrict__ w_out,
    const float* __restrict__ ew1, const float* __restrict__ ew2,
    const float* __restrict__ nw1, const float* __restrict__ nw2,
    const float* __restrict__ eb1,
    unsigned short* __restrict__ w_in_t, unsigned short* __restrict__ w_out_t,
    unsigned short* __restrict__ ew1cat, float* __restrict__ w1r,
    float* __restrict__ b1e,
    unsigned short* __restrict__ ew2t, unsigned short* __restrict__ nw1t,
    unsigned short* __restrict__ nw2t, unsigned short* __restrict__ hb_in,
    float* __restrict__ radial)
{
  const int s = blockIdx.y;
  const int tid = blockIdx.x * 256 + threadIdx.x;
  if (s == 18) {
    if (tid < NN * NF) hb_in[tid] = f2bf(h_in[tid]);
    return;
  }
  if (s == 19) {
    if (tid < NE) {
      float x = cd[tid*3+0], y = cd[tid*3+1], z = cd[tid*3+2];
      radial[tid] = x*x + y*y + z*z;
    }
    return;
  }
  if (s == 20) {
    if (tid < NL * 512) {
      int l = tid >> 9, c = tid & 511;
      b1e[tid] = (c < 256) ? eb1[l * HD + c] : 0.0f;
    }
    return;
  }
  if (s >= 2 && s < 6) {
    // edge_w1: [513][256] -> ew1cat [512][256] (rows 0..255 = k<256 half as rows n;
    // rows 256..511 = k in 256..511 half), radial row (k=512) -> w1r
    int l = s - 2;
    if (tid >= 513 * HD) return;
    int k = tid / HD, n = tid - k * HD;
    float v = ew1[(size_t)l * 513 * HD + tid];
    if (k == 512) { w1r[l * HD + n] = v; return; }
    unsigned short* dst = ew1cat + (size_t)l * 512 * 256;
    if (k < 256) dst[(size_t)n * 256 + k] = f2bf(v);
    else         dst[(size_t)(256 + n) * 256 + (k - 256)] = f2bf(v);
    return;
  }
  const float* src; unsigned short* dst; int K, N;
  if (s == 0)      { src = w_in;  dst = w_in_t;  K = NF;   N = HD; }
  else if (s == 1) { src = w_out; dst = w_out_t; K = HD;   N = NF; }
  else if (s < 10) { int l = s-6;  src = ew2 + (size_t)l*HD*HD;   dst = ew2t + (size_t)l*HD*HD;  K = HD;   N = HD; }
  else if (s < 14) { int l = s-10; src = nw1 + (size_t)l*2*HD*HD; dst = nw1t + (size_t)l*HD*512; K = 2*HD; N = HD; }
  else             { int l = s-14; src = nw2 + (size_t)l*HD*HD;   dst = nw2t + (size_t)l*HD*HD;  K = HD;   N = HD; }
  if (tid >= K * N) return;
  int k = tid / N, n = tid - k * N;
  dst[(size_t)n * K + k] = f2bf(src[tid]);
}

// ---------------- CSR build (counting sort of edges by row) ----------------
__global__ __launch_bounds__(256) void hist_k(const int* __restrict__ erow, int* __restrict__ hist){
  int e = blockIdx.x * 256 + threadIdx.x;
  if (e < NE){
    unsigned r = (unsigned)erow[e]; if (r >= NN) r = 0;
    atomicAdd(&hist[r], 1);
  }
}

__global__ __launch_bounds__(256) void scan_k(const int* __restrict__ hist,
                                              int* __restrict__ starts, int* __restrict__ cursor){
  __shared__ int part[256];
  const int t = threadIdx.x;
  const int CH = 79;                 // 256*79 = 20224 >= 20000
  int lo = t * CH, hi = lo + CH; if (hi > NN) hi = NN; if (lo > NN) lo = NN;
  int s = 0;
  for (int i = lo; i < hi; ++i) s += hist[i];
  part[t] = s; __syncthreads();
  for (int off = 1; off < 256; off <<= 1){
    int v = (t >= off) ? part[t - off] : 0;
    __syncthreads();
    part[t] += v;
    __syncthreads();
  }
  int base = (t == 0) ? 0 : part[t - 1];
  for (int i = lo; i < hi; ++i){ starts[i] = base; cursor[i] = base; base += hist[i]; }
  if (t == 255) starts[NN] = part[255];
}

__global__ __launch_bounds__(256) void scatter_k(const int* __restrict__ erow,
                                                 int* __restrict__ cursor, int* __restrict__ sorted){
  int e = blockIdx.x * 256 + threadIdx.x;
  if (e < NE){
    unsigned r = (unsigned)erow[e]; if (r >= NN) r = 0;
    int pos = atomicAdd(&cursor[r], 1);
    sorted[pos] = e;
  }
}

// ---------------- generic 128x128 bf16 MFMA GEMM: out = [silu](A @ Wt^T + bias) ----------------
// outB2 (optional): duplicate bf16 store with row stride 512 (xcat first half)
__global__ __launch_bounds__(256) void gemm_k(
    const unsigned short* __restrict__ Am, const unsigned short* __restrict__ Wt,
    const float* __restrict__ bias,
    unsigned short* __restrict__ outB, float* __restrict__ outF,
    unsigned short* __restrict__ outB2,
    int M, int N, int K, int fuseSilu)
{
  __shared__ __align__(16) unsigned short As[128*32];
  __shared__ __align__(16) unsigned short Bs[128*32];
  const int t = threadIdx.x;
  const int lane = t & 63, wave = t >> 6;
  const int ln15 = lane & 15, q = lane >> 4;
  const int bm = blockIdx.x, bn = blockIdx.y;
  const int wm = wave >> 1, wn = wave & 1;

  f32x4 acc[4][4];
  #pragma unroll
  for (int i = 0; i < 4; ++i)
    #pragma unroll
    for (int j = 0; j < 4; ++j) acc[i][j] = (f32x4){0.f,0.f,0.f,0.f};

  const int sr = t >> 2;
  const int sc = (t & 3) * 8;
  int am0 = bm*128 + sr;      if (am0 > M-1) am0 = M-1;
  int am1 = bm*128 + 64 + sr; if (am1 > M-1) am1 = M-1;
  int an0 = bn*128 + sr;      if (an0 > N-1) an0 = N-1;
  int an1 = bn*128 + 64 + sr; if (an1 > N-1) an1 = N-1;
  const unsigned short* a0 = Am + (size_t)am0 * K + sc;
  const unsigned short* a1 = Am + (size_t)am1 * K + sc;
  const unsigned short* b0 = Wt + (size_t)an0 * K + sc;
  const unsigned short* b1 = Wt + (size_t)an1 * K + sc;

  const int nkt = K >> 5;
  for (int kt = 0; kt < nkt; ++kt) {
    const int k0 = kt * 32;
    async16(a0 + k0, &As[t*8]);
    async16(a1 + k0, &As[2048 + t*8]);
    async16(b0 + k0, &Bs[t*8]);
    async16(b1 + k0, &Bs[2048 + t*8]);
    __syncthreads();
    short8 fa[4], fb[4];
    #pragma unroll
    for (int i = 0; i < 4; ++i)
      fa[i] = *(const short8*)&As[(wm*64 + i*16 + ln15)*32 + q*8];
    #pragma unroll
    for (int j = 0; j < 4; ++j)
      fb[j] = *(const short8*)&Bs[(wn*64 + j*16 + ln15)*32 + q*8];
    #pragma unroll
    for (int i = 0; i < 4; ++i)
      #pragma unroll
      for (int j = 0; j < 4; ++j)
        acc[i][j] = __builtin_amdgcn_mfma_f32_16x16x32_bf16(fa[i], fb[j], acc[i][j], 0, 0, 0);
    __syncthreads();
  }

  #pragma unroll
  for (int i = 0; i < 4; ++i) {
    #pragma unroll
    for (int j = 0; j < 4; ++j) {
      const int n = bn*128 + wn*64 + j*16 + ln15;
      if (n >= N) continue;
      const float bv = bias ? bias[n] : 0.0f;
      #pragma unroll
      for (int r = 0; r < 4; ++r) {
        const int m = bm*128 + wm*64 + i*16 + q*4 + r;
        if (m >= M) continue;
        float v = acc[i][j][r] + bv;
        if (fuseSilu) v = silu_f(v);
        if (outB) {
          unsigned short b = f2bf(v);
          outB[(size_t)m * N + n] = b;
          if (outB2) outB2[(size_t)m * 512 + n] = b;
        }
        else outF[(size_t)m * N + n] = v;
      }
    }
  }
}

// ---------------- fused edge MLP + aggregation (gather-based phase 1) ----------------
// Phase 1 precomputed at node level: hT[n] = [hcur@W1_row + b1 | hcur@W1_col] (bf16).
// Per block (64 sorted edges): m1 = silu(hT[row][c] + hT[col][256+c] + radial*w1r[c])
// written directly into swizzled kt-blocked M1; phase 2 (K=256, MFMA) + transposed
// LDS segmented reduction into agg.
__global__ __launch_bounds__(256) void edge_k(
    const unsigned short* __restrict__ hT,   // [NN][512]
    const int* __restrict__ erow, const int* __restrict__ ecol,
    const float* __restrict__ radial, const int* __restrict__ sorted,
    const float* __restrict__ w1r,           // [256]
    const unsigned short* __restrict__ w2t,  // [256][256]
    const float* __restrict__ b2,
    float* __restrict__ agg)                  // [NN][256] fp32, pre-zeroed
{
  __shared__ __align__(16) unsigned short Bs[256*32];    // 16 KB
  // MBUF: M1 kt-blocked [8][64][32] (16384), then m2T [256][stride 68] (17408)
  __shared__ __align__(16) unsigned short MBUF[17408];   // 34 KB
  __shared__ float radS[64];
  __shared__ int   rowS[64];
  __shared__ float w1rS[256];
  unsigned short* M1  = MBUF;
  unsigned short* m2T = MBUF;

  const int t = threadIdx.x;
  const int lane = t & 63, wave = t >> 6;
  const int ln15 = lane & 15, q = lane >> 4;
  const int e0 = blockIdx.x * 64;
  const int sr = t >> 2;                                  // edge row 0..63
  const int sc_swz = (((t & 3) ^ ((sr >> 1) & 3))) * 8;   // logical k-seg for phys slot t&3
  const int xq = ((q ^ ((ln15 >> 1) & 3))) * 8;           // reader phys seg

  const int es = sorted[e0 + sr];
  unsigned nr = (unsigned)erow[es]; if (nr >= NN) nr = 0;
  unsigned nc = (unsigned)ecol[es]; if (nc >= NN) nc = 0;
  const unsigned short* hr = hT + (size_t)nr * 512 + sc_swz;
  const unsigned short* hc = hT + (size_t)nc * 512 + 256 + sc_swz;
  if (t < 64) {
    int e = sorted[e0 + t];
    radS[t] = radial[e];
    unsigned r = (unsigned)erow[e]; if (r >= NN) r = 0;
    rowS[t] = (int)r;
  }
  w1rS[t] = w1r[t];

  // prefetch b2 per-thread (epilogue 2)
  float bv2[4];
  #pragma unroll
  for (int j = 0; j < 4; ++j) bv2[j] = b2[wave*64 + j*16 + ln15];

  __syncthreads();   // radS, w1rS visible
  const float rad = radS[sr];

  // prologue: m1 = silu(hr + hc + rad*w1r) -> M1 (kt-blocked, swizzled), b128 stores
  #pragma unroll
  for (int ch = 0; ch < 8; ++ch) {
    const int c0 = ch*32 + sc_swz;                 // logical col base (8 cols)
    short8 va = *(const short8*)(hr + ch*32);
    short8 vb = *(const short8*)(hc + ch*32);
    float4 w0 = *(const float4*)&w1rS[c0];
    float4 w1 = *(const float4*)&w1rS[c0 + 4];
    const unsigned int* ua = (const unsigned int*)&va;
    const unsigned int* ub = (const unsigned int*)&vb;
    float o[8];
    #pragma unroll
    for (int i = 0; i < 4; ++i) {
      union { unsigned int i; float f; } alo, ahi, blo, bhi;
      alo.i = ua[i] << 16; ahi.i = ua[i] & 0xFFFF0000u;
      blo.i = ub[i] << 16; bhi.i = ub[i] & 0xFFFF0000u;
      o[2*i]   = alo.f + blo.f;
      o[2*i+1] = ahi.f + bhi.f;
    }
    o[0] = silu_f(o[0] + rad * w0.x);  o[1] = silu_f(o[1] + rad * w0.y);
    o[2] = silu_f(o[2] + rad * w0.z);  o[3] = silu_f(o[3] + rad * w0.w);
    o[4] = silu_f(o[4] + rad * w1.x);  o[5] = silu_f(o[5] + rad * w1.y);
    o[6] = silu_f(o[6] + rad * w1.z);  o[7] = silu_f(o[7] + rad * w1.w);
    union { unsigned int u[4]; short8 s; } res;
    res.u[0] = pk2bf(o[0], o[1]); res.u[1] = pk2bf(o[2], o[3]);
    res.u[2] = pk2bf(o[4], o[5]); res.u[3] = pk2bf(o[6], o[7]);
    *(short8*)&M1[ch*2048 + sr*32 + (t & 3)*8] = res.s;
  }

  // phase 2: K = 256 (M1 @ W2^T)
  f32x4 acc2[4][4];
  #pragma unroll
  for (int i = 0; i < 4; ++i)
    #pragma unroll
    for (int j = 0; j < 4; ++j) acc2[i][j] = (f32x4){0.f,0.f,0.f,0.f};

  #pragma unroll
  for (int kt = 0; kt < 8; ++kt) {
    const int k0 = kt * 32;
    #pragma unroll
    for (int p = 0; p < 4; ++p)
      async16(w2t + (size_t)(p*64 + sr)*HD + k0 + sc_swz, &Bs[p*2048 + t*8]);
    __syncthreads();   // kt=0: also covers prologue M1 writes
    short8 fa[4], fb[4];
    #pragma unroll
    for (int i = 0; i < 4; ++i) fa[i] = *(const short8*)&M1[kt*2048 + (i*16 + ln15)*32 + xq];
    #pragma unroll
    for (int j = 0; j < 4; ++j) fb[j] = *(const short8*)&Bs[(wave*64 + j*16 + ln15)*32 + xq];
    #pragma unroll
    for (int i = 0; i < 4; ++i)
      #pragma unroll
      for (int j = 0; j < 4; ++j)
        acc2[i][j] = __builtin_amdgcn_mfma_f32_16x16x32_bf16(fa[i], fb[j], acc2[i][j], 0, 0, 0);
    __syncthreads();   // last iteration: MBUF reusable as m2T
  }

  // epilogue 2a: silu -> m2T[col][row] (bf16, stride 68) in LDS, packed b64 stores
  #pragma unroll
  for (int i = 0; i < 4; ++i) {
    #pragma unroll
    for (int j = 0; j < 4; ++j) {
      const int n = wave*64 + j*16 + ln15;
      const float bv = bv2[j];
      float s0 = silu_f(acc2[i][j][0] + bv);
      float s1 = silu_f(acc2[i][j][1] + bv);
      float s2 = silu_f(acc2[i][j][2] + bv);
      float s3 = silu_f(acc2[i][j][3] + bv);
      const int m = i*16 + q*4;
      uint2 pk; pk.x = pk2bf(s0, s1); pk.y = pk2bf(s2, s3);
      *(uint2*)&m2T[n*68 + m] = pk;
    }
  }
  __syncthreads();

  // epilogue 2b: per-column segmented reduction (scalar run boundaries via readfirstlane)
  {
    const int c = t;                   // 256 threads = 256 columns
    int cur = __builtin_amdgcn_readfirstlane(rowS[0]);
    float s = 0.f;
    #pragma unroll
    for (int m = 0; m < 64; m += 4) {
      ushort4 v = *(const ushort4*)&m2T[c*68 + m];
      int n0 = __builtin_amdgcn_readfirstlane(rowS[m]);
      int n1 = __builtin_amdgcn_readfirstlane(rowS[m+1]);
      int n2 = __builtin_amdgcn_readfirstlane(rowS[m+2]);
      int n3 = __builtin_amdgcn_readfirstlane(rowS[m+3]);
      float f0 = bf2f(v.x), f1 = bf2f(v.y), f2v = bf2f(v.z), f3 = bf2f(v.w);
      if (n0 != cur) { atomicAdd(&agg[(size_t)cur * HD + c], s); s = 0.f; cur = n0; }
      s += f0;
      if (n1 != cur) { atomicAdd(&agg[(size_t)cur * HD + c], s); s = 0.f; cur = n1; }
      s += f1;
      if (n2 != cur) { atomicAdd(&agg[(size_t)cur * HD + c], s); s = 0.f; cur = n2; }
      s += f2v;
      if (n3 != cur) { atomicAdd(&agg[(size_t)cur * HD + c], s); s = 0.f; cur = n3; }
      s += f3;
    }
    atomicAdd(&agg[(size_t)cur * HD + c], s);
  }
}

// ---------------- aggcvt: xcat[:,256:512] = bf16(agg); agg re-zeroed for next layer ----
__global__ __launch_bounds__(256) void aggcvt_k(
    float* __restrict__ agg, unsigned short* __restrict__ xcat)
{
  const int g = blockIdx.x * 256 + threadIdx.x;   // NN*64 threads, 4 cols each
  const int node = g >> 6;
  const int c = (g & 63) * 4;
  if (node >= NN) return;
  float4 a = *(const float4*)(agg + (size_t)node * HD + c);
  uint2 pk; pk.x = pk2bf(a.x, a.y); pk.y = pk2bf(a.z, a.w);
  *(uint2*)(xcat + (size_t)node * 2 * HD + HD + c) = pk;
  *(float4*)(agg + (size_t)node * HD + c) = float4{0.f, 0.f, 0.f, 0.f};
}

// ---------------- launch ----------------
extern "C" void kernel_launch(void* const* d_in, const int* in_sizes, int n_in,
                              void* d_out, int out_size, void* d_ws, size_t ws_size,
                              hipStream_t stream)
{
  (void)in_sizes; (void)n_in; (void)out_size; (void)ws_size;
  const float* h_in  = (const float*)d_in[0];
  const int*   ei    = (const int*)d_in[1];
  const float* cd    = (const float*)d_in[2];
  const float* w_in  = (const float*)d_in[3];
  const float* b_in  = (const float*)d_in[4];
  const float* w_out = (const float*)d_in[5];
  const float* b_out = (const float*)d_in[6];
  const float* ew1   = (const float*)d_in[7];
  const float* eb1   = (const float*)d_in[8];
  const float* ew2   = (const float*)d_in[9];
  const float* eb2   = (const float*)d_in[10];
  const float* nw1   = (const float*)d_in[11];
  const float* nb1   = (const float*)d_in[12];
  const float* nw2   = (const float*)d_in[13];
  const float* nb2   = (const float*)d_in[14];
  float* out = (float*)d_out;

  char* base = (char*)d_ws;
  size_t off = 0;
  auto WS = [&](size_t bytes) -> char* {
    char* p = base + off;
    off = (off + bytes + 255) & ~(size_t)255;
    return p;
  };
  float*          radial  = (float*)WS((size_t)NE * 4);
  unsigned short* hb_in   = (unsigned short*)WS((size_t)NN * NF * 2);
  unsigned short* hcur    = (unsigned short*)WS((size_t)NN * HD * 2);
  unsigned short* xcat    = (unsigned short*)WS((size_t)NN * 2 * HD * 2);
  float*          aggF    = (float*)WS((size_t)NN * HD * 4);
  unsigned short* hT      = (unsigned short*)WS((size_t)NN * 512 * 2);  // 20.5 MB
  unsigned short* x1      = hT;   // alias: hT dead once edge_k done; x1 lives after
  unsigned short* w_in_t  = (unsigned short*)WS((size_t)NF * HD * 2);
  unsigned short* w_out_t = (unsigned short*)WS((size_t)NF * HD * 2);
  unsigned short* ew1cat  = (unsigned short*)WS((size_t)NL * 512 * 256 * 2);
  float*          w1r     = (float*)WS((size_t)NL * HD * 4);
  float*          b1e     = (float*)WS((size_t)NL * 512 * 4);
  unsigned short* ew2t    = (unsigned short*)WS((size_t)NL * HD * HD * 2);
  unsigned short* nw1t    = (unsigned short*)WS((size_t)NL * HD * 512 * 2);
  unsigned short* nw2t    = (unsigned short*)WS((size_t)NL * HD * HD * 2);
  int*            hist    = (int*)WS((size_t)NN * 4);
  int*            starts  = (int*)WS((size_t)(NN + 1) * 4);
  int*            cursor  = (int*)WS((size_t)NN * 4);
  int*            sorted  = (int*)WS((size_t)NE * 4);

  hipMemsetAsync(hist, 0, (size_t)NN * 4, stream);
  hipMemsetAsync(aggF, 0, (size_t)NN * HD * 4, stream);
  prep_k<<<dim3(5000, 21, 1), 256, 0, stream>>>(h_in, cd, w_in, w_out, ew1, ew2, nw1, nw2,
      eb1, w_in_t, w_out_t, ew1cat, w1r, b1e, ew2t, nw1t, nw2t, hb_in, radial);
  hist_k<<<NE / 256, 256, 0, stream>>>(ei, hist);
  scan_k<<<1, 256, 0, stream>>>(hist, starts, cursor);
  scatter_k<<<NE / 256, 256, 0, stream>>>(ei, cursor, sorted);

  // h = h_in @ w_in + b_in  (also writes xcat first half)
  gemm_k<<<dim3(157, 2), 256, 0, stream>>>(hb_in, w_in_t, b_in, hcur, nullptr, xcat,
      NN, HD, NF, 0);

  for (int l = 0; l < NL; ++l) {
    // node-level phase-1 table: hT = hcur @ [W1_row | W1_col]^T + [b1 | 0]
    gemm_k<<<dim3(157, 4), 256, 0, stream>>>(hcur, ew1cat + (size_t)l * 512 * 256,
        b1e + (size_t)l * 512, hT, nullptr, nullptr, NN, 512, HD, 0);
    edge_k<<<NE / 64, 256, 0, stream>>>(hT, ei, ei + NE, radial, sorted,
        w1r + l * HD, ew2t + (size_t)l * HD * HD, eb2 + l * HD, aggF);
    aggcvt_k<<<NN * 64 / 256, 256, 0, stream>>>(aggF, xcat);
    gemm_k<<<dim3(157, 2), 256, 0, stream>>>(xcat, nw1t + (size_t)l * HD * 512,
        nb1 + l * HD, x1, nullptr, nullptr, NN, HD, 2 * HD, 1);
    // nw2 writes hcur AND xcat first half for the next layer's concat
    gemm_k<<<dim3(157, 2), 256, 0, stream>>>(x1, nw2t + (size_t)l * HD * HD,
        nb2 + l * HD, hcur, nullptr, (l < NL-1) ? xcat : nullptr, NN, HD, HD, 0);
  }

  // out = h @ w_out + b_out  (fp32 output)
  gemm_k<<<dim3(157, 1), 256, 0, stream>>>(hcur, w_out_t, b_out, nullptr, out, nullptr,
      NN, NF, HD, 0);
}

// Round 11
// 1551.506 us; speedup vs baseline: 2.4768x; 1.1618x over previous
//
#include <hip/hip_runtime.h>
#include <hip/hip_bf16.h>
#include <cstdint>
#include <cstddef>

#define NN 20000
#define NE 640000
#define NF 64
#define HD 256
#define NL 4

typedef __attribute__((ext_vector_type(8))) short short8;
typedef __attribute__((ext_vector_type(4))) float f32x4;

__device__ __forceinline__ float bf2f(unsigned short u){
  union { unsigned int i; float f; } x; x.i = ((unsigned int)u) << 16; return x.f;
}
__device__ __forceinline__ unsigned short f2bf(float f){
  union { float f; unsigned int i; } x; x.f = f;
  unsigned int r = x.i + 0x7FFFu + ((x.i >> 16) & 1u);   // RNE
  return (unsigned short)(r >> 16);
}
// packed 2xf32 -> 2xbf16 (v_cvt_pk_bf16_f32 on gfx950, RNE)
__device__ __forceinline__ unsigned int pk2bf(float a, float b){
  union { __hip_bfloat162 h; unsigned int u; } cv;
  cv.h = __float22bfloat162_rn(float2{a, b});
  return cv.u;
}
__device__ __forceinline__ float silu_f(float v){
  return v * (1.0f / (1.0f + __expf(-v)));
}
__device__ __forceinline__ void async16(const void* g, void* l){
  __builtin_amdgcn_global_load_lds(
      (const __attribute__((address_space(1))) unsigned int*)g,
      (__attribute__((address_space(3))) unsigned int*)l, 16, 0, 0);
}

// ---------------- prep: weight transpose->bf16, h->bf16, radial, b1e ----------------
__global__ __launch_bounds__(256) void prep_k(
    const float* __restrict__ h_in, const float* __restrict__ cd,
    const float* __restrict__ w_in, const float* __restrict__ w_out,
    const float* __restrict__ ew1, const float* __restrict__ ew2,
    const float* __restrict__ nw1, const float* __restrict__ nw2,
    const float* __restrict__ eb1,
    unsigned short* __restrict__ w_in_t, unsigned short* __restrict__ w_out_t,
    unsigned short* __restrict__ ew1cat, float* __restrict__ w1r,
    float* __restrict__ b1e,
    unsigned short* __restrict__ ew2t, unsigned short* __restrict__ nw1t,
    unsigned short* __restrict__ nw2t, unsigned short* __restrict__ hb_in,
    float* __restrict__ radial)
{
  const int s = blockIdx.y;
  const int tid = blockIdx.x * 256 + threadIdx.x;
  if (s == 18) {
    if (tid < NN * NF) hb_in[tid] = f2bf(h_in[tid]);
    return;
  }
  if (s == 19) {
    if (tid < NE) {
      float x = cd[tid*3+0], y = cd[tid*3+1], z = cd[tid*3+2];
      radial[tid] = x*x + y*y + z*z;
    }
    return;
  }
  if (s == 20) {
    if (tid < NL * 512) {
      int l = tid >> 9, c = tid & 511;
      b1e[tid] = (c < 256) ? eb1[l * HD + c] : 0.0f;
    }
    return;
  }
  if (s >= 2 && s < 6) {
    // edge_w1: [513][256] -> ew1cat [512][256]; radial row (k=512) -> w1r
    int l = s - 2;
    if (tid >= 513 * HD) return;
    int k = tid / HD, n = tid - k * HD;
    float v = ew1[(size_t)l * 513 * HD + tid];
    if (k == 512) { w1r[l * HD + n] = v; return; }
    unsigned short* dst = ew1cat + (size_t)l * 512 * 256;
    if (k < 256) dst[(size_t)n * 256 + k] = f2bf(v);
    else         dst[(size_t)(256 + n) * 256 + (k - 256)] = f2bf(v);
    return;
  }
  const float* src; unsigned short* dst; int K, N;
  if (s == 0)      { src = w_in;  dst = w_in_t;  K = NF;   N = HD; }
  else if (s == 1) { src = w_out; dst = w_out_t; K = HD;   N = NF; }
  else if (s < 10) { int l = s-6;  src = ew2 + (size_t)l*HD*HD;   dst = ew2t + (size_t)l*HD*HD;  K = HD;   N = HD; }
  else if (s < 14) { int l = s-10; src = nw1 + (size_t)l*2*HD*HD; dst = nw1t + (size_t)l*HD*512; K = 2*HD; N = HD; }
  else             { int l = s-14; src = nw2 + (size_t)l*HD*HD;   dst = nw2t + (size_t)l*HD*HD;  K = HD;   N = HD; }
  if (tid >= K * N) return;
  int k = tid / N, n = tid - k * N;
  dst[(size_t)n * K + k] = f2bf(src[tid]);
}

// ---------------- CSR build (counting sort of edges by row) ----------------
__global__ __launch_bounds__(256) void hist_k(const int* __restrict__ erow, int* __restrict__ hist){
  int e = blockIdx.x * 256 + threadIdx.x;
  if (e < NE){
    unsigned r = (unsigned)erow[e]; if (r >= NN) r = 0;
    atomicAdd(&hist[r], 1);
  }
}

__global__ __launch_bounds__(256) void scan_k(const int* __restrict__ hist,
                                              int* __restrict__ starts, int* __restrict__ cursor){
  __shared__ int part[256];
  const int t = threadIdx.x;
  const int CH = 79;                 // 256*79 = 20224 >= 20000
  int lo = t * CH, hi = lo + CH; if (hi > NN) hi = NN; if (lo > NN) lo = NN;
  int s = 0;
  for (int i = lo; i < hi; ++i) s += hist[i];
  part[t] = s; __syncthreads();
  for (int off = 1; off < 256; off <<= 1){
    int v = (t >= off) ? part[t - off] : 0;
    __syncthreads();
    part[t] += v;
    __syncthreads();
  }
  int base = (t == 0) ? 0 : part[t - 1];
  for (int i = lo; i < hi; ++i){ starts[i] = base; cursor[i] = base; base += hist[i]; }
  if (t == 255) starts[NN] = part[255];
}

__global__ __launch_bounds__(256) void scatter_k(const int* __restrict__ erow,
                                                 int* __restrict__ cursor, int* __restrict__ sorted){
  int e = blockIdx.x * 256 + threadIdx.x;
  if (e < NE){
    unsigned r = (unsigned)erow[e]; if (r >= NN) r = 0;
    int pos = atomicAdd(&cursor[r], 1);
    sorted[pos] = e;
  }
}

// ---------------- generic 128x128 bf16 MFMA GEMM: out = [silu](A @ Wt^T + bias) ----------------
// outB2 (optional): duplicate bf16 store with row stride 512 (xcat first half)
__global__ __launch_bounds__(256) void gemm_k(
    const unsigned short* __restrict__ Am, const unsigned short* __restrict__ Wt,
    const float* __restrict__ bias,
    unsigned short* __restrict__ outB, float* __restrict__ outF,
    unsigned short* __restrict__ outB2,
    int M, int N, int K, int fuseSilu)
{
  __shared__ __align__(16) unsigned short As[128*32];
  __shared__ __align__(16) unsigned short Bs[128*32];
  const int t = threadIdx.x;
  const int lane = t & 63, wave = t >> 6;
  const int ln15 = lane & 15, q = lane >> 4;
  const int bm = blockIdx.x, bn = blockIdx.y;
  const int wm = wave >> 1, wn = wave & 1;

  f32x4 acc[4][4];
  #pragma unroll
  for (int i = 0; i < 4; ++i)
    #pragma unroll
    for (int j = 0; j < 4; ++j) acc[i][j] = (f32x4){0.f,0.f,0.f,0.f};

  const int sr = t >> 2;
  const int sc = (t & 3) * 8;
  int am0 = bm*128 + sr;      if (am0 > M-1) am0 = M-1;
  int am1 = bm*128 + 64 + sr; if (am1 > M-1) am1 = M-1;
  int an0 = bn*128 + sr;      if (an0 > N-1) an0 = N-1;
  int an1 = bn*128 + 64 + sr; if (an1 > N-1) an1 = N-1;
  const unsigned short* a0 = Am + (size_t)am0 * K + sc;
  const unsigned short* a1 = Am + (size_t)am1 * K + sc;
  const unsigned short* b0 = Wt + (size_t)an0 * K + sc;
  const unsigned short* b1 = Wt + (size_t)an1 * K + sc;

  const int nkt = K >> 5;
  for (int kt = 0; kt < nkt; ++kt) {
    const int k0 = kt * 32;
    async16(a0 + k0, &As[t*8]);
    async16(a1 + k0, &As[2048 + t*8]);
    async16(b0 + k0, &Bs[t*8]);
    async16(b1 + k0, &Bs[2048 + t*8]);
    __syncthreads();
    short8 fa[4], fb[4];
    #pragma unroll
    for (int i = 0; i < 4; ++i)
      fa[i] = *(const short8*)&As[(wm*64 + i*16 + ln15)*32 + q*8];
    #pragma unroll
    for (int j = 0; j < 4; ++j)
      fb[j] = *(const short8*)&Bs[(wn*64 + j*16 + ln15)*32 + q*8];
    #pragma unroll
    for (int i = 0; i < 4; ++i)
      #pragma unroll
      for (int j = 0; j < 4; ++j)
        acc[i][j] = __builtin_amdgcn_mfma_f32_16x16x32_bf16(fa[i], fb[j], acc[i][j], 0, 0, 0);
    __syncthreads();
  }

  #pragma unroll
  for (int i = 0; i < 4; ++i) {
    #pragma unroll
    for (int j = 0; j < 4; ++j) {
      const int n = bn*128 + wn*64 + j*16 + ln15;
      if (n >= N) continue;
      const float bv = bias ? bias[n] : 0.0f;
      #pragma unroll
      for (int r = 0; r < 4; ++r) {
        const int m = bm*128 + wm*64 + i*16 + q*4 + r;
        if (m >= M) continue;
        float v = acc[i][j][r] + bv;
        if (fuseSilu) v = silu_f(v);
        if (outB) {
          unsigned short b = f2bf(v);
          outB[(size_t)m * N + n] = b;
          if (outB2) outB2[(size_t)m * 512 + n] = b;
        }
        else outF[(size_t)m * N + n] = v;
      }
    }
  }
}

// ---------------- fused edge MLP + aggregation (3-barrier, B-direct phase 2) ----------------
// Prologue: m1 = silu(hT[row] + hT[col]+256 + rad*w1r) -> M1 (swizzled kt-blocked LDS).
// Phase 2: K=256 MFMA; B fragments load global->VGPR (each wave owns its 64 W2 rows,
// L2-resident) -- no Bs staging, no per-kt barriers. Epilogue: transposed LDS
// segmented reduction -> few coalesced atomics. LDS ~34.5 KB -> 4 blocks/CU.
__global__ __launch_bounds__(256, 4) void edge_k(
    const unsigned short* __restrict__ hT,   // [NN][512]
    const int* __restrict__ erow, const int* __restrict__ ecol,
    const float* __restrict__ radial, const int* __restrict__ sorted,
    const float* __restrict__ w1r,           // [256]
    const unsigned short* __restrict__ w2t,  // [256][256]
    const float* __restrict__ b2,
    float* __restrict__ agg)                  // [NN][256] fp32, pre-zeroed
{
  // MBUF: M1 kt-blocked [8][64][32] (16384 shorts), then m2T [256][stride 66] (16896)
  __shared__ __align__(16) unsigned short MBUF[16896];   // 33.8 KB
  __shared__ float radS[64];
  __shared__ int   rowS[64];
  __shared__ float w1rS[256];
  unsigned short* M1  = MBUF;
  unsigned short* m2T = MBUF;

  const int t = threadIdx.x;
  const int lane = t & 63, wave = t >> 6;
  const int ln15 = lane & 15, q = lane >> 4;
  const int e0 = blockIdx.x * 64;
  const int sr = t >> 2;                                  // edge row 0..63
  const int sc_swz = (((t & 3) ^ ((sr >> 1) & 3))) * 8;   // logical k-seg for phys slot t&3
  const int xq = ((q ^ ((ln15 >> 1) & 3))) * 8;           // reader phys seg

  const int es = sorted[e0 + sr];
  unsigned nr = (unsigned)erow[es]; if (nr >= NN) nr = 0;
  unsigned nc = (unsigned)ecol[es]; if (nc >= NN) nc = 0;
  const unsigned short* hr = hT + (size_t)nr * 512 + sc_swz;
  const unsigned short* hc = hT + (size_t)nc * 512 + 256 + sc_swz;
  if (t < 64) {
    int e = sorted[e0 + t];
    radS[t] = radial[e];
    unsigned r = (unsigned)erow[e]; if (r >= NN) r = 0;
    rowS[t] = (int)r;
  }
  w1rS[t] = w1r[t];

  // per-wave private W2 rows for phase-2 B fragments (global, L2-hot)
  const unsigned short* w2row[4];
  #pragma unroll
  for (int j = 0; j < 4; ++j)
    w2row[j] = w2t + (size_t)(wave*64 + j*16 + ln15) * HD + q*8;

  // prefetch b2 per-thread (epilogue 2)
  float bv2[4];
  #pragma unroll
  for (int j = 0; j < 4; ++j) bv2[j] = b2[wave*64 + j*16 + ln15];

  __syncthreads();   // radS, w1rS visible
  const float rad = radS[sr];

  // prologue: m1 = silu(hr + hc + rad*w1r) -> M1 (kt-blocked, swizzled), b128 stores
  #pragma unroll
  for (int ch = 0; ch < 8; ++ch) {
    const int c0 = ch*32 + sc_swz;                 // logical col base (8 cols)
    short8 va = *(const short8*)(hr + ch*32);
    short8 vb = *(const short8*)(hc + ch*32);
    float4 w0 = *(const float4*)&w1rS[c0];
    float4 w1 = *(const float4*)&w1rS[c0 + 4];
    const unsigned int* ua = (const unsigned int*)&va;
    const unsigned int* ub = (const unsigned int*)&vb;
    float o[8];
    #pragma unroll
    for (int i = 0; i < 4; ++i) {
      union { unsigned int i; float f; } alo, ahi, blo, bhi;
      alo.i = ua[i] << 16; ahi.i = ua[i] & 0xFFFF0000u;
      blo.i = ub[i] << 16; bhi.i = ub[i] & 0xFFFF0000u;
      o[2*i]   = alo.f + blo.f;
      o[2*i+1] = ahi.f + bhi.f;
    }
    o[0] = silu_f(o[0] + rad * w0.x);  o[1] = silu_f(o[1] + rad * w0.y);
    o[2] = silu_f(o[2] + rad * w0.z);  o[3] = silu_f(o[3] + rad * w0.w);
    o[4] = silu_f(o[4] + rad * w1.x);  o[5] = silu_f(o[5] + rad * w1.y);
    o[6] = silu_f(o[6] + rad * w1.z);  o[7] = silu_f(o[7] + rad * w1.w);
    union { unsigned int u[4]; short8 s; } res;
    res.u[0] = pk2bf(o[0], o[1]); res.u[1] = pk2bf(o[2], o[3]);
    res.u[2] = pk2bf(o[4], o[5]); res.u[3] = pk2bf(o[6], o[7]);
    *(short8*)&M1[ch*2048 + sr*32 + (t & 3)*8] = res.s;
  }
  __syncthreads();   // M1 visible to all waves

  // phase 2: K = 256 (M1 @ W2^T), barrier-free; fb direct from global (L2)
  f32x4 acc2[4][4];
  #pragma unroll
  for (int i = 0; i < 4; ++i)
    #pragma unroll
    for (int j = 0; j < 4; ++j) acc2[i][j] = (f32x4){0.f,0.f,0.f,0.f};

  #pragma unroll
  for (int kt = 0; kt < 8; ++kt) {
    short8 fa[4], fb[4];
    #pragma unroll
    for (int j = 0; j < 4; ++j) fb[j] = *(const short8*)(w2row[j] + kt*32);
    #pragma unroll
    for (int i = 0; i < 4; ++i) fa[i] = *(const short8*)&M1[kt*2048 + (i*16 + ln15)*32 + xq];
    #pragma unroll
    for (int i = 0; i < 4; ++i)
      #pragma unroll
      for (int j = 0; j < 4; ++j)
        acc2[i][j] = __builtin_amdgcn_mfma_f32_16x16x32_bf16(fa[i], fb[j], acc2[i][j], 0, 0, 0);
  }
  __syncthreads();   // all M1 reads done -> MBUF reusable as m2T

  // epilogue 2a: silu -> m2T[col][stride 66] in LDS (paired b32 stores, 4B aligned)
  #pragma unroll
  for (int i = 0; i < 4; ++i) {
    #pragma unroll
    for (int j = 0; j < 4; ++j) {
      const int n = wave*64 + j*16 + ln15;
      const float bv = bv2[j];
      float s0 = silu_f(acc2[i][j][0] + bv);
      float s1 = silu_f(acc2[i][j][1] + bv);
      float s2 = silu_f(acc2[i][j][2] + bv);
      float s3 = silu_f(acc2[i][j][3] + bv);
      const int m = i*16 + q*4;
      *(unsigned int*)&m2T[n*66 + m]     = pk2bf(s0, s1);
      *(unsigned int*)&m2T[n*66 + m + 2] = pk2bf(s2, s3);
    }
  }
  __syncthreads();

  // epilogue 2b: per-column segmented reduction (scalar run boundaries via readfirstlane)
  {
    const int c = t;                   // 256 threads = 256 columns
    int cur = __builtin_amdgcn_readfirstlane(rowS[0]);
    float s = 0.f;
    #pragma unroll
    for (int m = 0; m < 64; m += 4) {
      unsigned int u0 = *(const unsigned int*)&m2T[c*66 + m];
      unsigned int u1 = *(const unsigned int*)&m2T[c*66 + m + 2];
      int n0 = __builtin_amdgcn_readfirstlane(rowS[m]);
      int n1 = __builtin_amdgcn_readfirstlane(rowS[m+1]);
      int n2 = __builtin_amdgcn_readfirstlane(rowS[m+2]);
      int n3 = __builtin_amdgcn_readfirstlane(rowS[m+3]);
      float f0 = bf2f((unsigned short)u0), f1 = bf2f((unsigned short)(u0 >> 16));
      float f2v = bf2f((unsigned short)u1), f3 = bf2f((unsigned short)(u1 >> 16));
      if (n0 != cur) { atomicAdd(&agg[(size_t)cur * HD + c], s); s = 0.f; cur = n0; }
      s += f0;
      if (n1 != cur) { atomicAdd(&agg[(size_t)cur * HD + c], s); s = 0.f; cur = n1; }
      s += f1;
      if (n2 != cur) { atomicAdd(&agg[(size_t)cur * HD + c], s); s = 0.f; cur = n2; }
      s += f2v;
      if (n3 != cur) { atomicAdd(&agg[(size_t)cur * HD + c], s); s = 0.f; cur = n3; }
      s += f3;
    }
    atomicAdd(&agg[(size_t)cur * HD + c], s);
  }
}

// ---------------- aggcvt: xcat[:,256:512] = bf16(agg); agg re-zeroed for next layer ----
__global__ __launch_bounds__(256) void aggcvt_k(
    float* __restrict__ agg, unsigned short* __restrict__ xcat)
{
  const int g = blockIdx.x * 256 + threadIdx.x;   // NN*64 threads, 4 cols each
  const int node = g >> 6;
  const int c = (g & 63) * 4;
  if (node >= NN) return;
  float4 a = *(const float4*)(agg + (size_t)node * HD + c);
  uint2 pk; pk.x = pk2bf(a.x, a.y); pk.y = pk2bf(a.z, a.w);
  *(uint2*)(xcat + (size_t)node * 2 * HD + HD + c) = pk;
  *(float4*)(agg + (size_t)node * HD + c) = float4{0.f, 0.f, 0.f, 0.f};
}

// ---------------- launch ----------------
extern "C" void kernel_launch(void* const* d_in, const int* in_sizes, int n_in,
                              void* d_out, int out_size, void* d_ws, size_t ws_size,
                              hipStream_t stream)
{
  (void)in_sizes; (void)n_in; (void)out_size; (void)ws_size;
  const float* h_in  = (const float*)d_in[0];
  const int*   ei    = (const int*)d_in[1];
  const float* cd    = (const float*)d_in[2];
  const float* w_in  = (const float*)d_in[3];
  const float* b_in  = (const float*)d_in[4];
  const float* w_out = (const float*)d_in[5];
  const float* b_out = (const float*)d_in[6];
  const float* ew1   = (const float*)d_in[7];
  const float* eb1   = (const float*)d_in[8];
  const float* ew2   = (const float*)d_in[9];
  const float* eb2   = (const float*)d_in[10];
  const float* nw1   = (const float*)d_in[11];
  const float* nb1   = (const float*)d_in[12];
  const float* nw2   = (const float*)d_in[13];
  const float* nb2   = (const float*)d_in[14];
  float* out = (float*)d_out;

  char* base = (char*)d_ws;
  size_t off = 0;
  auto WS = [&](size_t bytes) -> char* {
    char* p = base + off;
    off = (off + bytes + 255) & ~(size_t)255;
    return p;
  };
  float*          radial  = (float*)WS((size_t)NE * 4);
  unsigned short* hb_in   = (unsigned short*)WS((size_t)NN * NF * 2);
  unsigned short* hcur    = (unsigned short*)WS((size_t)NN * HD * 2);
  unsigned short* xcat    = (unsigned short*)WS((size_t)NN * 2 * HD * 2);
  float*          aggF    = (float*)WS((size_t)NN * HD * 4);
  unsigned short* hT      = (unsigned short*)WS((size_t)NN * 512 * 2);  // 20.5 MB
  unsigned short* x1      = hT;   // alias: hT dead once edge_k done; x1 lives after
  unsigned short* w_in_t  = (unsigned short*)WS((size_t)NF * HD * 2);
  unsigned short* w_out_t = (unsigned short*)WS((size_t)NF * HD * 2);
  unsigned short* ew1cat  = (unsigned short*)WS((size_t)NL * 512 * 256 * 2);
  float*          w1r     = (float*)WS((size_t)NL * HD * 4);
  float*          b1e     = (float*)WS((size_t)NL * 512 * 4);
  unsigned short* ew2t    = (unsigned short*)WS((size_t)NL * HD * HD * 2);
  unsigned short* nw1t    = (unsigned short*)WS((size_t)NL * HD * 512 * 2);
  unsigned short* nw2t    = (unsigned short*)WS((size_t)NL * HD * HD * 2);
  int*            hist    = (int*)WS((size_t)NN * 4);
  int*            starts  = (int*)WS((size_t)(NN + 1) * 4);
  int*            cursor  = (int*)WS((size_t)NN * 4);
  int*            sorted  = (int*)WS((size_t)NE * 4);

  hipMemsetAsync(hist, 0, (size_t)NN * 4, stream);
  hipMemsetAsync(aggF, 0, (size_t)NN * HD * 4, stream);
  prep_k<<<dim3(5000, 21, 1), 256, 0, stream>>>(h_in, cd, w_in, w_out, ew1, ew2, nw1, nw2,
      eb1, w_in_t, w_out_t, ew1cat, w1r, b1e, ew2t, nw1t, nw2t, hb_in, radial);
  hist_k<<<NE / 256, 256, 0, stream>>>(ei, hist);
  scan_k<<<1, 256, 0, stream>>>(hist, starts, cursor);
  scatter_k<<<NE / 256, 256, 0, stream>>>(ei, cursor, sorted);

  // h = h_in @ w_in + b_in  (also writes xcat first half)
  gemm_k<<<dim3(157, 2), 256, 0, stream>>>(hb_in, w_in_t, b_in, hcur, nullptr, xcat,
      NN, HD, NF, 0);

  for (int l = 0; l < NL; ++l) {
    // node-level phase-1 table: hT = hcur @ [W1_row | W1_col]^T + [b1 | 0]
    gemm_k<<<dim3(157, 4), 256, 0, stream>>>(hcur, ew1cat + (size_t)l * 512 * 256,
        b1e + (size_t)l * 512, hT, nullptr, nullptr, NN, 512, HD, 0);
    edge_k<<<NE / 64, 256, 0, stream>>>(hT, ei, ei + NE, radial, sorted,
        w1r + l * HD, ew2t + (size_t)l * HD * HD, eb2 + l * HD, aggF);
    aggcvt_k<<<NN * 64 / 256, 256, 0, stream>>>(aggF, xcat);
    gemm_k<<<dim3(157, 2), 256, 0, stream>>>(xcat, nw1t + (size_t)l * HD * 512,
        nb1 + l * HD, x1, nullptr, nullptr, NN, HD, 2 * HD, 1);
    // nw2 writes hcur AND xcat first half for the next layer's concat
    gemm_k<<<dim3(157, 2), 256, 0, stream>>>(x1, nw2t + (size_t)l * HD * HD,
        nb2 + l * HD, hcur, nullptr, (l < NL-1) ? xcat : nullptr, NN, HD, HD, 0);
  }

  // out = h @ w_out + b_out  (fp32 output)
  gemm_k<<<dim3(157, 1), 256, 0, stream>>>(hcur, w_out_t, b_out, nullptr, out, nullptr,
      NN, NF, HD, 0);
}

// Round 12
// 1437.078 us; speedup vs baseline: 2.6740x; 1.0796x over previous
//
#include <hip/hip_runtime.h>
#include <hip/hip_bf16.h>
#include <cstdint>
#include <cstddef>

#define NN 20000
#define NE 640000
#define NF 64
#define HD 256
#define NL 4

typedef __attribute__((ext_vector_type(8))) short short8;
typedef __attribute__((ext_vector_type(4))) float f32x4;

__device__ __forceinline__ float bf2f(unsigned short u){
  union { unsigned int i; float f; } x; x.i = ((unsigned int)u) << 16; return x.f;
}
__device__ __forceinline__ unsigned short f2bf(float f){
  union { float f; unsigned int i; } x; x.f = f;
  unsigned int r = x.i + 0x7FFFu + ((x.i >> 16) & 1u);   // RNE
  return (unsigned short)(r >> 16);
}
// packed 2xf32 -> 2xbf16 (v_cvt_pk_bf16_f32 on gfx950, RNE)
__device__ __forceinline__ unsigned int pk2bf(float a, float b){
  union { __hip_bfloat162 h; unsigned int u; } cv;
  cv.h = __float22bfloat162_rn(float2{a, b});
  return cv.u;
}
// silu via guaranteed-native v_exp_f32 + v_rcp_f32 (5 VALU, 2 quarter-rate)
__device__ __forceinline__ float silu_f(float v){
  float e = __builtin_amdgcn_exp2f(v * -1.442695041f);
  return v * __builtin_amdgcn_rcpf(1.0f + e);
}
__device__ __forceinline__ void async16(const void* g, void* l){
  __builtin_amdgcn_global_load_lds(
      (const __attribute__((address_space(1))) unsigned int*)g,
      (__attribute__((address_space(3))) unsigned int*)l, 16, 0, 0);
}

// ---------------- prep: weight transpose->bf16, h->bf16, radial, b1e ----------------
__global__ __launch_bounds__(256) void prep_k(
    const float* __restrict__ h_in, const float* __restrict__ cd,
    const float* __restrict__ w_in, const float* __restrict__ w_out,
    const float* __restrict__ ew1, const float* __restrict__ ew2,
    const float* __restrict__ nw1, const float* __restrict__ nw2,
    const float* __restrict__ eb1,
    unsigned short* __restrict__ w_in_t, unsigned short* __restrict__ w_out_t,
    unsigned short* __restrict__ ew1cat, float* __restrict__ w1r,
    float* __restrict__ b1e,
    unsigned short* __restrict__ ew2t, unsigned short* __restrict__ nw1t,
    unsigned short* __restrict__ nw2t, unsigned short* __restrict__ hb_in,
    float* __restrict__ radial)
{
  const int s = blockIdx.y;
  const int tid = blockIdx.x * 256 + threadIdx.x;
  if (s == 18) {
    if (tid < NN * NF) hb_in[tid] = f2bf(h_in[tid]);
    return;
  }
  if (s == 19) {
    if (tid < NE) {
      float x = cd[tid*3+0], y = cd[tid*3+1], z = cd[tid*3+2];
      radial[tid] = x*x + y*y + z*z;
    }
    return;
  }
  if (s == 20) {
    if (tid < NL * 512) {
      int l = tid >> 9, c = tid & 511;
      b1e[tid] = (c < 256) ? eb1[l * HD + c] : 0.0f;
    }
    return;
  }
  if (s >= 2 && s < 6) {
    // edge_w1: [513][256] -> ew1cat [512][256]; radial row (k=512) -> w1r
    int l = s - 2;
    if (tid >= 513 * HD) return;
    int k = tid / HD, n = tid - k * HD;
    float v = ew1[(size_t)l * 513 * HD + tid];
    if (k == 512) { w1r[l * HD + n] = v; return; }
    unsigned short* dst = ew1cat + (size_t)l * 512 * 256;
    if (k < 256) dst[(size_t)n * 256 + k] = f2bf(v);
    else         dst[(size_t)(256 + n) * 256 + (k - 256)] = f2bf(v);
    return;
  }
  const float* src; unsigned short* dst; int K, N;
  if (s == 0)      { src = w_in;  dst = w_in_t;  K = NF;   N = HD; }
  else if (s == 1) { src = w_out; dst = w_out_t; K = HD;   N = NF; }
  else if (s < 10) { int l = s-6;  src = ew2 + (size_t)l*HD*HD;   dst = ew2t + (size_t)l*HD*HD;  K = HD;   N = HD; }
  else if (s < 14) { int l = s-10; src = nw1 + (size_t)l*2*HD*HD; dst = nw1t + (size_t)l*HD*512; K = 2*HD; N = HD; }
  else             { int l = s-14; src = nw2 + (size_t)l*HD*HD;   dst = nw2t + (size_t)l*HD*HD;  K = HD;   N = HD; }
  if (tid >= K * N) return;
  int k = tid / N, n = tid - k * N;
  dst[(size_t)n * K + k] = f2bf(src[tid]);
}

// ---------------- CSR build (counting sort of edges by row) ----------------
__global__ __launch_bounds__(256) void hist_k(const int* __restrict__ erow, int* __restrict__ hist){
  int e = blockIdx.x * 256 + threadIdx.x;
  if (e < NE){
    unsigned r = (unsigned)erow[e]; if (r >= NN) r = 0;
    atomicAdd(&hist[r], 1);
  }
}

__global__ __launch_bounds__(256) void scan_k(const int* __restrict__ hist,
                                              int* __restrict__ starts, int* __restrict__ cursor){
  __shared__ int part[256];
  const int t = threadIdx.x;
  const int CH = 79;                 // 256*79 = 20224 >= 20000
  int lo = t * CH, hi = lo + CH; if (hi > NN) hi = NN; if (lo > NN) lo = NN;
  int s = 0;
  for (int i = lo; i < hi; ++i) s += hist[i];
  part[t] = s; __syncthreads();
  for (int off = 1; off < 256; off <<= 1){
    int v = (t >= off) ? part[t - off] : 0;
    __syncthreads();
    part[t] += v;
    __syncthreads();
  }
  int base = (t == 0) ? 0 : part[t - 1];
  for (int i = lo; i < hi; ++i){ starts[i] = base; cursor[i] = base; base += hist[i]; }
  if (t == 255) starts[NN] = part[255];
}

__global__ __launch_bounds__(256) void scatter_k(const int* __restrict__ erow,
                                                 int* __restrict__ cursor, int* __restrict__ sorted){
  int e = blockIdx.x * 256 + threadIdx.x;
  if (e < NE){
    unsigned r = (unsigned)erow[e]; if (r >= NN) r = 0;
    int pos = atomicAdd(&cursor[r], 1);
    sorted[pos] = e;
  }
}

// ---------------- generic 128x128 bf16 MFMA GEMM: out = [silu](A @ Wt^T + bias) ----------------
// outB2 (optional): duplicate bf16 store with row stride 512 (xcat first half)
__global__ __launch_bounds__(256) void gemm_k(
    const unsigned short* __restrict__ Am, const unsigned short* __restrict__ Wt,
    const float* __restrict__ bias,
    unsigned short* __restrict__ outB, float* __restrict__ outF,
    unsigned short* __restrict__ outB2,
    int M, int N, int K, int fuseSilu)
{
  __shared__ __align__(16) unsigned short As[128*32];
  __shared__ __align__(16) unsigned short Bs[128*32];
  const int t = threadIdx.x;
  const int lane = t & 63, wave = t >> 6;
  const int ln15 = lane & 15, q = lane >> 4;
  const int bm = blockIdx.x, bn = blockIdx.y;
  const int wm = wave >> 1, wn = wave & 1;

  f32x4 acc[4][4];
  #pragma unroll
  for (int i = 0; i < 4; ++i)
    #pragma unroll
    for (int j = 0; j < 4; ++j) acc[i][j] = (f32x4){0.f,0.f,0.f,0.f};

  const int sr = t >> 2;
  const int sc = (t & 3) * 8;
  int am0 = bm*128 + sr;      if (am0 > M-1) am0 = M-1;
  int am1 = bm*128 + 64 + sr; if (am1 > M-1) am1 = M-1;
  int an0 = bn*128 + sr;      if (an0 > N-1) an0 = N-1;
  int an1 = bn*128 + 64 + sr; if (an1 > N-1) an1 = N-1;
  const unsigned short* a0 = Am + (size_t)am0 * K + sc;
  const unsigned short* a1 = Am + (size_t)am1 * K + sc;
  const unsigned short* b0 = Wt + (size_t)an0 * K + sc;
  const unsigned short* b1 = Wt + (size_t)an1 * K + sc;

  const int nkt = K >> 5;
  for (int kt = 0; kt < nkt; ++kt) {
    const int k0 = kt * 32;
    async16(a0 + k0, &As[t*8]);
    async16(a1 + k0, &As[2048 + t*8]);
    async16(b0 + k0, &Bs[t*8]);
    async16(b1 + k0, &Bs[2048 + t*8]);
    __syncthreads();
    short8 fa[4], fb[4];
    #pragma unroll
    for (int i = 0; i < 4; ++i)
      fa[i] = *(const short8*)&As[(wm*64 + i*16 + ln15)*32 + q*8];
    #pragma unroll
    for (int j = 0; j < 4; ++j)
      fb[j] = *(const short8*)&Bs[(wn*64 + j*16 + ln15)*32 + q*8];
    #pragma unroll
    for (int i = 0; i < 4; ++i)
      #pragma unroll
      for (int j = 0; j < 4; ++j)
        acc[i][j] = __builtin_amdgcn_mfma_f32_16x16x32_bf16(fa[i], fb[j], acc[i][j], 0, 0, 0);
    __syncthreads();
  }

  #pragma unroll
  for (int i = 0; i < 4; ++i) {
    #pragma unroll
    for (int j = 0; j < 4; ++j) {
      const int n = bn*128 + wn*64 + j*16 + ln15;
      if (n >= N) continue;
      const float bv = bias ? bias[n] : 0.0f;
      #pragma unroll
      for (int r = 0; r < 4; ++r) {
        const int m = bm*128 + wm*64 + i*16 + q*4 + r;
        if (m >= M) continue;
        float v = acc[i][j][r] + bv;
        if (fuseSilu) v = silu_f(v);
        if (outB) {
          unsigned short b = f2bf(v);
          outB[(size_t)m * N + n] = b;
          if (outB2) outB2[(size_t)m * 512 + n] = b;
        }
        else outF[(size_t)m * N + n] = v;
      }
    }
  }
}

// ---------------- fused edge MLP + aggregation (fp32 hT, native silu, pk-f32 math) ----
// Prologue: m1 = silu(hTf[row] + hTf[col]+256 + rad*w1r) -> M1 (swizzled kt-blocked).
// Phase 2: K=256 MFMA, B direct from global (L2-hot, per-wave-private rows), no
// per-kt barriers. Epilogue: transposed LDS segmented reduction -> few atomics.
__global__ __launch_bounds__(256, 4) void edge_k(
    const float* __restrict__ hTf,           // [NN][512] fp32
    const int* __restrict__ erow, const int* __restrict__ ecol,
    const float* __restrict__ radial, const int* __restrict__ sorted,
    const float* __restrict__ w1r,           // [256]
    const unsigned short* __restrict__ w2t,  // [256][256]
    const float* __restrict__ b2,
    float* __restrict__ agg)                  // [NN][256] fp32, pre-zeroed
{
  // MBUF: M1 kt-blocked [8][64][32] (16384 shorts), then m2T [256][stride 66] (16896)
  __shared__ __align__(16) unsigned short MBUF[16896];   // 33.8 KB
  __shared__ float radS[64];
  __shared__ int   rowS[64];
  __shared__ float w1rS[256];
  unsigned short* M1  = MBUF;
  unsigned short* m2T = MBUF;

  const int t = threadIdx.x;
  const int lane = t & 63, wave = t >> 6;
  const int ln15 = lane & 15, q = lane >> 4;
  const int e0 = blockIdx.x * 64;
  const int sr = t >> 2;                                  // edge row 0..63
  const int sc_swz = (((t & 3) ^ ((sr >> 1) & 3))) * 8;   // logical k-seg (elements)
  const int xq = ((q ^ ((ln15 >> 1) & 3))) * 8;           // reader phys seg

  const int es = sorted[e0 + sr];
  unsigned nr = (unsigned)erow[es]; if (nr >= NN) nr = 0;
  unsigned nc = (unsigned)ecol[es]; if (nc >= NN) nc = 0;
  const float* hr = hTf + (size_t)nr * 512 + sc_swz;
  const float* hc = hTf + (size_t)nc * 512 + 256 + sc_swz;
  if (t < 64) {
    int e = sorted[e0 + t];
    radS[t] = radial[e];
    unsigned r = (unsigned)erow[e]; if (r >= NN) r = 0;
    rowS[t] = (int)r;
  }
  w1rS[t] = w1r[t];

  // per-wave private W2 rows for phase-2 B fragments (global, L2-hot)
  const unsigned short* w2row[4];
  #pragma unroll
  for (int j = 0; j < 4; ++j)
    w2row[j] = w2t + (size_t)(wave*64 + j*16 + ln15) * HD + q*8;

  // prefetch b2 per-thread (epilogue 2)
  float bv2[4];
  #pragma unroll
  for (int j = 0; j < 4; ++j) bv2[j] = b2[wave*64 + j*16 + ln15];

  __syncthreads();   // radS, w1rS visible
  const float rad = radS[sr];

  // prologue: m1 = silu(hr + hc + rad*w1r) -> M1 (kt-blocked, swizzled), b128 stores
  #pragma unroll
  for (int ch = 0; ch < 8; ++ch) {
    const int c0 = ch*32 + sc_swz;                 // logical col base (8 cols)
    f32x4 a0 = *(const f32x4*)(hr + ch*32);
    f32x4 a1 = *(const f32x4*)(hr + ch*32 + 4);
    f32x4 c0v = *(const f32x4*)(hc + ch*32);
    f32x4 c1v = *(const f32x4*)(hc + ch*32 + 4);
    f32x4 w0 = *(const f32x4*)&w1rS[c0];
    f32x4 w1 = *(const f32x4*)&w1rS[c0 + 4];
    f32x4 s0 = a0 + c0v + rad * w0;                // v_pk_add/fma_f32
    f32x4 s1 = a1 + c1v + rad * w1;
    float o0 = silu_f(s0[0]), o1 = silu_f(s0[1]), o2 = silu_f(s0[2]), o3 = silu_f(s0[3]);
    float o4 = silu_f(s1[0]), o5 = silu_f(s1[1]), o6 = silu_f(s1[2]), o7 = silu_f(s1[3]);
    union { unsigned int u[4]; short8 s; } res;
    res.u[0] = pk2bf(o0, o1); res.u[1] = pk2bf(o2, o3);
    res.u[2] = pk2bf(o4, o5); res.u[3] = pk2bf(o6, o7);
    *(short8*)&M1[ch*2048 + sr*32 + (t & 3)*8] = res.s;
  }
  __syncthreads();   // M1 visible to all waves

  // phase 2: K = 256 (M1 @ W2^T), barrier-free; fb direct from global (L2)
  f32x4 acc2[4][4];
  #pragma unroll
  for (int i = 0; i < 4; ++i)
    #pragma unroll
    for (int j = 0; j < 4; ++j) acc2[i][j] = (f32x4){0.f,0.f,0.f,0.f};

  #pragma unroll
  for (int kt = 0; kt < 8; ++kt) {
    short8 fa[4], fb[4];
    #pragma unroll
    for (int j = 0; j < 4; ++j) fb[j] = *(const short8*)(w2row[j] + kt*32);
    #pragma unroll
    for (int i = 0; i < 4; ++i) fa[i] = *(const short8*)&M1[kt*2048 + (i*16 + ln15)*32 + xq];
    #pragma unroll
    for (int i = 0; i < 4; ++i)
      #pragma unroll
      for (int j = 0; j < 4; ++j)
        acc2[i][j] = __builtin_amdgcn_mfma_f32_16x16x32_bf16(fa[i], fb[j], acc2[i][j], 0, 0, 0);
  }
  __syncthreads();   // all M1 reads done -> MBUF reusable as m2T

  // epilogue 2a: silu -> m2T[col][stride 66] in LDS (paired b32 stores, 4B aligned)
  #pragma unroll
  for (int i = 0; i < 4; ++i) {
    #pragma unroll
    for (int j = 0; j < 4; ++j) {
      const int n = wave*64 + j*16 + ln15;
      f32x4 s = acc2[i][j] + bv2[j];               // v_pk_add_f32
      float s0 = silu_f(s[0]), s1 = silu_f(s[1]), s2 = silu_f(s[2]), s3 = silu_f(s[3]);
      const int m = i*16 + q*4;
      *(unsigned int*)&m2T[n*66 + m]     = pk2bf(s0, s1);
      *(unsigned int*)&m2T[n*66 + m + 2] = pk2bf(s2, s3);
    }
  }
  __syncthreads();

  // epilogue 2b: per-column segmented reduction (scalar run boundaries via readfirstlane)
  {
    const int c = t;                   // 256 threads = 256 columns
    int cur = __builtin_amdgcn_readfirstlane(rowS[0]);
    float s = 0.f;
    #pragma unroll
    for (int m = 0; m < 64; m += 4) {
      unsigned int u0 = *(const unsigned int*)&m2T[c*66 + m];
      unsigned int u1 = *(const unsigned int*)&m2T[c*66 + m + 2];
      int n0 = __builtin_amdgcn_readfirstlane(rowS[m]);
      int n1 = __builtin_amdgcn_readfirstlane(rowS[m+1]);
      int n2 = __builtin_amdgcn_readfirstlane(rowS[m+2]);
      int n3 = __builtin_amdgcn_readfirstlane(rowS[m+3]);
      float f0 = bf2f((unsigned short)u0), f1 = bf2f((unsigned short)(u0 >> 16));
      float f2v = bf2f((unsigned short)u1), f3 = bf2f((unsigned short)(u1 >> 16));
      if (n0 != cur) { atomicAdd(&agg[(size_t)cur * HD + c], s); s = 0.f; cur = n0; }
      s += f0;
      if (n1 != cur) { atomicAdd(&agg[(size_t)cur * HD + c], s); s = 0.f; cur = n1; }
      s += f1;
      if (n2 != cur) { atomicAdd(&agg[(size_t)cur * HD + c], s); s = 0.f; cur = n2; }
      s += f2v;
      if (n3 != cur) { atomicAdd(&agg[(size_t)cur * HD + c], s); s = 0.f; cur = n3; }
      s += f3;
    }
    atomicAdd(&agg[(size_t)cur * HD + c], s);
  }
}

// ---------------- aggcvt: xcat[:,256:512] = bf16(agg); agg re-zeroed for next layer ----
__global__ __launch_bounds__(256) void aggcvt_k(
    float* __restrict__ agg, unsigned short* __restrict__ xcat)
{
  const int g = blockIdx.x * 256 + threadIdx.x;   // NN*64 threads, 4 cols each
  const int node = g >> 6;
  const int c = (g & 63) * 4;
  if (node >= NN) return;
  float4 a = *(const float4*)(agg + (size_t)node * HD + c);
  uint2 pk; pk.x = pk2bf(a.x, a.y); pk.y = pk2bf(a.z, a.w);
  *(uint2*)(xcat + (size_t)node * 2 * HD + HD + c) = pk;
  *(float4*)(agg + (size_t)node * HD + c) = float4{0.f, 0.f, 0.f, 0.f};
}

// ---------------- launch ----------------
extern "C" void kernel_launch(void* const* d_in, const int* in_sizes, int n_in,
                              void* d_out, int out_size, void* d_ws, size_t ws_size,
                              hipStream_t stream)
{
  (void)in_sizes; (void)n_in; (void)out_size; (void)ws_size;
  const float* h_in  = (const float*)d_in[0];
  const int*   ei    = (const int*)d_in[1];
  const float* cd    = (const float*)d_in[2];
  const float* w_in  = (const float*)d_in[3];
  const float* b_in  = (const float*)d_in[4];
  const float* w_out = (const float*)d_in[5];
  const float* b_out = (const float*)d_in[6];
  const float* ew1   = (const float*)d_in[7];
  const float* eb1   = (const float*)d_in[8];
  const float* ew2   = (const float*)d_in[9];
  const float* eb2   = (const float*)d_in[10];
  const float* nw1   = (const float*)d_in[11];
  const float* nb1   = (const float*)d_in[12];
  const float* nw2   = (const float*)d_in[13];
  const float* nb2   = (const float*)d_in[14];
  float* out = (float*)d_out;

  char* base = (char*)d_ws;
  size_t off = 0;
  auto WS = [&](size_t bytes) -> char* {
    char* p = base + off;
    off = (off + bytes + 255) & ~(size_t)255;
    return p;
  };
  float*          radial  = (float*)WS((size_t)NE * 4);
  unsigned short* hb_in   = (unsigned short*)WS((size_t)NN * NF * 2);
  unsigned short* hcur    = (unsigned short*)WS((size_t)NN * HD * 2);
  unsigned short* xcat    = (unsigned short*)WS((size_t)NN * 2 * HD * 2);
  float*          aggF    = (float*)WS((size_t)NN * HD * 4);
  float*          hTf     = (float*)WS((size_t)NN * 512 * 4);   // 41 MB fp32
  unsigned short* x1      = (unsigned short*)hTf;  // alias: hTf dead when x1 live
  unsigned short* w_in_t  = (unsigned short*)WS((size_t)NF * HD * 2);
  unsigned short* w_out_t = (unsigned short*)WS((size_t)NF * HD * 2);
  unsigned short* ew1cat  = (unsigned short*)WS((size_t)NL * 512 * 256 * 2);
  float*          w1r     = (float*)WS((size_t)NL * HD * 4);
  float*          b1e     = (float*)WS((size_t)NL * 512 * 4);
  unsigned short* ew2t    = (unsigned short*)WS((size_t)NL * HD * HD * 2);
  unsigned short* nw1t    = (unsigned short*)WS((size_t)NL * HD * 512 * 2);
  unsigned short* nw2t    = (unsigned short*)WS((size_t)NL * HD * HD * 2);
  int*            hist    = (int*)WS((size_t)NN * 4);
  int*            starts  = (int*)WS((size_t)(NN + 1) * 4);
  int*            cursor  = (int*)WS((size_t)NN * 4);
  int*            sorted  = (int*)WS((size_t)NE * 4);

  hipMemsetAsync(hist, 0, (size_t)NN * 4, stream);
  hipMemsetAsync(aggF, 0, (size_t)NN * HD * 4, stream);
  prep_k<<<dim3(5000, 21, 1), 256, 0, stream>>>(h_in, cd, w_in, w_out, ew1, ew2, nw1, nw2,
      eb1, w_in_t, w_out_t, ew1cat, w1r, b1e, ew2t, nw1t, nw2t, hb_in, radial);
  hist_k<<<NE / 256, 256, 0, stream>>>(ei, hist);
  scan_k<<<1, 256, 0, stream>>>(hist, starts, cursor);
  scatter_k<<<NE / 256, 256, 0, stream>>>(ei, cursor, sorted);

  // h = h_in @ w_in + b_in  (also writes xcat first half)
  gemm_k<<<dim3(157, 2), 256, 0, stream>>>(hb_in, w_in_t, b_in, hcur, nullptr, xcat,
      NN, HD, NF, 0);

  for (int l = 0; l < NL; ++l) {
    // node-level phase-1 table (fp32): hTf = hcur @ [W1_row | W1_col]^T + [b1 | 0]
    gemm_k<<<dim3(157, 4), 256, 0, stream>>>(hcur, ew1cat + (size_t)l * 512 * 256,
        b1e + (size_t)l * 512, nullptr, hTf, nullptr, NN, 512, HD, 0);
    edge_k<<<NE / 64, 256, 0, stream>>>(hTf, ei, ei + NE, radial, sorted,
        w1r + l * HD, ew2t + (size_t)l * HD * HD, eb2 + l * HD, aggF);
    aggcvt_k<<<NN * 64 / 256, 256, 0, stream>>>(aggF, xcat);
    gemm_k<<<dim3(157, 2), 256, 0, stream>>>(xcat, nw1t + (size_t)l * HD * 512,
        nb1 + l * HD, x1, nullptr, nullptr, NN, HD, 2 * HD, 1);
    // nw2 writes hcur AND xcat first half for the next layer's concat
    gemm_k<<<dim3(157, 2), 256, 0, stream>>>(x1, nw2t + (size_t)l * HD * HD,
        nb2 + l * HD, hcur, nullptr, (l < NL-1) ? xcat : nullptr, NN, HD, HD, 0);
  }

  // out = h @ w_out + b_out  (fp32 output)
  gemm_k<<<dim3(157, 1), 256, 0, stream>>>(hcur, w_out_t, b_out, nullptr, out, nullptr,
      NN, NF, HD, 0);
}

// Round 13
// 1385.791 us; speedup vs baseline: 2.7730x; 1.0370x over previous
//
#include <hip/hip_runtime.h>
#include <hip/hip_bf16.h>
#include <cstdint>
#include <cstddef>

#define NN 20000
#define NE 640000
#define NF 64
#define HD 256
#define NL 4

typedef __attribute__((ext_vector_type(8))) short short8;
typedef __attribute__((ext_vector_type(4))) float f32x4;

__device__ __forceinline__ float bf2f(unsigned short u){
  union { unsigned int i; float f; } x; x.i = ((unsigned int)u) << 16; return x.f;
}
__device__ __forceinline__ unsigned short f2bf(float f){
  union { float f; unsigned int i; } x; x.f = f;
  unsigned int r = x.i + 0x7FFFu + ((x.i >> 16) & 1u);   // RNE
  return (unsigned short)(r >> 16);
}
// packed 2xf32 -> 2xbf16 (v_cvt_pk_bf16_f32 on gfx950, RNE)
__device__ __forceinline__ unsigned int pk2bf(float a, float b){
  union { __hip_bfloat162 h; unsigned int u; } cv;
  cv.h = __float22bfloat162_rn(float2{a, b});
  return cv.u;
}
// silu via guaranteed-native v_exp_f32 + v_rcp_f32 (5 VALU, 2 quarter-rate)
__device__ __forceinline__ float silu_f(float v){
  float e = __builtin_amdgcn_exp2f(v * -1.442695041f);
  return v * __builtin_amdgcn_rcpf(1.0f + e);
}
__device__ __forceinline__ void async16(const void* g, void* l){
  __builtin_amdgcn_global_load_lds(
      (const __attribute__((address_space(1))) unsigned int*)g,
      (__attribute__((address_space(3))) unsigned int*)l, 16, 0, 0);
}

// ---------------- prep: weight transpose->bf16, h->bf16, radial, b1e ----------------
__global__ __launch_bounds__(256) void prep_k(
    const float* __restrict__ h_in, const float* __restrict__ cd,
    const float* __restrict__ w_in, const float* __restrict__ w_out,
    const float* __restrict__ ew1, const float* __restrict__ ew2,
    const float* __restrict__ nw1, const float* __restrict__ nw2,
    const float* __restrict__ eb1,
    unsigned short* __restrict__ w_in_t, unsigned short* __restrict__ w_out_t,
    unsigned short* __restrict__ ew1cat, float* __restrict__ w1r,
    float* __restrict__ b1e,
    unsigned short* __restrict__ ew2t, unsigned short* __restrict__ nw1t,
    unsigned short* __restrict__ nw2t, unsigned short* __restrict__ hb_in,
    float* __restrict__ radial)
{
  const int s = blockIdx.y;
  const int tid = blockIdx.x * 256 + threadIdx.x;
  if (s == 18) {
    if (tid < NN * NF) hb_in[tid] = f2bf(h_in[tid]);
    return;
  }
  if (s == 19) {
    if (tid < NE) {
      float x = cd[tid*3+0], y = cd[tid*3+1], z = cd[tid*3+2];
      radial[tid] = x*x + y*y + z*z;
    }
    return;
  }
  if (s == 20) {
    if (tid < NL * 512) {
      int l = tid >> 9, c = tid & 511;
      b1e[tid] = (c < 256) ? eb1[l * HD + c] : 0.0f;
    }
    return;
  }
  if (s >= 2 && s < 6) {
    // edge_w1: [513][256] -> ew1cat [512][256]; radial row (k=512) -> w1r
    int l = s - 2;
    if (tid >= 513 * HD) return;
    int k = tid / HD, n = tid - k * HD;
    float v = ew1[(size_t)l * 513 * HD + tid];
    if (k == 512) { w1r[l * HD + n] = v; return; }
    unsigned short* dst = ew1cat + (size_t)l * 512 * 256;
    if (k < 256) dst[(size_t)n * 256 + k] = f2bf(v);
    else         dst[(size_t)(256 + n) * 256 + (k - 256)] = f2bf(v);
    return;
  }
  const float* src; unsigned short* dst; int K, N;
  if (s == 0)      { src = w_in;  dst = w_in_t;  K = NF;   N = HD; }
  else if (s == 1) { src = w_out; dst = w_out_t; K = HD;   N = NF; }
  else if (s < 10) { int l = s-6;  src = ew2 + (size_t)l*HD*HD;   dst = ew2t + (size_t)l*HD*HD;  K = HD;   N = HD; }
  else if (s < 14) { int l = s-10; src = nw1 + (size_t)l*2*HD*HD; dst = nw1t + (size_t)l*HD*512; K = 2*HD; N = HD; }
  else             { int l = s-14; src = nw2 + (size_t)l*HD*HD;   dst = nw2t + (size_t)l*HD*HD;  K = HD;   N = HD; }
  if (tid >= K * N) return;
  int k = tid / N, n = tid - k * N;
  dst[(size_t)n * K + k] = f2bf(src[tid]);
}

// ---------------- CSR build (counting sort of edges by row) ----------------
__global__ __launch_bounds__(256) void hist_k(const int* __restrict__ erow, int* __restrict__ hist){
  int e = blockIdx.x * 256 + threadIdx.x;
  if (e < NE){
    unsigned r = (unsigned)erow[e]; if (r >= NN) r = 0;
    atomicAdd(&hist[r], 1);
  }
}

__global__ __launch_bounds__(256) void scan_k(const int* __restrict__ hist,
                                              int* __restrict__ starts, int* __restrict__ cursor){
  __shared__ int part[256];
  const int t = threadIdx.x;
  const int CH = 79;                 // 256*79 = 20224 >= 20000
  int lo = t * CH, hi = lo + CH; if (hi > NN) hi = NN; if (lo > NN) lo = NN;
  int s = 0;
  for (int i = lo; i < hi; ++i) s += hist[i];
  part[t] = s; __syncthreads();
  for (int off = 1; off < 256; off <<= 1){
    int v = (t >= off) ? part[t - off] : 0;
    __syncthreads();
    part[t] += v;
    __syncthreads();
  }
  int base = (t == 0) ? 0 : part[t - 1];
  for (int i = lo; i < hi; ++i){ starts[i] = base; cursor[i] = base; base += hist[i]; }
  if (t == 255) starts[NN] = part[255];
}

__global__ __launch_bounds__(256) void scatter_k(const int* __restrict__ erow,
                                                 int* __restrict__ cursor, int* __restrict__ sorted){
  int e = blockIdx.x * 256 + threadIdx.x;
  if (e < NE){
    unsigned r = (unsigned)erow[e]; if (r >= NN) r = 0;
    int pos = atomicAdd(&cursor[r], 1);
    sorted[pos] = e;
  }
}

// ---------------- generic 128x128 bf16 MFMA GEMM: out = [silu](A @ Wt^T + bias) ----------------
// outB2 (optional): duplicate bf16 store with row stride 512 (xcat first half)
__global__ __launch_bounds__(256) void gemm_k(
    const unsigned short* __restrict__ Am, const unsigned short* __restrict__ Wt,
    const float* __restrict__ bias,
    unsigned short* __restrict__ outB, float* __restrict__ outF,
    unsigned short* __restrict__ outB2,
    int M, int N, int K, int fuseSilu)
{
  __shared__ __align__(16) unsigned short As[128*32];
  __shared__ __align__(16) unsigned short Bs[128*32];
  const int t = threadIdx.x;
  const int lane = t & 63, wave = t >> 6;
  const int ln15 = lane & 15, q = lane >> 4;
  const int bm = blockIdx.x, bn = blockIdx.y;
  const int wm = wave >> 1, wn = wave & 1;

  f32x4 acc[4][4];
  #pragma unroll
  for (int i = 0; i < 4; ++i)
    #pragma unroll
    for (int j = 0; j < 4; ++j) acc[i][j] = (f32x4){0.f,0.f,0.f,0.f};

  const int sr = t >> 2;
  const int sc = (t & 3) * 8;
  int am0 = bm*128 + sr;      if (am0 > M-1) am0 = M-1;
  int am1 = bm*128 + 64 + sr; if (am1 > M-1) am1 = M-1;
  int an0 = bn*128 + sr;      if (an0 > N-1) an0 = N-1;
  int an1 = bn*128 + 64 + sr; if (an1 > N-1) an1 = N-1;
  const unsigned short* a0 = Am + (size_t)am0 * K + sc;
  const unsigned short* a1 = Am + (size_t)am1 * K + sc;
  const unsigned short* b0 = Wt + (size_t)an0 * K + sc;
  const unsigned short* b1 = Wt + (size_t)an1 * K + sc;

  const int nkt = K >> 5;
  for (int kt = 0; kt < nkt; ++kt) {
    const int k0 = kt * 32;
    async16(a0 + k0, &As[t*8]);
    async16(a1 + k0, &As[2048 + t*8]);
    async16(b0 + k0, &Bs[t*8]);
    async16(b1 + k0, &Bs[2048 + t*8]);
    __syncthreads();
    short8 fa[4], fb[4];
    #pragma unroll
    for (int i = 0; i < 4; ++i)
      fa[i] = *(const short8*)&As[(wm*64 + i*16 + ln15)*32 + q*8];
    #pragma unroll
    for (int j = 0; j < 4; ++j)
      fb[j] = *(const short8*)&Bs[(wn*64 + j*16 + ln15)*32 + q*8];
    #pragma unroll
    for (int i = 0; i < 4; ++i)
      #pragma unroll
      for (int j = 0; j < 4; ++j)
        acc[i][j] = __builtin_amdgcn_mfma_f32_16x16x32_bf16(fa[i], fb[j], acc[i][j], 0, 0, 0);
    __syncthreads();
  }

  #pragma unroll
  for (int i = 0; i < 4; ++i) {
    #pragma unroll
    for (int j = 0; j < 4; ++j) {
      const int n = bn*128 + wn*64 + j*16 + ln15;
      if (n >= N) continue;
      const float bv = bias ? bias[n] : 0.0f;
      #pragma unroll
      for (int r = 0; r < 4; ++r) {
        const int m = bm*128 + wm*64 + i*16 + q*4 + r;
        if (m >= M) continue;
        float v = acc[i][j][r] + bv;
        if (fuseSilu) v = silu_f(v);
        if (outB) {
          unsigned short b = f2bf(v);
          outB[(size_t)m * N + n] = b;
          if (outB2) outB2[(size_t)m * 512 + n] = b;
        }
        else outF[(size_t)m * N + n] = v;
      }
    }
  }
}

// ---------------- fused edge MLP + aggregation (bf16 hT, native silu) ----------------
// Prologue: m1 = silu(hT[row] + hT[col]+256 + rad*w1r) -> M1 (swizzled kt-blocked).
// Phase 2: K=256 MFMA, B direct from global (L2-hot, per-wave-private rows), no
// per-kt barriers. Epilogue: transposed LDS segmented reduction -> few atomics.
__global__ __launch_bounds__(256, 4) void edge_k(
    const unsigned short* __restrict__ hT,   // [NN][512] bf16
    const int* __restrict__ erow, const int* __restrict__ ecol,
    const float* __restrict__ radial, const int* __restrict__ sorted,
    const float* __restrict__ w1r,           // [256]
    const unsigned short* __restrict__ w2t,  // [256][256]
    const float* __restrict__ b2,
    float* __restrict__ agg)                  // [NN][256] fp32, pre-zeroed
{
  // MBUF: M1 kt-blocked [8][64][32] (16384 shorts), then m2T [256][stride 66] (16896)
  __shared__ __align__(16) unsigned short MBUF[16896];   // 33.8 KB
  __shared__ float radS[64];
  __shared__ int   rowS[64];
  __shared__ float w1rS[256];
  unsigned short* M1  = MBUF;
  unsigned short* m2T = MBUF;

  const int t = threadIdx.x;
  const int lane = t & 63, wave = t >> 6;
  const int ln15 = lane & 15, q = lane >> 4;
  const int e0 = blockIdx.x * 64;
  const int sr = t >> 2;                                  // edge row 0..63
  const int sc_swz = (((t & 3) ^ ((sr >> 1) & 3))) * 8;   // logical k-seg (elements)
  const int xq = ((q ^ ((ln15 >> 1) & 3))) * 8;           // reader phys seg

  const int es = sorted[e0 + sr];
  unsigned nr = (unsigned)erow[es]; if (nr >= NN) nr = 0;
  unsigned nc = (unsigned)ecol[es]; if (nc >= NN) nc = 0;
  const unsigned short* hr = hT + (size_t)nr * 512 + sc_swz;
  const unsigned short* hc = hT + (size_t)nc * 512 + 256 + sc_swz;
  if (t < 64) {
    int e = sorted[e0 + t];
    radS[t] = radial[e];
    unsigned r = (unsigned)erow[e]; if (r >= NN) r = 0;
    rowS[t] = (int)r;
  }
  w1rS[t] = w1r[t];

  // per-wave private W2 rows for phase-2 B fragments (global, L2-hot)
  const unsigned short* w2row[4];
  #pragma unroll
  for (int j = 0; j < 4; ++j)
    w2row[j] = w2t + (size_t)(wave*64 + j*16 + ln15) * HD + q*8;

  // prefetch b2 per-thread (epilogue 2)
  float bv2[4];
  #pragma unroll
  for (int j = 0; j < 4; ++j) bv2[j] = b2[wave*64 + j*16 + ln15];

  __syncthreads();   // radS, w1rS visible
  const float rad = radS[sr];

  // prologue: m1 = silu(hr + hc + rad*w1r) -> M1 (kt-blocked, swizzled), b128 stores
  #pragma unroll
  for (int ch = 0; ch < 8; ++ch) {
    const int c0 = ch*32 + sc_swz;                 // logical col base (8 cols)
    short8 va = *(const short8*)(hr + ch*32);
    short8 vb = *(const short8*)(hc + ch*32);
    f32x4 w0 = *(const f32x4*)&w1rS[c0];
    f32x4 w1 = *(const f32x4*)&w1rS[c0 + 4];
    const unsigned int* ua = (const unsigned int*)&va;
    const unsigned int* ub = (const unsigned int*)&vb;
    float o[8];
    #pragma unroll
    for (int i = 0; i < 4; ++i) {
      union { unsigned int i; float f; } alo, ahi, blo, bhi;
      alo.i = ua[i] << 16; ahi.i = ua[i] & 0xFFFF0000u;
      blo.i = ub[i] << 16; bhi.i = ub[i] & 0xFFFF0000u;
      o[2*i]   = alo.f + blo.f;
      o[2*i+1] = ahi.f + bhi.f;
    }
    o[0] = silu_f(o[0] + rad * w0[0]);  o[1] = silu_f(o[1] + rad * w0[1]);
    o[2] = silu_f(o[2] + rad * w0[2]);  o[3] = silu_f(o[3] + rad * w0[3]);
    o[4] = silu_f(o[4] + rad * w1[0]);  o[5] = silu_f(o[5] + rad * w1[1]);
    o[6] = silu_f(o[6] + rad * w1[2]);  o[7] = silu_f(o[7] + rad * w1[3]);
    union { unsigned int u[4]; short8 s; } res;
    res.u[0] = pk2bf(o[0], o[1]); res.u[1] = pk2bf(o[2], o[3]);
    res.u[2] = pk2bf(o[4], o[5]); res.u[3] = pk2bf(o[6], o[7]);
    *(short8*)&M1[ch*2048 + sr*32 + (t & 3)*8] = res.s;
  }
  __syncthreads();   // M1 visible to all waves

  // phase 2: K = 256 (M1 @ W2^T), barrier-free; fb direct from global (L2)
  f32x4 acc2[4][4];
  #pragma unroll
  for (int i = 0; i < 4; ++i)
    #pragma unroll
    for (int j = 0; j < 4; ++j) acc2[i][j] = (f32x4){0.f,0.f,0.f,0.f};

  #pragma unroll
  for (int kt = 0; kt < 8; ++kt) {
    short8 fa[4], fb[4];
    #pragma unroll
    for (int j = 0; j < 4; ++j) fb[j] = *(const short8*)(w2row[j] + kt*32);
    #pragma unroll
    for (int i = 0; i < 4; ++i) fa[i] = *(const short8*)&M1[kt*2048 + (i*16 + ln15)*32 + xq];
    #pragma unroll
    for (int i = 0; i < 4; ++i)
      #pragma unroll
      for (int j = 0; j < 4; ++j)
        acc2[i][j] = __builtin_amdgcn_mfma_f32_16x16x32_bf16(fa[i], fb[j], acc2[i][j], 0, 0, 0);
  }
  __syncthreads();   // all M1 reads done -> MBUF reusable as m2T

  // epilogue 2a: silu -> m2T[col][stride 66] in LDS (paired b32 stores, 4B aligned)
  #pragma unroll
  for (int i = 0; i < 4; ++i) {
    #pragma unroll
    for (int j = 0; j < 4; ++j) {
      const int n = wave*64 + j*16 + ln15;
      f32x4 s = acc2[i][j] + bv2[j];               // v_pk_add_f32
      float s0 = silu_f(s[0]), s1 = silu_f(s[1]), s2 = silu_f(s[2]), s3 = silu_f(s[3]);
      const int m = i*16 + q*4;
      *(unsigned int*)&m2T[n*66 + m]     = pk2bf(s0, s1);
      *(unsigned int*)&m2T[n*66 + m + 2] = pk2bf(s2, s3);
    }
  }
  __syncthreads();

  // epilogue 2b: per-column segmented reduction (scalar run boundaries via readfirstlane)
  {
    const int c = t;                   // 256 threads = 256 columns
    int cur = __builtin_amdgcn_readfirstlane(rowS[0]);
    float s = 0.f;
    #pragma unroll
    for (int m = 0; m < 64; m += 4) {
      unsigned int u0 = *(const unsigned int*)&m2T[c*66 + m];
      unsigned int u1 = *(const unsigned int*)&m2T[c*66 + m + 2];
      int n0 = __builtin_amdgcn_readfirstlane(rowS[m]);
      int n1 = __builtin_amdgcn_readfirstlane(rowS[m+1]);
      int n2 = __builtin_amdgcn_readfirstlane(rowS[m+2]);
      int n3 = __builtin_amdgcn_readfirstlane(rowS[m+3]);
      float f0 = bf2f((unsigned short)u0), f1 = bf2f((unsigned short)(u0 >> 16));
      float f2v = bf2f((unsigned short)u1), f3 = bf2f((unsigned short)(u1 >> 16));
      if (n0 != cur) { atomicAdd(&agg[(size_t)cur * HD + c], s); s = 0.f; cur = n0; }
      s += f0;
      if (n1 != cur) { atomicAdd(&agg[(size_t)cur * HD + c], s); s = 0.f; cur = n1; }
      s += f1;
      if (n2 != cur) { atomicAdd(&agg[(size_t)cur * HD + c], s); s = 0.f; cur = n2; }
      s += f2v;
      if (n3 != cur) { atomicAdd(&agg[(size_t)cur * HD + c], s); s = 0.f; cur = n3; }
      s += f3;
    }
    atomicAdd(&agg[(size_t)cur * HD + c], s);
  }
}

// ---------------- aggcvt: xcat[:,256:512] = bf16(agg); agg re-zeroed for next layer ----
__global__ __launch_bounds__(256) void aggcvt_k(
    float* __restrict__ agg, unsigned short* __restrict__ xcat)
{
  const int g = blockIdx.x * 256 + threadIdx.x;   // NN*64 threads, 4 cols each
  const int node = g >> 6;
  const int c = (g & 63) * 4;
  if (node >= NN) return;
  float4 a = *(const float4*)(agg + (size_t)node * HD + c);
  uint2 pk; pk.x = pk2bf(a.x, a.y); pk.y = pk2bf(a.z, a.w);
  *(uint2*)(xcat + (size_t)node * 2 * HD + HD + c) = pk;
  *(float4*)(agg + (size_t)node * HD + c) = float4{0.f, 0.f, 0.f, 0.f};
}

// ---------------- launch ----------------
extern "C" void kernel_launch(void* const* d_in, const int* in_sizes, int n_in,
                              void* d_out, int out_size, void* d_ws, size_t ws_size,
                              hipStream_t stream)
{
  (void)in_sizes; (void)n_in; (void)out_size; (void)ws_size;
  const float* h_in  = (const float*)d_in[0];
  const int*   ei    = (const int*)d_in[1];
  const float* cd    = (const float*)d_in[2];
  const float* w_in  = (const float*)d_in[3];
  const float* b_in  = (const float*)d_in[4];
  const float* w_out = (const float*)d_in[5];
  const float* b_out = (const float*)d_in[6];
  const float* ew1   = (const float*)d_in[7];
  const float* eb1   = (const float*)d_in[8];
  const float* ew2   = (const float*)d_in[9];
  const float* eb2   = (const float*)d_in[10];
  const float* nw1   = (const float*)d_in[11];
  const float* nb1   = (const float*)d_in[12];
  const float* nw2   = (const float*)d_in[13];
  const float* nb2   = (const float*)d_in[14];
  float* out = (float*)d_out;

  char* base = (char*)d_ws;
  size_t off = 0;
  auto WS = [&](size_t bytes) -> char* {
    char* p = base + off;
    off = (off + bytes + 255) & ~(size_t)255;
    return p;
  };
  float*          radial  = (float*)WS((size_t)NE * 4);
  unsigned short* hb_in   = (unsigned short*)WS((size_t)NN * NF * 2);
  unsigned short* hcur    = (unsigned short*)WS((size_t)NN * HD * 2);
  unsigned short* xcat    = (unsigned short*)WS((size_t)NN * 2 * HD * 2);
  float*          aggF    = (float*)WS((size_t)NN * HD * 4);
  unsigned short* hT      = (unsigned short*)WS((size_t)NN * 512 * 2);  // 20.5 MB bf16
  unsigned short* x1      = hT;   // alias: hT dead once edge_k done; x1 lives after
  unsigned short* w_in_t  = (unsigned short*)WS((size_t)NF * HD * 2);
  unsigned short* w_out_t = (unsigned short*)WS((size_t)NF * HD * 2);
  unsigned short* ew1cat  = (unsigned short*)WS((size_t)NL * 512 * 256 * 2);
  float*          w1r     = (float*)WS((size_t)NL * HD * 4);
  float*          b1e     = (float*)WS((size_t)NL * 512 * 4);
  unsigned short* ew2t    = (unsigned short*)WS((size_t)NL * HD * HD * 2);
  unsigned short* nw1t    = (unsigned short*)WS((size_t)NL * HD * 512 * 2);
  unsigned short* nw2t    = (unsigned short*)WS((size_t)NL * HD * HD * 2);
  int*            hist    = (int*)WS((size_t)NN * 4);
  int*            starts  = (int*)WS((size_t)(NN + 1) * 4);
  int*            cursor  = (int*)WS((size_t)NN * 4);
  int*            sorted  = (int*)WS((size_t)NE * 4);

  hipMemsetAsync(hist, 0, (size_t)NN * 4, stream);
  hipMemsetAsync(aggF, 0, (size_t)NN * HD * 4, stream);
  prep_k<<<dim3(5000, 21, 1), 256, 0, stream>>>(h_in, cd, w_in, w_out, ew1, ew2, nw1, nw2,
      eb1, w_in_t, w_out_t, ew1cat, w1r, b1e, ew2t, nw1t, nw2t, hb_in, radial);
  hist_k<<<NE / 256, 256, 0, stream>>>(ei, hist);
  scan_k<<<1, 256, 0, stream>>>(hist, starts, cursor);
  scatter_k<<<NE / 256, 256, 0, stream>>>(ei, cursor, sorted);

  // h = h_in @ w_in + b_in  (also writes xcat first half)
  gemm_k<<<dim3(157, 2), 256, 0, stream>>>(hb_in, w_in_t, b_in, hcur, nullptr, xcat,
      NN, HD, NF, 0);

  for (int l = 0; l < NL; ++l) {
    // node-level phase-1 table (bf16): hT = hcur @ [W1_row | W1_col]^T + [b1 | 0]
    gemm_k<<<dim3(157, 4), 256, 0, stream>>>(hcur, ew1cat + (size_t)l * 512 * 256,
        b1e + (size_t)l * 512, hT, nullptr, nullptr, NN, 512, HD, 0);
    edge_k<<<NE / 64, 256, 0, stream>>>(hT, ei, ei + NE, radial, sorted,
        w1r + l * HD, ew2t + (size_t)l * HD * HD, eb2 + l * HD, aggF);
    aggcvt_k<<<NN * 64 / 256, 256, 0, stream>>>(aggF, xcat);
    gemm_k<<<dim3(157, 2), 256, 0, stream>>>(xcat, nw1t + (size_t)l * HD * 512,
        nb1 + l * HD, x1, nullptr, nullptr, NN, HD, 2 * HD, 1);
    // nw2 writes hcur AND xcat first half for the next layer's concat
    gemm_k<<<dim3(157, 2), 256, 0, stream>>>(x1, nw2t + (size_t)l * HD * HD,
        nb2 + l * HD, hcur, nullptr, (l < NL-1) ? xcat : nullptr, NN, HD, HD, 0);
  }

  // out = h @ w_out + b_out  (fp32 output)
  gemm_k<<<dim3(157, 1), 256, 0, stream>>>(hcur, w_out_t, b_out, nullptr, out, nullptr,
      NN, NF, HD, 0);
}